// Round 7
// baseline (438.822 us; speedup 1.0000x reference)
//
#include <hip/hip_runtime.h>

#define DIM 256
#define NLr 16384
#define NGr 32768
#define NDr 8192
#define NE  262144
#define HSTRIDE 32772  // hist/offs per-relation stride (16B-aligned)

typedef short bf16x8 __attribute__((ext_vector_type(8)));
typedef float f32x4 __attribute__((ext_vector_type(4)));

__device__ __forceinline__ unsigned short f2bf(float f) {
  unsigned int u = __builtin_bit_cast(unsigned int, f);
  u += 0x7fffu + ((u >> 16) & 1u);
  return (unsigned short)(u >> 16);
}
__device__ __forceinline__ float bf2f(unsigned short b) {
  return __builtin_bit_cast(float, ((unsigned int)b) << 16);
}
__device__ __forceinline__ float bflo(unsigned int u) {
  return __builtin_bit_cast(float, u << 16);
}
__device__ __forceinline__ float bfhi(unsigned int u) {
  return __builtin_bit_cast(float, u & 0xffff0000u);
}

struct WPtrs { const float* p[9]; };
struct NTab { int n[6]; };
struct RelIdx { const int* dst[6]; };
struct ETab { const int* src[6]; const int* dst[6]; const float* w[6]; };
struct TTab3 { const float* h[3]; unsigned short* hp[3];
               const unsigned short* w[3]; int cum[4]; };
struct GTab3 { const unsigned short* hp[3]; unsigned short* acc[3];
               const int2* sw[3]; const int* of[3]; int cum[4]; };

// ---- convert 9 weight matrices (f32 -> bf16), 65536 elems each ----
__global__ __launch_bounds__(256) void conv_w_kernel(WPtrs wp, unsigned short* __restrict__ dst) {
  int m = blockIdx.y;
  int i = blockIdx.x * 256 + threadIdx.x;
  dst[m * 65536 + i] = f2bf(wp.p[m][i]);
}

// ---- CSR build: histogram over dst for all 6 relations ----
__global__ __launch_bounds__(256) void hist6_kernel(RelIdx R, int* __restrict__ hist) {
  int r = blockIdx.y;
  int e = blockIdx.x * 256 + threadIdx.x;
  atomicAdd(&hist[r * HSTRIDE + R.dst[r][e]], 1);
}

// ---- scan stage A: per-block partial sums (4096 bins / block) ----
__global__ __launch_bounds__(256) void scanA_kernel(const int* __restrict__ hist,
                                                    int* __restrict__ partials, NTab N) {
  int r = blockIdx.y, b = blockIdx.x;
  int n = N.n[r], base = b * 4096;
  int s = 0;
  if (base < n) {
    const int4* h4 = reinterpret_cast<const int4*>(hist + r * HSTRIDE + base);
#pragma unroll
    for (int k = 0; k < 4; ++k) {
      int4 v = h4[threadIdx.x * 4 + k];
      s += v.x + v.y + v.z + v.w;
    }
  }
#pragma unroll
  for (int o = 1; o < 64; o <<= 1) s += __shfl_xor(s, o);
  __shared__ int wsum[4];
  if ((threadIdx.x & 63) == 0) wsum[threadIdx.x >> 6] = s;
  __syncthreads();
  if (threadIdx.x == 0) partials[r * 8 + b] = wsum[0] + wsum[1] + wsum[2] + wsum[3];
}

// ---- scan stage B: tiny per-relation exclusive scan of 8 partials ----
__global__ void scanTop_kernel(const int* __restrict__ partials, int* __restrict__ boff) {
  int r = threadIdx.x;
  if (r < 6) {
    int off = 0;
    for (int b = 0; b < 8; ++b) { boff[r * 8 + b] = off; off += partials[r * 8 + b]; }
  }
}

// ---- scan stage C: block-local scan + write offs + zero cursor + offs[n]=NE ----
__global__ __launch_bounds__(256) void scanC_kernel(const int* __restrict__ hist,
                                                    const int* __restrict__ boff,
                                                    int* __restrict__ offs,
                                                    int* __restrict__ cursor, NTab N) {
  int r = blockIdx.y, b = blockIdx.x;
  int n = N.n[r], base = b * 4096;
  if (b == 0 && threadIdx.x == 0) offs[r * HSTRIDE + n] = NE;
  if (base >= n) return;
  const int tid = threadIdx.x;
  int vals[16];
  int s = 0;
  const int4* h4 = reinterpret_cast<const int4*>(hist + r * HSTRIDE + base);
#pragma unroll
  for (int k = 0; k < 4; ++k) {
    int4 v = h4[tid * 4 + k];
    vals[4 * k] = v.x; vals[4 * k + 1] = v.y; vals[4 * k + 2] = v.z; vals[4 * k + 3] = v.w;
    s += v.x + v.y + v.z + v.w;
  }
  __shared__ int part[256];
  part[tid] = s;
  __syncthreads();
  for (int off = 1; off < 256; off <<= 1) {
    int v = (tid >= off) ? part[tid - off] : 0;
    __syncthreads();
    part[tid] += v;
    __syncthreads();
  }
  int run = part[tid] - s + boff[r * 8 + b];
  int gbase = base + tid * 16;
#pragma unroll
  for (int j = 0; j < 16; ++j) {
    offs[r * HSTRIDE + gbase + j] = run;
    run += vals[j];
    cursor[r * 32768 + gbase + j] = 0;
  }
}

// ---- CSR build: bucket-scatter packed (src, w), explicit cursor ----
__global__ __launch_bounds__(256) void scatter6_kernel(ETab E, const int* __restrict__ offs,
                                                       int* __restrict__ cursor,
                                                       int2* __restrict__ srcw) {
  int r = blockIdx.y;
  int e = blockIdx.x * 256 + threadIdx.x;
  int d = E.dst[r][e];
  int pos = offs[r * HSTRIDE + d] + atomicAdd(&cursor[r * 32768 + d], 1);
  srcw[(size_t)r * NE + pos] = make_int2(E.src[r][e], __builtin_bit_cast(int, E.w[r][e]));
}

// ---- gather: msg[node] = (sum w_e * hp[src_e]) / deg, one wave per node ----
// bucket semantics [offs[node], offs[node+1]), unroll-4 body (round-6 proven)
__global__ __launch_bounds__(256) void gather3_kernel(GTab3 T) {
  const int bx = blockIdx.x;
  int r = 0;
#pragma unroll
  for (int k = 1; k < 3; ++k) r += (bx >= T.cum[k]);
  const int node = (bx - T.cum[r]) * 4 + (threadIdx.x >> 6);
  const int lane = threadIdx.x & 63;
  const int* of = T.of[r];
  const int beg = of[node], end = of[node + 1];
  const uint2* __restrict__ hv = reinterpret_cast<const uint2*>(T.hp[r]);
  const int2* __restrict__ sw = T.sw[r];
  float4 a = {0.f, 0.f, 0.f, 0.f};
  float degw = 0.f;
  int j = beg;
  for (; j + 3 < end; j += 4) {
    int2 p0 = sw[j], p1 = sw[j + 1], p2 = sw[j + 2], p3 = sw[j + 3];
    float w0 = __builtin_bit_cast(float, p0.y);
    float w1 = __builtin_bit_cast(float, p1.y);
    float w2 = __builtin_bit_cast(float, p2.y);
    float w3 = __builtin_bit_cast(float, p3.y);
    uint2 x0 = hv[(size_t)p0.x * 64 + lane];
    uint2 x1 = hv[(size_t)p1.x * 64 + lane];
    uint2 x2 = hv[(size_t)p2.x * 64 + lane];
    uint2 x3 = hv[(size_t)p3.x * 64 + lane];
    degw += (w0 + w1) + (w2 + w3);
    a.x += w0 * bflo(x0.x) + w1 * bflo(x1.x) + w2 * bflo(x2.x) + w3 * bflo(x3.x);
    a.y += w0 * bfhi(x0.x) + w1 * bfhi(x1.x) + w2 * bfhi(x2.x) + w3 * bfhi(x3.x);
    a.z += w0 * bflo(x0.y) + w1 * bflo(x1.y) + w2 * bflo(x2.y) + w3 * bflo(x3.y);
    a.w += w0 * bfhi(x0.y) + w1 * bfhi(x1.y) + w2 * bfhi(x2.y) + w3 * bfhi(x3.y);
  }
  for (; j < end; ++j) {
    int2 p0 = sw[j];
    float w0 = __builtin_bit_cast(float, p0.y);
    uint2 x0 = hv[(size_t)p0.x * 64 + lane];
    degw += w0;
    a.x += w0 * bflo(x0.x); a.y += w0 * bfhi(x0.x);
    a.z += w0 * bflo(x0.y); a.w += w0 * bfhi(x0.y);
  }
  float inv = (degw == 0.f) ? 1.f : 1.f / degw;
  uint2 o;
  o.x = (unsigned)f2bf(a.x * inv) | ((unsigned)f2bf(a.y * inv) << 16);
  o.y = (unsigned)f2bf(a.z * inv) | ((unsigned)f2bf(a.w * inv) << 16);
  reinterpret_cast<uint2*>(T.acc[r])[(size_t)node * 64 + lane] = o;
}

// ---- shared GEMM pieces: 64 rows x (256x256) bf16 MFMA (round-6 proven) ----
__device__ __forceinline__ void stage_x_f32(const float* __restrict__ g, int r0,
                                            unsigned short* xs, int tid) {
#pragma unroll
  for (int it = 0; it < 16; ++it) {
    int i = it * 256 + tid;
    int row = i >> 6, q = i & 63;
    float4 v = reinterpret_cast<const float4*>(g)[(size_t)(r0 + row) * 64 + q];
    ushort4 b;
    b.x = f2bf(v.x); b.y = f2bf(v.y); b.z = f2bf(v.z); b.w = f2bf(v.w);
    *reinterpret_cast<ushort4*>(&xs[row * 264 + q * 4]) = b;
  }
}

__device__ __forceinline__ void gemm_frag(const unsigned short* xs,
                                          const unsigned short* __restrict__ Wg,
                                          unsigned short* wl, int tid,
                                          f32x4 accv[4][4]) {
  const int wid = tid >> 6, lhi = (tid & 63) >> 4, llo = tid & 15;
  for (int ks = 0; ks < 8; ++ks) {
    const int k0 = ks * 32;
    __syncthreads();  // protects xs (first iter) and wl reads from prev iter
    {
      const uint4* gp = reinterpret_cast<const uint4*>(Wg + (size_t)tid * 256 + k0);
      uint4 a0 = gp[0], a1 = gp[1], a2 = gp[2], a3 = gp[3];
      uint4* lp = reinterpret_cast<uint4*>(wl + tid * 56);
      lp[0] = a0; lp[1] = a1; lp[2] = a2; lp[3] = a3;
    }
    __syncthreads();
    bf16x8 afr[4], bfr[4];
#pragma unroll
    for (int rt = 0; rt < 4; ++rt)
      afr[rt] = *reinterpret_cast<const bf16x8*>(&xs[(rt * 16 + llo) * 264 + k0 + lhi * 8]);
#pragma unroll
    for (int nt = 0; nt < 4; ++nt)
      bfr[nt] = *reinterpret_cast<const bf16x8*>(&wl[(wid * 64 + nt * 16 + llo) * 56 + lhi * 8]);
#pragma unroll
    for (int rt = 0; rt < 4; ++rt)
#pragma unroll
      for (int nt = 0; nt < 4; ++nt)
        accv[rt][nt] = __builtin_amdgcn_mfma_f32_16x16x32_bf16(afr[rt], bfr[nt], accv[rt][nt], 0, 0, 0);
  }
}

// ---- pre-transform (3 relations per launch): hp = h_src @ W_rel.T, bf16 ----
// relT6-proven structure: stage_x_f32 input + gemm_frag + scalar writeout
__global__ __launch_bounds__(256) void transform3_kernel(TTab3 T) {
  __shared__ alignas(16) unsigned short xs[64 * 264];
  __shared__ alignas(16) unsigned short wl[256 * 56];
  const int tid = threadIdx.x;
  const int bx = blockIdx.x;
  int r = 0;
#pragma unroll
  for (int k = 1; k < 3; ++k) r += (bx >= T.cum[k]);
  const int r0 = (bx - T.cum[r]) * 64;
  unsigned short* hp = T.hp[r];

  stage_x_f32(T.h[r], r0, xs, tid);

  f32x4 accv[4][4];
#pragma unroll
  for (int a = 0; a < 4; ++a)
#pragma unroll
    for (int b = 0; b < 4; ++b) accv[a][b] = {0.f, 0.f, 0.f, 0.f};

  gemm_frag(xs, T.w[r], wl, tid, accv);

  const int wid = tid >> 6, lane = tid & 63, lhi = lane >> 4, llo = lane & 15;
#pragma unroll
  for (int rt = 0; rt < 4; ++rt)
#pragma unroll
    for (int nt = 0; nt < 4; ++nt) {
      int col = wid * 64 + nt * 16 + llo;
#pragma unroll
      for (int rg = 0; rg < 4; ++rg) {
        int row = rt * 16 + lhi * 4 + rg;
        hp[(size_t)(r0 + row) * DIM + col] = f2bf(accv[rt][nt][rg]);
      }
    }
}

// ---- per node type: self-GEMM + relation attention + residual + LN + leaky ----
__global__ __launch_bounds__(256) void fuse_kernel(
    const float* __restrict__ h, const unsigned short* __restrict__ msg1,
    const unsigned short* __restrict__ msg2, const unsigned short* __restrict__ Wbf,
    const float* __restrict__ A1, const float* __restrict__ A2,
    const float* __restrict__ gamma, const float* __restrict__ beta,
    float* __restrict__ out) {
  __shared__ alignas(16) union SM {
    struct { unsigned short x[64 * 264]; unsigned short w[256 * 56]; } g;
    unsigned short s[64 * 260];  // self result, bf16
  } ov;
  __shared__ float sgb[512];
  const int tid = threadIdx.x;
  const int r0 = blockIdx.x * 64;

  stage_x_f32(h, r0, ov.g.x, tid);
  for (int i = tid; i < 512; i += 256) sgb[i] = (i < 256) ? gamma[i] : beta[i - 256];

  f32x4 accv[4][4];
#pragma unroll
  for (int a = 0; a < 4; ++a)
#pragma unroll
    for (int b = 0; b < 4; ++b) accv[a][b] = {0.f, 0.f, 0.f, 0.f};

  gemm_frag(ov.g.x, Wbf, ov.g.w, tid, accv);

  const int wid = tid >> 6, lane = tid & 63, lhi = lane >> 4, llo = lane & 15;
  __syncthreads();  // all MFMA LDS reads done before overlaying ov.s
#pragma unroll
  for (int rt = 0; rt < 4; ++rt)
#pragma unroll
    for (int nt = 0; nt < 4; ++nt) {
      int col = wid * 64 + nt * 16 + llo;
#pragma unroll
      for (int rg = 0; rg < 4; ++rg)
        ov.s[(rt * 16 + lhi * 4 + rg) * 260 + col] = f2bf(accv[rt][nt][rg]);
    }
  __syncthreads();

  // epilogue: wave handles 16 rows; lane owns 4 dims
  const int d0 = lane * 4;
  const float4* A1v = reinterpret_cast<const float4*>(A1);
  const float4* A2v = reinterpret_cast<const float4*>(A2);
  float4 a1f[4], a2f[4];
#pragma unroll
  for (int hh = 0; hh < 4; ++hh) { a1f[hh] = A1v[hh * 64 + lane]; a2f[hh] = A2v[hh * 64 + lane]; }
  const float4 g4 = *reinterpret_cast<const float4*>(&sgb[d0]);
  const float4 b4 = *reinterpret_cast<const float4*>(&sgb[256 + d0]);

  for (int rl = 0; rl < 16; ++rl) {
    int row = wid * 16 + rl;
    size_t gb = (size_t)(r0 + row) * DIM + d0;
    ushort4 m1b = *reinterpret_cast<const ushort4*>(msg1 + gb);
    ushort4 m2b = *reinterpret_cast<const ushort4*>(msg2 + gb);
    float4 m1 = {bf2f(m1b.x), bf2f(m1b.y), bf2f(m1b.z), bf2f(m1b.w)};
    float4 m2 = {bf2f(m2b.x), bf2f(m2b.y), bf2f(m2b.z), bf2f(m2b.w)};
    float4 hvv = *reinterpret_cast<const float4*>(h + gb);
    ushort4 sb = *reinterpret_cast<const ushort4*>(&ov.s[row * 260 + d0]);
    float4 sv = {bf2f(sb.x), bf2f(sb.y), bf2f(sb.z), bf2f(sb.w)};

    float sc[8];
#pragma unroll
    for (int hh = 0; hh < 4; ++hh) {
      sc[hh]     = m1.x * a1f[hh].x + m1.y * a1f[hh].y + m1.z * a1f[hh].z + m1.w * a1f[hh].w;
      sc[4 + hh] = m2.x * a2f[hh].x + m2.y * a2f[hh].y + m2.z * a2f[hh].z + m2.w * a2f[hh].w;
    }
#pragma unroll
    for (int o = 1; o < 64; o <<= 1) {
#pragma unroll
      for (int j = 0; j < 8; ++j) sc[j] += __shfl_xor(sc[j], o);
    }
    // softmax over the 2 relations per head; scale = 1/(sqrt(256)*0.5) = 0.125
    float c1 = 0.f, c2 = 0.f;
#pragma unroll
    for (int hh = 0; hh < 4; ++hh) {
      float s1 = sc[hh] * 0.125f, s2 = sc[4 + hh] * 0.125f;
      float mx = fmaxf(s1, s2);
      float e1 = __expf(s1 - mx), e2 = __expf(s2 - mx);
      float inv = 1.f / (e1 + e2);
      c1 += e1 * inv; c2 += e2 * inv;
    }
    c1 *= 0.25f; c2 *= 0.25f;  // mean over H=4 heads

    float4 u;
    u.x = sv.x + c1 * m1.x + c2 * m2.x + hvv.x;
    u.y = sv.y + c1 * m1.y + c2 * m2.y + hvv.y;
    u.z = sv.z + c1 * m1.z + c2 * m2.z + hvv.z;
    u.w = sv.w + c1 * m1.w + c2 * m2.w + hvv.w;

    float s1v = u.x + u.y + u.z + u.w;
    float s2v = u.x * u.x + u.y * u.y + u.z * u.z + u.w * u.w;
#pragma unroll
    for (int o = 1; o < 64; o <<= 1) { s1v += __shfl_xor(s1v, o); s2v += __shfl_xor(s2v, o); }
    float mu = s1v * (1.f / 256.f);
    float var = s2v * (1.f / 256.f) - mu * mu;
    float rstd = rsqrtf(var + 1e-5f);

    float4 y;
    y.x = (u.x - mu) * rstd * g4.x + b4.x;
    y.y = (u.y - mu) * rstd * g4.y + b4.y;
    y.z = (u.z - mu) * rstd * g4.z + b4.z;
    y.w = (u.w - mu) * rstd * g4.w + b4.w;
    y.x = fmaxf(y.x, 0.01f * y.x);
    y.y = fmaxf(y.y, 0.01f * y.y);
    y.z = fmaxf(y.z, 0.01f * y.z);
    y.w = fmaxf(y.w, 0.01f * y.w);
    *reinterpret_cast<float4*>(out + gb) = y;
  }
}

// ---- workspace layout (bytes); ~105 MB peak (< round-1-proven ~119 MB) ----
static constexpr size_t AL(size_t x) { return (x + 255) & ~size_t(255); }
// final messages (bf16), sized by DST rows, ushort offsets
static constexpr size_t ACCe_L2G = 0;
static constexpr size_t ACCe_G2L = ACCe_L2G + (size_t)NGr * DIM;
static constexpr size_t ACCe_G2D = ACCe_G2L + (size_t)NLr * DIM;
static constexpr size_t ACCe_D2G = ACCe_G2D + (size_t)NDr * DIM;
static constexpr size_t ACCe_L2D = ACCe_D2G + (size_t)NGr * DIM;
static constexpr size_t ACCe_D2L = ACCe_L2D + (size_t)NDr * DIM;
static constexpr size_t ACC_TOT  = ACCe_D2L + (size_t)NLr * DIM;
// hp buffer: reused by the two 3-relation groups; 57,344 rows (29.4 MB)
static constexpr size_t HP3_TOT  = (size_t)(NLr + NGr + NDr) * DIM;
static constexpr size_t OFF_ACC  = 0;
static constexpr size_t OFF_HP   = AL(OFF_ACC + ACC_TOT * 2);
static constexpr size_t OFF_WBF  = AL(OFF_HP + HP3_TOT * 2);
static constexpr size_t OFF_HIST = AL(OFF_WBF + 9 * 65536 * 2);
static constexpr size_t OFF_OFFS = AL(OFF_HIST + 6 * HSTRIDE * 4);
static constexpr size_t OFF_CURS = AL(OFF_OFFS + 6 * HSTRIDE * 4);
static constexpr size_t OFF_PART = AL(OFF_CURS + 6 * 32768 * 4);
static constexpr size_t OFF_BOFF = AL(OFF_PART + 48 * 4);
static constexpr size_t OFF_SRCW = AL(OFF_BOFF + 48 * 4);

extern "C" void kernel_launch(void* const* d_in, const int* in_sizes, int n_in,
                              void* d_out, int out_size, void* d_ws, size_t ws_size,
                              hipStream_t stream) {
  char* wsb = (char*)d_ws;
  unsigned short* acc = (unsigned short*)(wsb + OFF_ACC);
  unsigned short* hp  = (unsigned short*)(wsb + OFF_HP);
  unsigned short* wbf = (unsigned short*)(wsb + OFF_WBF);
  int* hist = (int*)(wsb + OFF_HIST);
  int* offs = (int*)(wsb + OFF_OFFS);
  int* curs = (int*)(wsb + OFF_CURS);
  int* part = (int*)(wsb + OFF_PART);
  int* boff = (int*)(wsb + OFF_BOFF);
  int2* srcw = (int2*)(wsb + OFF_SRCW);
  float* out = (float*)d_out;

  // relation order: l2g, g2l, g2d, d2g, l2d, d2l
  const int base[6] = {3, 8, 13, 18, 23, 28};
  const int hidx[6] = {0, 1, 1, 2, 0, 2};              // SOURCE type per relation
  const int nsrc[6] = {NLr, NGr, NGr, NDr, NLr, NDr};
  const int ndst[6] = {NGr, NLr, NDr, NGr, NDr, NLr};
  const size_t accOff[6] = {ACCe_L2G, ACCe_G2L, ACCe_G2D, ACCe_D2G, ACCe_L2D, ACCe_D2L};

  // weights -> bf16: slots 0..5 = W_rel, 6..8 = Wself_{l,g,d}
  WPtrs wp;
  wp.p[0] = (const float*)d_in[6];  wp.p[1] = (const float*)d_in[11];
  wp.p[2] = (const float*)d_in[16]; wp.p[3] = (const float*)d_in[21];
  wp.p[4] = (const float*)d_in[26]; wp.p[5] = (const float*)d_in[31];
  wp.p[6] = (const float*)d_in[33]; wp.p[7] = (const float*)d_in[36];
  wp.p[8] = (const float*)d_in[39];
  conv_w_kernel<<<dim3(256, 9), 256, 0, stream>>>(wp, wbf);

  // CSR build (fast multi-block scan, explicit cursor)
  (void)hipMemsetAsync(hist, 0, 6 * HSTRIDE * 4, stream);
  RelIdx R; NTab N; ETab Eb;
  for (int r = 0; r < 6; ++r) {
    R.dst[r] = (const int*)d_in[base[r] + 1];
    N.n[r] = ndst[r];
    Eb.src[r] = (const int*)d_in[base[r]];
    Eb.dst[r] = (const int*)d_in[base[r] + 1];
    Eb.w[r]  = (const float*)d_in[base[r] + 2];
  }
  hist6_kernel<<<dim3(NE / 256, 6), 256, 0, stream>>>(R, hist);
  scanA_kernel<<<dim3(8, 6), 256, 0, stream>>>(hist, part, N);
  scanTop_kernel<<<1, 64, 0, stream>>>(part, boff);
  scanC_kernel<<<dim3(8, 6), 256, 0, stream>>>(hist, boff, offs, curs, N);
  scatter6_kernel<<<dim3(NE / 256, 6), 256, 0, stream>>>(Eb, offs, curs, srcw);

  // two 3-relation groups sharing one hp buffer (ws cap)
  const int groups[2][3] = {{0, 1, 3}, {2, 4, 5}};
  for (int gidx = 0; gidx < 2; ++gidx) {
    const int* rel = groups[gidx];
    TTab3 T; GTab3 G;
    size_t hpo = 0;
    int cumT = 0, cumG = 0;
    for (int k = 0; k < 3; ++k) {
      int r = rel[k];
      T.h[k] = (const float*)d_in[hidx[r]];
      T.hp[k] = hp + hpo;
      T.w[k] = wbf + r * 65536;
      T.cum[k] = cumT;
      cumT += nsrc[r] / 64;
      G.hp[k] = hp + hpo;
      G.acc[k] = acc + accOff[r];
      G.sw[k] = srcw + (size_t)r * NE;
      G.of[k] = offs + r * HSTRIDE;
      G.cum[k] = cumG;
      cumG += ndst[r] / 4;
      hpo += (size_t)nsrc[r] * DIM;
    }
    T.cum[3] = cumT;
    G.cum[3] = cumG;
    transform3_kernel<<<cumT, 256, 0, stream>>>(T);
    gather3_kernel<<<cumG, 256, 0, stream>>>(G);
  }

  // type l: msgs [g2l, d2l]
  fuse_kernel<<<NLr / 64, 256, 0, stream>>>(
      (const float*)d_in[0], acc + ACCe_G2L, acc + ACCe_D2L, wbf + 6 * 65536,
      (const float*)d_in[12], (const float*)d_in[32],
      (const float*)d_in[34], (const float*)d_in[35], out);
  // type g: msgs [l2g, d2g]
  fuse_kernel<<<NGr / 64, 256, 0, stream>>>(
      (const float*)d_in[1], acc + ACCe_L2G, acc + ACCe_D2G, wbf + 7 * 65536,
      (const float*)d_in[7], (const float*)d_in[22],
      (const float*)d_in[37], (const float*)d_in[38], out + (size_t)NLr * DIM);
  // type d: msgs [g2d, l2d]
  fuse_kernel<<<NDr / 64, 256, 0, stream>>>(
      (const float*)d_in[2], acc + ACCe_G2D, acc + ACCe_L2D, wbf + 8 * 65536,
      (const float*)d_in[17], (const float*)d_in[27],
      (const float*)d_in[40], (const float*)d_in[41], out + (size_t)(NLr + NGr) * DIM);
}

// Round 8
// 422.079 us; speedup vs baseline: 1.0397x; 1.0397x over previous
//
#include <hip/hip_runtime.h>

#define DIM 256
#define NLr 16384
#define NGr 32768
#define NDr 8192
#define NE  262144
#define HSTRIDE 32772  // hist/offs per-relation stride (16B-aligned)

typedef short bf16x8 __attribute__((ext_vector_type(8)));
typedef float f32x4 __attribute__((ext_vector_type(4)));

__device__ __forceinline__ unsigned short f2bf(float f) {
  unsigned int u = __builtin_bit_cast(unsigned int, f);
  u += 0x7fffu + ((u >> 16) & 1u);
  return (unsigned short)(u >> 16);
}
__device__ __forceinline__ float bf2f(unsigned short b) {
  return __builtin_bit_cast(float, ((unsigned int)b) << 16);
}
__device__ __forceinline__ float bflo(unsigned int u) {
  return __builtin_bit_cast(float, u << 16);
}
__device__ __forceinline__ float bfhi(unsigned int u) {
  return __builtin_bit_cast(float, u & 0xffff0000u);
}

struct WPtrs { const float* p[9]; };
struct NTab { int n[6]; };
struct RelIdx { const int* dst[6]; };
struct ETab { const int* src[6]; const int* dst[6]; const float* w[6]; };
struct TTab3 { const float* h[3]; unsigned short* hp[3];
               const unsigned short* w[3]; int cum[4]; };
struct GTab3 { const unsigned short* hp[3]; unsigned short* acc[3];
               const unsigned* sw[3]; const int* of[3]; int cum[4]; };

// ---- convert 9 weight matrices (f32 -> bf16), 65536 elems each ----
__global__ __launch_bounds__(256) void conv_w_kernel(WPtrs wp, unsigned short* __restrict__ dst) {
  int m = blockIdx.y;
  int i = blockIdx.x * 256 + threadIdx.x;
  dst[m * 65536 + i] = f2bf(wp.p[m][i]);
}

// ---- CSR build: histogram over dst for all 6 relations ----
__global__ __launch_bounds__(256) void hist6_kernel(RelIdx R, int* __restrict__ hist) {
  int r = blockIdx.y;
  int e = blockIdx.x * 256 + threadIdx.x;
  atomicAdd(&hist[r * HSTRIDE + R.dst[r][e]], 1);
}

// ---- scan stage A: per-block partial sums (4096 bins / block) ----
__global__ __launch_bounds__(256) void scanA_kernel(const int* __restrict__ hist,
                                                    int* __restrict__ partials, NTab N) {
  int r = blockIdx.y, b = blockIdx.x;
  int n = N.n[r], base = b * 4096;
  int s = 0;
  if (base < n) {
    const int4* h4 = reinterpret_cast<const int4*>(hist + r * HSTRIDE + base);
#pragma unroll
    for (int k = 0; k < 4; ++k) {
      int4 v = h4[threadIdx.x * 4 + k];
      s += v.x + v.y + v.z + v.w;
    }
  }
#pragma unroll
  for (int o = 1; o < 64; o <<= 1) s += __shfl_xor(s, o);
  __shared__ int wsum[4];
  if ((threadIdx.x & 63) == 0) wsum[threadIdx.x >> 6] = s;
  __syncthreads();
  if (threadIdx.x == 0) partials[r * 8 + b] = wsum[0] + wsum[1] + wsum[2] + wsum[3];
}

// ---- scan stage B: tiny per-relation exclusive scan of 8 partials ----
__global__ void scanTop_kernel(const int* __restrict__ partials, int* __restrict__ boff) {
  int r = threadIdx.x;
  if (r < 6) {
    int off = 0;
    for (int b = 0; b < 8; ++b) { boff[r * 8 + b] = off; off += partials[r * 8 + b]; }
  }
}

// ---- scan stage C: block-local scan + write offs + zero cursor + offs[n]=NE ----
__global__ __launch_bounds__(256) void scanC_kernel(const int* __restrict__ hist,
                                                    const int* __restrict__ boff,
                                                    int* __restrict__ offs,
                                                    int* __restrict__ cursor, NTab N) {
  int r = blockIdx.y, b = blockIdx.x;
  int n = N.n[r], base = b * 4096;
  if (b == 0 && threadIdx.x == 0) offs[r * HSTRIDE + n] = NE;
  if (base >= n) return;
  const int tid = threadIdx.x;
  int vals[16];
  int s = 0;
  const int4* h4 = reinterpret_cast<const int4*>(hist + r * HSTRIDE + base);
#pragma unroll
  for (int k = 0; k < 4; ++k) {
    int4 v = h4[tid * 4 + k];
    vals[4 * k] = v.x; vals[4 * k + 1] = v.y; vals[4 * k + 2] = v.z; vals[4 * k + 3] = v.w;
    s += v.x + v.y + v.z + v.w;
  }
  __shared__ int part[256];
  part[tid] = s;
  __syncthreads();
  for (int off = 1; off < 256; off <<= 1) {
    int v = (tid >= off) ? part[tid - off] : 0;
    __syncthreads();
    part[tid] += v;
    __syncthreads();
  }
  int run = part[tid] - s + boff[r * 8 + b];
  int gbase = base + tid * 16;
#pragma unroll
  for (int j = 0; j < 16; ++j) {
    offs[r * HSTRIDE + gbase + j] = run;
    run += vals[j];
    cursor[r * 32768 + gbase + j] = 0;
  }
}

// ---- CSR build: bucket-scatter packed 4B (src:u16 | w:bf16), explicit cursor ----
__global__ __launch_bounds__(256) void scatter6_kernel(ETab E, const int* __restrict__ offs,
                                                       int* __restrict__ cursor,
                                                       unsigned* __restrict__ srcw) {
  int r = blockIdx.y;
  int e = blockIdx.x * 256 + threadIdx.x;
  int d = E.dst[r][e];
  int pos = offs[r * HSTRIDE + d] + atomicAdd(&cursor[r * 32768 + d], 1);
  srcw[(size_t)r * NE + pos] =
      (unsigned)E.src[r][e] | ((unsigned)f2bf(E.w[r][e]) << 16);
}

// ---- gather: msg[node] = (sum w_e * hp[src_e]) / deg ----
// one wave per node; half-wave 0 = even edge, half-wave 1 = odd edge;
// lane loads uint4 (8 dims); cross-half shfl_xor(32) combine at the end.
__global__ __launch_bounds__(256) void gather3_kernel(GTab3 T) {
  const int bx = blockIdx.x;
  int r = 0;
#pragma unroll
  for (int k = 1; k < 3; ++k) r += (bx >= T.cum[k]);
  const int node = (bx - T.cum[r]) * 4 + (threadIdx.x >> 6);
  const int lane = threadIdx.x & 63;
  const int half = lane >> 5;   // which edge of the pair
  const int c8 = lane & 31;     // uint4 column (8 dims) within the row
  const int* of = T.of[r];
  const int beg = of[node], end = of[node + 1];
  const uint4* __restrict__ hv = reinterpret_cast<const uint4*>(T.hp[r]);  // 32 uint4 / row
  const unsigned* __restrict__ sw = T.sw[r];
  float a0 = 0.f, a1 = 0.f, a2 = 0.f, a3 = 0.f, a4 = 0.f, a5 = 0.f, a6 = 0.f, a7 = 0.f;
  float degw = 0.f;
  for (int j = beg; j < end; j += 4) {
    int i0 = j + half * 2, i1 = i0 + 1;
    unsigned e0 = (i0 < end) ? sw[i0] : 0u;
    unsigned e1 = (i1 < end) ? sw[i1] : 0u;
    float w0 = bfhi(e0), w1 = bfhi(e1);        // w in high 16 bits
    int s0 = e0 & 0xffff, s1 = e1 & 0xffff;
    uint4 x0 = hv[(size_t)s0 * 32 + c8];
    uint4 x1 = hv[(size_t)s1 * 32 + c8];
    degw += w0 + w1;
    a0 += w0 * bflo(x0.x) + w1 * bflo(x1.x);
    a1 += w0 * bfhi(x0.x) + w1 * bfhi(x1.x);
    a2 += w0 * bflo(x0.y) + w1 * bflo(x1.y);
    a3 += w0 * bfhi(x0.y) + w1 * bfhi(x1.y);
    a4 += w0 * bflo(x0.z) + w1 * bflo(x1.z);
    a5 += w0 * bfhi(x0.z) + w1 * bfhi(x1.z);
    a6 += w0 * bflo(x0.w) + w1 * bflo(x1.w);
    a7 += w0 * bfhi(x0.w) + w1 * bfhi(x1.w);
  }
  // combine the two half-wave partials (lane <-> lane^32)
  a0 += __shfl_xor(a0, 32); a1 += __shfl_xor(a1, 32);
  a2 += __shfl_xor(a2, 32); a3 += __shfl_xor(a3, 32);
  a4 += __shfl_xor(a4, 32); a5 += __shfl_xor(a5, 32);
  a6 += __shfl_xor(a6, 32); a7 += __shfl_xor(a7, 32);
  degw += __shfl_xor(degw, 32);
  float inv = (degw == 0.f) ? 1.f : 1.f / degw;
  if (half == 0) {
    uint4 o;
    o.x = (unsigned)f2bf(a0 * inv) | ((unsigned)f2bf(a1 * inv) << 16);
    o.y = (unsigned)f2bf(a2 * inv) | ((unsigned)f2bf(a3 * inv) << 16);
    o.z = (unsigned)f2bf(a4 * inv) | ((unsigned)f2bf(a5 * inv) << 16);
    o.w = (unsigned)f2bf(a6 * inv) | ((unsigned)f2bf(a7 * inv) << 16);
    reinterpret_cast<uint4*>(T.acc[r])[(size_t)node * 32 + c8] = o;
  }
}

// ---- shared GEMM pieces: 64 rows x (256x256) bf16 MFMA (round-6/7 proven) ----
__device__ __forceinline__ void stage_x_f32(const float* __restrict__ g, int r0,
                                            unsigned short* xs, int tid) {
#pragma unroll
  for (int it = 0; it < 16; ++it) {
    int i = it * 256 + tid;
    int row = i >> 6, q = i & 63;
    float4 v = reinterpret_cast<const float4*>(g)[(size_t)(r0 + row) * 64 + q];
    ushort4 b;
    b.x = f2bf(v.x); b.y = f2bf(v.y); b.z = f2bf(v.z); b.w = f2bf(v.w);
    *reinterpret_cast<ushort4*>(&xs[row * 264 + q * 4]) = b;
  }
}

__device__ __forceinline__ void gemm_frag(const unsigned short* xs,
                                          const unsigned short* __restrict__ Wg,
                                          unsigned short* wl, int tid,
                                          f32x4 accv[4][4]) {
  const int wid = tid >> 6, lhi = (tid & 63) >> 4, llo = tid & 15;
  for (int ks = 0; ks < 8; ++ks) {
    const int k0 = ks * 32;
    __syncthreads();  // protects xs (first iter) and wl reads from prev iter
    {
      const uint4* gp = reinterpret_cast<const uint4*>(Wg + (size_t)tid * 256 + k0);
      uint4 a0 = gp[0], a1 = gp[1], a2 = gp[2], a3 = gp[3];
      uint4* lp = reinterpret_cast<uint4*>(wl + tid * 56);
      lp[0] = a0; lp[1] = a1; lp[2] = a2; lp[3] = a3;
    }
    __syncthreads();
    bf16x8 afr[4], bfr[4];
#pragma unroll
    for (int rt = 0; rt < 4; ++rt)
      afr[rt] = *reinterpret_cast<const bf16x8*>(&xs[(rt * 16 + llo) * 264 + k0 + lhi * 8]);
#pragma unroll
    for (int nt = 0; nt < 4; ++nt)
      bfr[nt] = *reinterpret_cast<const bf16x8*>(&wl[(wid * 64 + nt * 16 + llo) * 56 + lhi * 8]);
#pragma unroll
    for (int rt = 0; rt < 4; ++rt)
#pragma unroll
      for (int nt = 0; nt < 4; ++nt)
        accv[rt][nt] = __builtin_amdgcn_mfma_f32_16x16x32_bf16(afr[rt], bfr[nt], accv[rt][nt], 0, 0, 0);
  }
}

// ---- pre-transform (3 relations per launch): hp = h_src @ W_rel.T, bf16 ----
__global__ __launch_bounds__(256) void transform3_kernel(TTab3 T) {
  __shared__ alignas(16) unsigned short xs[64 * 264];
  __shared__ alignas(16) unsigned short wl[256 * 56];
  const int tid = threadIdx.x;
  const int bx = blockIdx.x;
  int r = 0;
#pragma unroll
  for (int k = 1; k < 3; ++k) r += (bx >= T.cum[k]);
  const int r0 = (bx - T.cum[r]) * 64;
  unsigned short* hp = T.hp[r];

  stage_x_f32(T.h[r], r0, xs, tid);

  f32x4 accv[4][4];
#pragma unroll
  for (int a = 0; a < 4; ++a)
#pragma unroll
    for (int b = 0; b < 4; ++b) accv[a][b] = {0.f, 0.f, 0.f, 0.f};

  gemm_frag(xs, T.w[r], wl, tid, accv);

  const int wid = tid >> 6, lane = tid & 63, lhi = lane >> 4, llo = lane & 15;
#pragma unroll
  for (int rt = 0; rt < 4; ++rt)
#pragma unroll
    for (int nt = 0; nt < 4; ++nt) {
      int col = wid * 64 + nt * 16 + llo;
#pragma unroll
      for (int rg = 0; rg < 4; ++rg) {
        int row = rt * 16 + lhi * 4 + rg;
        hp[(size_t)(r0 + row) * DIM + col] = f2bf(accv[rt][nt][rg]);
      }
    }
}

// ---- per node type: self-GEMM + relation attention + residual + LN + leaky ----
__global__ __launch_bounds__(256) void fuse_kernel(
    const float* __restrict__ h, const unsigned short* __restrict__ msg1,
    const unsigned short* __restrict__ msg2, const unsigned short* __restrict__ Wbf,
    const float* __restrict__ A1, const float* __restrict__ A2,
    const float* __restrict__ gamma, const float* __restrict__ beta,
    float* __restrict__ out) {
  __shared__ alignas(16) union SM {
    struct { unsigned short x[64 * 264]; unsigned short w[256 * 56]; } g;
    unsigned short s[64 * 260];  // self result, bf16
  } ov;
  __shared__ float sgb[512];
  const int tid = threadIdx.x;
  const int r0 = blockIdx.x * 64;

  stage_x_f32(h, r0, ov.g.x, tid);
  for (int i = tid; i < 512; i += 256) sgb[i] = (i < 256) ? gamma[i] : beta[i - 256];

  f32x4 accv[4][4];
#pragma unroll
  for (int a = 0; a < 4; ++a)
#pragma unroll
    for (int b = 0; b < 4; ++b) accv[a][b] = {0.f, 0.f, 0.f, 0.f};

  gemm_frag(ov.g.x, Wbf, ov.g.w, tid, accv);

  const int wid = tid >> 6, lane = tid & 63, lhi = lane >> 4, llo = lane & 15;
  __syncthreads();  // all MFMA LDS reads done before overlaying ov.s
#pragma unroll
  for (int rt = 0; rt < 4; ++rt)
#pragma unroll
    for (int nt = 0; nt < 4; ++nt) {
      int col = wid * 64 + nt * 16 + llo;
#pragma unroll
      for (int rg = 0; rg < 4; ++rg)
        ov.s[(rt * 16 + lhi * 4 + rg) * 260 + col] = f2bf(accv[rt][nt][rg]);
    }
  __syncthreads();

  // epilogue: wave handles 16 rows; lane owns 4 dims
  const int d0 = lane * 4;
  const float4* A1v = reinterpret_cast<const float4*>(A1);
  const float4* A2v = reinterpret_cast<const float4*>(A2);
  float4 a1f[4], a2f[4];
#pragma unroll
  for (int hh = 0; hh < 4; ++hh) { a1f[hh] = A1v[hh * 64 + lane]; a2f[hh] = A2v[hh * 64 + lane]; }
  const float4 g4 = *reinterpret_cast<const float4*>(&sgb[d0]);
  const float4 b4 = *reinterpret_cast<const float4*>(&sgb[256 + d0]);

  for (int rl = 0; rl < 16; ++rl) {
    int row = wid * 16 + rl;
    size_t gb = (size_t)(r0 + row) * DIM + d0;
    ushort4 m1b = *reinterpret_cast<const ushort4*>(msg1 + gb);
    ushort4 m2b = *reinterpret_cast<const ushort4*>(msg2 + gb);
    float4 m1 = {bf2f(m1b.x), bf2f(m1b.y), bf2f(m1b.z), bf2f(m1b.w)};
    float4 m2 = {bf2f(m2b.x), bf2f(m2b.y), bf2f(m2b.z), bf2f(m2b.w)};
    float4 hvv = *reinterpret_cast<const float4*>(h + gb);
    ushort4 sb = *reinterpret_cast<const ushort4*>(&ov.s[row * 260 + d0]);
    float4 sv = {bf2f(sb.x), bf2f(sb.y), bf2f(sb.z), bf2f(sb.w)};

    float sc[8];
#pragma unroll
    for (int hh = 0; hh < 4; ++hh) {
      sc[hh]     = m1.x * a1f[hh].x + m1.y * a1f[hh].y + m1.z * a1f[hh].z + m1.w * a1f[hh].w;
      sc[4 + hh] = m2.x * a2f[hh].x + m2.y * a2f[hh].y + m2.z * a2f[hh].z + m2.w * a2f[hh].w;
    }
#pragma unroll
    for (int o = 1; o < 64; o <<= 1) {
#pragma unroll
      for (int j = 0; j < 8; ++j) sc[j] += __shfl_xor(sc[j], o);
    }
    // softmax over the 2 relations per head; scale = 1/(sqrt(256)*0.5) = 0.125
    float c1 = 0.f, c2 = 0.f;
#pragma unroll
    for (int hh = 0; hh < 4; ++hh) {
      float s1 = sc[hh] * 0.125f, s2 = sc[4 + hh] * 0.125f;
      float mx = fmaxf(s1, s2);
      float e1 = __expf(s1 - mx), e2 = __expf(s2 - mx);
      float inv = 1.f / (e1 + e2);
      c1 += e1 * inv; c2 += e2 * inv;
    }
    c1 *= 0.25f; c2 *= 0.25f;  // mean over H=4 heads

    float4 u;
    u.x = sv.x + c1 * m1.x + c2 * m2.x + hvv.x;
    u.y = sv.y + c1 * m1.y + c2 * m2.y + hvv.y;
    u.z = sv.z + c1 * m1.z + c2 * m2.z + hvv.z;
    u.w = sv.w + c1 * m1.w + c2 * m2.w + hvv.w;

    float s1v = u.x + u.y + u.z + u.w;
    float s2v = u.x * u.x + u.y * u.y + u.z * u.z + u.w * u.w;
#pragma unroll
    for (int o = 1; o < 64; o <<= 1) { s1v += __shfl_xor(s1v, o); s2v += __shfl_xor(s2v, o); }
    float mu = s1v * (1.f / 256.f);
    float var = s2v * (1.f / 256.f) - mu * mu;
    float rstd = rsqrtf(var + 1e-5f);

    float4 y;
    y.x = (u.x - mu) * rstd * g4.x + b4.x;
    y.y = (u.y - mu) * rstd * g4.y + b4.y;
    y.z = (u.z - mu) * rstd * g4.z + b4.z;
    y.w = (u.w - mu) * rstd * g4.w + b4.w;
    y.x = fmaxf(y.x, 0.01f * y.x);
    y.y = fmaxf(y.y, 0.01f * y.y);
    y.z = fmaxf(y.z, 0.01f * y.z);
    y.w = fmaxf(y.w, 0.01f * y.w);
    *reinterpret_cast<float4*>(out + gb) = y;
  }
}

// ---- workspace layout (bytes); ~99 MB peak (< round-1-proven ~119 MB) ----
static constexpr size_t AL(size_t x) { return (x + 255) & ~size_t(255); }
// final messages (bf16), sized by DST rows, ushort offsets
static constexpr size_t ACCe_L2G = 0;
static constexpr size_t ACCe_G2L = ACCe_L2G + (size_t)NGr * DIM;
static constexpr size_t ACCe_G2D = ACCe_G2L + (size_t)NLr * DIM;
static constexpr size_t ACCe_D2G = ACCe_G2D + (size_t)NDr * DIM;
static constexpr size_t ACCe_L2D = ACCe_D2G + (size_t)NGr * DIM;
static constexpr size_t ACCe_D2L = ACCe_L2D + (size_t)NDr * DIM;
static constexpr size_t ACC_TOT  = ACCe_D2L + (size_t)NLr * DIM;
// hp buffer: reused by the two 3-relation groups; 57,344 rows (29.4 MB)
static constexpr size_t HP3_TOT  = (size_t)(NLr + NGr + NDr) * DIM;
static constexpr size_t OFF_ACC  = 0;
static constexpr size_t OFF_HP   = AL(OFF_ACC + ACC_TOT * 2);
static constexpr size_t OFF_WBF  = AL(OFF_HP + HP3_TOT * 2);
static constexpr size_t OFF_HIST = AL(OFF_WBF + 9 * 65536 * 2);
static constexpr size_t OFF_OFFS = AL(OFF_HIST + 6 * HSTRIDE * 4);
static constexpr size_t OFF_CURS = AL(OFF_OFFS + 6 * HSTRIDE * 4);
static constexpr size_t OFF_PART = AL(OFF_CURS + 6 * 32768 * 4);
static constexpr size_t OFF_BOFF = AL(OFF_PART + 48 * 4);
static constexpr size_t OFF_SRCW = AL(OFF_BOFF + 48 * 4);  // 6 * NE * 4B packed

extern "C" void kernel_launch(void* const* d_in, const int* in_sizes, int n_in,
                              void* d_out, int out_size, void* d_ws, size_t ws_size,
                              hipStream_t stream) {
  char* wsb = (char*)d_ws;
  unsigned short* acc = (unsigned short*)(wsb + OFF_ACC);
  unsigned short* hp  = (unsigned short*)(wsb + OFF_HP);
  unsigned short* wbf = (unsigned short*)(wsb + OFF_WBF);
  int* hist = (int*)(wsb + OFF_HIST);
  int* offs = (int*)(wsb + OFF_OFFS);
  int* curs = (int*)(wsb + OFF_CURS);
  int* part = (int*)(wsb + OFF_PART);
  int* boff = (int*)(wsb + OFF_BOFF);
  unsigned* srcw = (unsigned*)(wsb + OFF_SRCW);
  float* out = (float*)d_out;

  // relation order: l2g, g2l, g2d, d2g, l2d, d2l
  const int base[6] = {3, 8, 13, 18, 23, 28};
  const int hidx[6] = {0, 1, 1, 2, 0, 2};              // SOURCE type per relation
  const int nsrc[6] = {NLr, NGr, NGr, NDr, NLr, NDr};
  const int ndst[6] = {NGr, NLr, NDr, NGr, NDr, NLr};
  const size_t accOff[6] = {ACCe_L2G, ACCe_G2L, ACCe_G2D, ACCe_D2G, ACCe_L2D, ACCe_D2L};

  // weights -> bf16: slots 0..5 = W_rel, 6..8 = Wself_{l,g,d}
  WPtrs wp;
  wp.p[0] = (const float*)d_in[6];  wp.p[1] = (const float*)d_in[11];
  wp.p[2] = (const float*)d_in[16]; wp.p[3] = (const float*)d_in[21];
  wp.p[4] = (const float*)d_in[26]; wp.p[5] = (const float*)d_in[31];
  wp.p[6] = (const float*)d_in[33]; wp.p[7] = (const float*)d_in[36];
  wp.p[8] = (const float*)d_in[39];
  conv_w_kernel<<<dim3(256, 9), 256, 0, stream>>>(wp, wbf);

  // CSR build (fast multi-block scan, explicit cursor)
  (void)hipMemsetAsync(hist, 0, 6 * HSTRIDE * 4, stream);
  RelIdx R; NTab N; ETab Eb;
  for (int r = 0; r < 6; ++r) {
    R.dst[r] = (const int*)d_in[base[r] + 1];
    N.n[r] = ndst[r];
    Eb.src[r] = (const int*)d_in[base[r]];
    Eb.dst[r] = (const int*)d_in[base[r] + 1];
    Eb.w[r]  = (const float*)d_in[base[r] + 2];
  }
  hist6_kernel<<<dim3(NE / 256, 6), 256, 0, stream>>>(R, hist);
  scanA_kernel<<<dim3(8, 6), 256, 0, stream>>>(hist, part, N);
  scanTop_kernel<<<1, 64, 0, stream>>>(part, boff);
  scanC_kernel<<<dim3(8, 6), 256, 0, stream>>>(hist, boff, offs, curs, N);
  scatter6_kernel<<<dim3(NE / 256, 6), 256, 0, stream>>>(Eb, offs, curs, srcw);

  // two 3-relation groups sharing one hp buffer (ws cap)
  const int groups[2][3] = {{0, 1, 3}, {2, 4, 5}};
  for (int gidx = 0; gidx < 2; ++gidx) {
    const int* rel = groups[gidx];
    TTab3 T; GTab3 G;
    size_t hpo = 0;
    int cumT = 0, cumG = 0;
    for (int k = 0; k < 3; ++k) {
      int r = rel[k];
      T.h[k] = (const float*)d_in[hidx[r]];
      T.hp[k] = hp + hpo;
      T.w[k] = wbf + r * 65536;
      T.cum[k] = cumT;
      cumT += nsrc[r] / 64;
      G.hp[k] = hp + hpo;
      G.acc[k] = acc + accOff[r];
      G.sw[k] = srcw + (size_t)r * NE;
      G.of[k] = offs + r * HSTRIDE;
      G.cum[k] = cumG;
      cumG += ndst[r] / 4;
      hpo += (size_t)nsrc[r] * DIM;
    }
    T.cum[3] = cumT;
    G.cum[3] = cumG;
    transform3_kernel<<<cumT, 256, 0, stream>>>(T);
    gather3_kernel<<<cumG, 256, 0, stream>>>(G);
  }

  // type l: msgs [g2l, d2l]
  fuse_kernel<<<NLr / 64, 256, 0, stream>>>(
      (const float*)d_in[0], acc + ACCe_G2L, acc + ACCe_D2L, wbf + 6 * 65536,
      (const float*)d_in[12], (const float*)d_in[32],
      (const float*)d_in[34], (const float*)d_in[35], out);
  // type g: msgs [l2g, d2g]
  fuse_kernel<<<NGr / 64, 256, 0, stream>>>(
      (const float*)d_in[1], acc + ACCe_L2G, acc + ACCe_D2G, wbf + 7 * 65536,
      (const float*)d_in[7], (const float*)d_in[22],
      (const float*)d_in[37], (const float*)d_in[38], out + (size_t)NLr * DIM);
  // type d: msgs [g2d, l2d]
  fuse_kernel<<<NDr / 64, 256, 0, stream>>>(
      (const float*)d_in[2], acc + ACCe_G2D, acc + ACCe_L2D, wbf + 8 * 65536,
      (const float*)d_in[17], (const float*)d_in[27],
      (const float*)d_in[40], (const float*)d_in[41], out + (size_t)(NLr + NGr) * DIM);
}

// Round 9
// 370.101 us; speedup vs baseline: 1.1857x; 1.1404x over previous
//
#include <hip/hip_runtime.h>

#define DIM 256
#define NLr 16384
#define NGr 32768
#define NDr 8192
#define NE  262144
#define HSTRIDE 32772  // hist/offs per-relation stride (16B-aligned)

typedef short bf16x8 __attribute__((ext_vector_type(8)));
typedef float f32x4 __attribute__((ext_vector_type(4)));

__device__ __forceinline__ unsigned short f2bf(float f) {
  unsigned int u = __builtin_bit_cast(unsigned int, f);
  u += 0x7fffu + ((u >> 16) & 1u);
  return (unsigned short)(u >> 16);
}
__device__ __forceinline__ float bf2f(unsigned short b) {
  return __builtin_bit_cast(float, ((unsigned int)b) << 16);
}
__device__ __forceinline__ float bflo(unsigned int u) {
  return __builtin_bit_cast(float, u << 16);
}
__device__ __forceinline__ float bfhi(unsigned int u) {
  return __builtin_bit_cast(float, u & 0xffff0000u);
}

struct WPtrs { const float* p[9]; };
struct NTab { int n[6]; };
struct RelIdx { const int* dst[6]; };
struct PTab { const int* src[6]; const int* dst[6]; const float* w[6]; int shift[6]; };
struct TTab { const float* h[6]; unsigned short* hp[6]; int cum[7]; };
struct GTab { const unsigned short* hp[6]; unsigned short* acc[6];
              const unsigned* sw[6]; const int* of[6]; int cum[7]; };

// ---- convert 9 weight matrices (f32 -> bf16), 65536 elems each ----
__global__ __launch_bounds__(256) void conv_w_kernel(WPtrs wp, unsigned short* __restrict__ dst) {
  int m = blockIdx.y;
  int i = blockIdx.x * 256 + threadIdx.x;
  dst[m * 65536 + i] = f2bf(wp.p[m][i]);
}

// ---- CSR build: histogram over dst for all 6 relations ----
__global__ __launch_bounds__(256) void hist6_kernel(RelIdx R, int* __restrict__ hist) {
  int r = blockIdx.y;
  int e = blockIdx.x * 256 + threadIdx.x;
  atomicAdd(&hist[r * HSTRIDE + R.dst[r][e]], 1);
}

// ---- scan stage A: per-block partial sums (4096 bins / block) ----
__global__ __launch_bounds__(256) void scanA_kernel(const int* __restrict__ hist,
                                                    int* __restrict__ partials, NTab N) {
  int r = blockIdx.y, b = blockIdx.x;
  int n = N.n[r], base = b * 4096;
  int s = 0;
  if (base < n) {
    const int4* h4 = reinterpret_cast<const int4*>(hist + r * HSTRIDE + base);
#pragma unroll
    for (int k = 0; k < 4; ++k) {
      int4 v = h4[threadIdx.x * 4 + k];
      s += v.x + v.y + v.z + v.w;
    }
  }
#pragma unroll
  for (int o = 1; o < 64; o <<= 1) s += __shfl_xor(s, o);
  __shared__ int wsum[4];
  if ((threadIdx.x & 63) == 0) wsum[threadIdx.x >> 6] = s;
  __syncthreads();
  if (threadIdx.x == 0) partials[r * 8 + b] = wsum[0] + wsum[1] + wsum[2] + wsum[3];
}

// ---- scan stage B: tiny per-relation exclusive scan of 8 partials ----
__global__ void scanTop_kernel(const int* __restrict__ partials, int* __restrict__ boff) {
  int r = threadIdx.x;
  if (r < 6) {
    int off = 0;
    for (int b = 0; b < 8; ++b) { boff[r * 8 + b] = off; off += partials[r * 8 + b]; }
  }
}

// ---- scan stage C: block-local scan + write offs + offs[n]=NE ----
__global__ __launch_bounds__(256) void scanC_kernel(const int* __restrict__ hist,
                                                    const int* __restrict__ boff,
                                                    int* __restrict__ offs, NTab N) {
  int r = blockIdx.y, b = blockIdx.x;
  int n = N.n[r], base = b * 4096;
  if (b == 0 && threadIdx.x == 0) offs[r * HSTRIDE + n] = NE;
  if (base >= n) return;
  const int tid = threadIdx.x;
  int vals[16];
  int s = 0;
  const int4* h4 = reinterpret_cast<const int4*>(hist + r * HSTRIDE + base);
#pragma unroll
  for (int k = 0; k < 4; ++k) {
    int4 v = h4[tid * 4 + k];
    vals[4 * k] = v.x; vals[4 * k + 1] = v.y; vals[4 * k + 2] = v.z; vals[4 * k + 3] = v.w;
    s += v.x + v.y + v.z + v.w;
  }
  __shared__ int part[256];
  part[tid] = s;
  __syncthreads();
  for (int off = 1; off < 256; off <<= 1) {
    int v = (tid >= off) ? part[tid - off] : 0;
    __syncthreads();
    part[tid] += v;
    __syncthreads();
  }
  int run = part[tid] - s + boff[r * 8 + b];
  int gbase = base + tid * 16;
#pragma unroll
  for (int j = 0; j < 16; ++j) {
    offs[r * HSTRIDE + gbase + j] = run;
    run += vals[j];
  }
}

// ---- init coarse cursors: ccur[r][b] = offs[r][b * (n>>6)] ----
__global__ void ccur_init_kernel(const int* __restrict__ offs, int* __restrict__ ccur, NTab N) {
  int t = threadIdx.x;
  if (t < 384) {
    int r = t >> 6, b = t & 63;
    ccur[t] = offs[r * HSTRIDE + b * (N.n[r] >> 6)];
  }
}

// ---- partition pass A: coarse 64-bucket partition into tmp (dst, packed) ----
// block = 1024 edges; LDS hist -> one global atomic per touched bucket -> grouped writes
__global__ __launch_bounds__(256) void partA6_kernel(PTab P, int* __restrict__ ccur,
                                                     int2* __restrict__ tmp) {
  int r = blockIdx.y;
  const int tid = threadIdx.x;
  __shared__ int hist[64], lbase[64], lcur[64];
  if (tid < 64) { hist[tid] = 0; lcur[tid] = 0; }
  __syncthreads();
  const int ebase = blockIdx.x * 1024;
  const int sh = P.shift[r];
  int dsts[4]; unsigned pk[4]; int bks[4];
#pragma unroll
  for (int k = 0; k < 4; ++k) {
    int e = ebase + k * 256 + tid;
    int d = P.dst[r][e];
    dsts[k] = d;
    pk[k] = (unsigned)P.src[r][e] | ((unsigned)f2bf(P.w[r][e]) << 16);
    bks[k] = d >> sh;
    atomicAdd(&hist[bks[k]], 1);
  }
  __syncthreads();
  if (tid < 64) {
    int c = hist[tid];
    if (c) lbase[tid] = atomicAdd(&ccur[r * 64 + tid], c);
  }
  __syncthreads();
#pragma unroll
  for (int k = 0; k < 4; ++k) {
    int pos = lbase[bks[k]] + atomicAdd(&lcur[bks[k]], 1);
    tmp[(size_t)r * NE + pos] = make_int2(dsts[k], (int)pk[k]);
  }
}

// ---- partition pass B: exact placement with LDS cursors; block owns one window ----
__global__ __launch_bounds__(256) void partB6_kernel(const int2* __restrict__ tmp,
                                                     const int* __restrict__ offs,
                                                     unsigned* __restrict__ srcw, NTab N) {
  int r = blockIdx.y, b = blockIdx.x;
  const int n = N.n[r], s = n >> 6;
  const int tid = threadIdx.x;
  __shared__ int cur[512];
  const int dbase = b * s;
  for (int i = tid; i < s; i += 256) cur[i] = offs[r * HSTRIDE + dbase + i];
  __syncthreads();
  const int wbeg = offs[r * HSTRIDE + dbase];
  const int wend = offs[r * HSTRIDE + dbase + s];  // b==63 hits offs[n]==NE
  for (int i = wbeg + tid; i < wend; i += 256) {
    int2 e = tmp[(size_t)r * NE + i];
    int pos = atomicAdd(&cur[e.x - dbase], 1);
    srcw[(size_t)r * NE + pos] = (unsigned)e.y;
  }
}

// ---- gather: msg[node] = (sum w_e * hp[src_e]) / deg (round-8 proven body) ----
__global__ __launch_bounds__(256) void gather6_kernel(GTab T) {
  const int bx = blockIdx.x;
  int r = 0;
#pragma unroll
  for (int k = 1; k < 6; ++k) r += (bx >= T.cum[k]);
  const int node = (bx - T.cum[r]) * 4 + (threadIdx.x >> 6);
  const int lane = threadIdx.x & 63;
  const int half = lane >> 5;
  const int c8 = lane & 31;
  const int* of = T.of[r];
  const int beg = of[node], end = of[node + 1];
  const uint4* __restrict__ hv = reinterpret_cast<const uint4*>(T.hp[r]);
  const unsigned* __restrict__ sw = T.sw[r];
  float a0 = 0.f, a1 = 0.f, a2 = 0.f, a3 = 0.f, a4 = 0.f, a5 = 0.f, a6 = 0.f, a7 = 0.f;
  float degw = 0.f;
  for (int j = beg; j < end; j += 4) {
    int i0 = j + half * 2, i1 = i0 + 1;
    unsigned e0 = (i0 < end) ? sw[i0] : 0u;
    unsigned e1 = (i1 < end) ? sw[i1] : 0u;
    float w0 = bfhi(e0), w1 = bfhi(e1);
    int s0 = e0 & 0xffff, s1 = e1 & 0xffff;
    uint4 x0 = hv[(size_t)s0 * 32 + c8];
    uint4 x1 = hv[(size_t)s1 * 32 + c8];
    degw += w0 + w1;
    a0 += w0 * bflo(x0.x) + w1 * bflo(x1.x);
    a1 += w0 * bfhi(x0.x) + w1 * bfhi(x1.x);
    a2 += w0 * bflo(x0.y) + w1 * bflo(x1.y);
    a3 += w0 * bfhi(x0.y) + w1 * bfhi(x1.y);
    a4 += w0 * bflo(x0.z) + w1 * bflo(x1.z);
    a5 += w0 * bfhi(x0.z) + w1 * bfhi(x1.z);
    a6 += w0 * bflo(x0.w) + w1 * bflo(x1.w);
    a7 += w0 * bfhi(x0.w) + w1 * bfhi(x1.w);
  }
  a0 += __shfl_xor(a0, 32); a1 += __shfl_xor(a1, 32);
  a2 += __shfl_xor(a2, 32); a3 += __shfl_xor(a3, 32);
  a4 += __shfl_xor(a4, 32); a5 += __shfl_xor(a5, 32);
  a6 += __shfl_xor(a6, 32); a7 += __shfl_xor(a7, 32);
  degw += __shfl_xor(degw, 32);
  float inv = (degw == 0.f) ? 1.f : 1.f / degw;
  if (half == 0) {
    uint4 o;
    o.x = (unsigned)f2bf(a0 * inv) | ((unsigned)f2bf(a1 * inv) << 16);
    o.y = (unsigned)f2bf(a2 * inv) | ((unsigned)f2bf(a3 * inv) << 16);
    o.z = (unsigned)f2bf(a4 * inv) | ((unsigned)f2bf(a5 * inv) << 16);
    o.w = (unsigned)f2bf(a6 * inv) | ((unsigned)f2bf(a7 * inv) << 16);
    reinterpret_cast<uint4*>(T.acc[r])[(size_t)node * 32 + c8] = o;
  }
}

// ---- shared GEMM pieces: 64 rows x (256x256) bf16 MFMA (round-6/7/8 proven) ----
__device__ __forceinline__ void stage_x_f32(const float* __restrict__ g, int r0,
                                            unsigned short* xs, int tid) {
#pragma unroll
  for (int it = 0; it < 16; ++it) {
    int i = it * 256 + tid;
    int row = i >> 6, q = i & 63;
    float4 v = reinterpret_cast<const float4*>(g)[(size_t)(r0 + row) * 64 + q];
    ushort4 b;
    b.x = f2bf(v.x); b.y = f2bf(v.y); b.z = f2bf(v.z); b.w = f2bf(v.w);
    *reinterpret_cast<ushort4*>(&xs[row * 264 + q * 4]) = b;
  }
}

__device__ __forceinline__ void gemm_frag(const unsigned short* xs,
                                          const unsigned short* __restrict__ Wg,
                                          unsigned short* wl, int tid,
                                          f32x4 accv[4][4]) {
  const int wid = tid >> 6, lhi = (tid & 63) >> 4, llo = tid & 15;
  for (int ks = 0; ks < 8; ++ks) {
    const int k0 = ks * 32;
    __syncthreads();  // protects xs (first iter) and wl reads from prev iter
    {
      const uint4* gp = reinterpret_cast<const uint4*>(Wg + (size_t)tid * 256 + k0);
      uint4 a0 = gp[0], a1 = gp[1], a2 = gp[2], a3 = gp[3];
      uint4* lp = reinterpret_cast<uint4*>(wl + tid * 56);
      lp[0] = a0; lp[1] = a1; lp[2] = a2; lp[3] = a3;
    }
    __syncthreads();
    bf16x8 afr[4], bfr[4];
#pragma unroll
    for (int rt = 0; rt < 4; ++rt)
      afr[rt] = *reinterpret_cast<const bf16x8*>(&xs[(rt * 16 + llo) * 264 + k0 + lhi * 8]);
#pragma unroll
    for (int nt = 0; nt < 4; ++nt)
      bfr[nt] = *reinterpret_cast<const bf16x8*>(&wl[(wid * 64 + nt * 16 + llo) * 56 + lhi * 8]);
#pragma unroll
    for (int rt = 0; rt < 4; ++rt)
#pragma unroll
      for (int nt = 0; nt < 4; ++nt)
        accv[rt][nt] = __builtin_amdgcn_mfma_f32_16x16x32_bf16(afr[rt], bfr[nt], accv[rt][nt], 0, 0, 0);
  }
}

// ---- pre-transform (all 6 relations): hp = h_src @ W_rel.T, bf16 ----
__global__ __launch_bounds__(256) void transform6_kernel(TTab T, const unsigned short* __restrict__ wbf) {
  __shared__ alignas(16) unsigned short xs[64 * 264];
  __shared__ alignas(16) unsigned short wl[256 * 56];
  const int tid = threadIdx.x;
  const int bx = blockIdx.x;
  int r = 0;
#pragma unroll
  for (int k = 1; k < 6; ++k) r += (bx >= T.cum[k]);
  const int r0 = (bx - T.cum[r]) * 64;
  unsigned short* hp = T.hp[r];

  stage_x_f32(T.h[r], r0, xs, tid);

  f32x4 accv[4][4];
#pragma unroll
  for (int a = 0; a < 4; ++a)
#pragma unroll
    for (int b = 0; b < 4; ++b) accv[a][b] = {0.f, 0.f, 0.f, 0.f};

  gemm_frag(xs, wbf + r * 65536, wl, tid, accv);

  const int wid = tid >> 6, lane = tid & 63, lhi = lane >> 4, llo = lane & 15;
#pragma unroll
  for (int rt = 0; rt < 4; ++rt)
#pragma unroll
    for (int nt = 0; nt < 4; ++nt) {
      int col = wid * 64 + nt * 16 + llo;
#pragma unroll
      for (int rg = 0; rg < 4; ++rg) {
        int row = rt * 16 + lhi * 4 + rg;
        hp[(size_t)(r0 + row) * DIM + col] = f2bf(accv[rt][nt][rg]);
      }
    }
}

// ---- per node type: self-GEMM + relation attention + residual + LN + leaky ----
__global__ __launch_bounds__(256) void fuse_kernel(
    const float* __restrict__ h, const unsigned short* __restrict__ msg1,
    const unsigned short* __restrict__ msg2, const unsigned short* __restrict__ Wbf,
    const float* __restrict__ A1, const float* __restrict__ A2,
    const float* __restrict__ gamma, const float* __restrict__ beta,
    float* __restrict__ out) {
  __shared__ alignas(16) union SM {
    struct { unsigned short x[64 * 264]; unsigned short w[256 * 56]; } g;
    unsigned short s[64 * 260];  // self result, bf16
  } ov;
  __shared__ float sgb[512];
  const int tid = threadIdx.x;
  const int r0 = blockIdx.x * 64;

  stage_x_f32(h, r0, ov.g.x, tid);
  for (int i = tid; i < 512; i += 256) sgb[i] = (i < 256) ? gamma[i] : beta[i - 256];

  f32x4 accv[4][4];
#pragma unroll
  for (int a = 0; a < 4; ++a)
#pragma unroll
    for (int b = 0; b < 4; ++b) accv[a][b] = {0.f, 0.f, 0.f, 0.f};

  gemm_frag(ov.g.x, Wbf, ov.g.w, tid, accv);

  const int wid = tid >> 6, lane = tid & 63, lhi = lane >> 4, llo = lane & 15;
  __syncthreads();  // all MFMA LDS reads done before overlaying ov.s
#pragma unroll
  for (int rt = 0; rt < 4; ++rt)
#pragma unroll
    for (int nt = 0; nt < 4; ++nt) {
      int col = wid * 64 + nt * 16 + llo;
#pragma unroll
      for (int rg = 0; rg < 4; ++rg)
        ov.s[(rt * 16 + lhi * 4 + rg) * 260 + col] = f2bf(accv[rt][nt][rg]);
    }
  __syncthreads();

  // epilogue: wave handles 16 rows; lane owns 4 dims
  const int d0 = lane * 4;
  const float4* A1v = reinterpret_cast<const float4*>(A1);
  const float4* A2v = reinterpret_cast<const float4*>(A2);
  float4 a1f[4], a2f[4];
#pragma unroll
  for (int hh = 0; hh < 4; ++hh) { a1f[hh] = A1v[hh * 64 + lane]; a2f[hh] = A2v[hh * 64 + lane]; }
  const float4 g4 = *reinterpret_cast<const float4*>(&sgb[d0]);
  const float4 b4 = *reinterpret_cast<const float4*>(&sgb[256 + d0]);

  for (int rl = 0; rl < 16; ++rl) {
    int row = wid * 16 + rl;
    size_t gb = (size_t)(r0 + row) * DIM + d0;
    ushort4 m1b = *reinterpret_cast<const ushort4*>(msg1 + gb);
    ushort4 m2b = *reinterpret_cast<const ushort4*>(msg2 + gb);
    float4 m1 = {bf2f(m1b.x), bf2f(m1b.y), bf2f(m1b.z), bf2f(m1b.w)};
    float4 m2 = {bf2f(m2b.x), bf2f(m2b.y), bf2f(m2b.z), bf2f(m2b.w)};
    float4 hvv = *reinterpret_cast<const float4*>(h + gb);
    ushort4 sb = *reinterpret_cast<const ushort4*>(&ov.s[row * 260 + d0]);
    float4 sv = {bf2f(sb.x), bf2f(sb.y), bf2f(sb.z), bf2f(sb.w)};

    float sc[8];
#pragma unroll
    for (int hh = 0; hh < 4; ++hh) {
      sc[hh]     = m1.x * a1f[hh].x + m1.y * a1f[hh].y + m1.z * a1f[hh].z + m1.w * a1f[hh].w;
      sc[4 + hh] = m2.x * a2f[hh].x + m2.y * a2f[hh].y + m2.z * a2f[hh].z + m2.w * a2f[hh].w;
    }
#pragma unroll
    for (int o = 1; o < 64; o <<= 1) {
#pragma unroll
      for (int j = 0; j < 8; ++j) sc[j] += __shfl_xor(sc[j], o);
    }
    // softmax over the 2 relations per head; scale = 1/(sqrt(256)*0.5) = 0.125
    float c1 = 0.f, c2 = 0.f;
#pragma unroll
    for (int hh = 0; hh < 4; ++hh) {
      float s1 = sc[hh] * 0.125f, s2 = sc[4 + hh] * 0.125f;
      float mx = fmaxf(s1, s2);
      float e1 = __expf(s1 - mx), e2 = __expf(s2 - mx);
      float inv = 1.f / (e1 + e2);
      c1 += e1 * inv; c2 += e2 * inv;
    }
    c1 *= 0.25f; c2 *= 0.25f;  // mean over H=4 heads

    float4 u;
    u.x = sv.x + c1 * m1.x + c2 * m2.x + hvv.x;
    u.y = sv.y + c1 * m1.y + c2 * m2.y + hvv.y;
    u.z = sv.z + c1 * m1.z + c2 * m2.z + hvv.z;
    u.w = sv.w + c1 * m1.w + c2 * m2.w + hvv.w;

    float s1v = u.x + u.y + u.z + u.w;
    float s2v = u.x * u.x + u.y * u.y + u.z * u.z + u.w * u.w;
#pragma unroll
    for (int o = 1; o < 64; o <<= 1) { s1v += __shfl_xor(s1v, o); s2v += __shfl_xor(s2v, o); }
    float mu = s1v * (1.f / 256.f);
    float var = s2v * (1.f / 256.f) - mu * mu;
    float rstd = rsqrtf(var + 1e-5f);

    float4 y;
    y.x = (u.x - mu) * rstd * g4.x + b4.x;
    y.y = (u.y - mu) * rstd * g4.y + b4.y;
    y.z = (u.z - mu) * rstd * g4.z + b4.z;
    y.w = (u.w - mu) * rstd * g4.w + b4.w;
    y.x = fmaxf(y.x, 0.01f * y.x);
    y.y = fmaxf(y.y, 0.01f * y.y);
    y.z = fmaxf(y.z, 0.01f * y.z);
    y.w = fmaxf(y.w, 0.01f * y.w);
    *reinterpret_cast<float4*>(out + gb) = y;
  }
}

// ---- workspace layout (bytes); ~110 MB peak (< round-1-proven ~119 MB) ----
static constexpr size_t AL(size_t x) { return (x + 255) & ~size_t(255); }
// final messages (bf16), sized by DST rows
static constexpr size_t ACCe_L2G = 0;
static constexpr size_t ACCe_G2L = ACCe_L2G + (size_t)NGr * DIM;
static constexpr size_t ACCe_G2D = ACCe_G2L + (size_t)NLr * DIM;
static constexpr size_t ACCe_D2G = ACCe_G2D + (size_t)NDr * DIM;
static constexpr size_t ACCe_L2D = ACCe_D2G + (size_t)NGr * DIM;
static constexpr size_t ACCe_D2L = ACCe_L2D + (size_t)NDr * DIM;
static constexpr size_t ACC_TOT  = ACCe_D2L + (size_t)NLr * DIM;
// transformed embeddings, all 6 relations, sized by SRC rows
static constexpr size_t HPe_L2G = 0;                                  // NLr
static constexpr size_t HPe_G2L = HPe_L2G + (size_t)NLr * DIM;        // NGr
static constexpr size_t HPe_G2D = HPe_G2L + (size_t)NGr * DIM;        // NGr
static constexpr size_t HPe_D2G = HPe_G2D + (size_t)NGr * DIM;        // NDr
static constexpr size_t HPe_L2D = HPe_D2G + (size_t)NDr * DIM;        // NLr
static constexpr size_t HPe_D2L = HPe_L2D + (size_t)NLr * DIM;        // NDr
static constexpr size_t HP_TOT  = HPe_D2L + (size_t)NDr * DIM;
static constexpr size_t OFF_ACC  = 0;
static constexpr size_t OFF_HP   = AL(OFF_ACC + ACC_TOT * 2);
static constexpr size_t OFF_WBF  = AL(OFF_HP + HP_TOT * 2);
static constexpr size_t OFF_HIST = AL(OFF_WBF + 9 * 65536 * 2);
static constexpr size_t OFF_OFFS = AL(OFF_HIST + 6 * HSTRIDE * 4);
static constexpr size_t OFF_PART = AL(OFF_OFFS + 6 * HSTRIDE * 4);
static constexpr size_t OFF_BOFF = AL(OFF_PART + 48 * 4);
static constexpr size_t OFF_CCUR = AL(OFF_BOFF + 48 * 4);
static constexpr size_t OFF_TMP  = AL(OFF_CCUR + 384 * 4);            // 6*NE int2
static constexpr size_t OFF_SRCW = AL(OFF_TMP + (size_t)6 * NE * 8);  // 6*NE u32

extern "C" void kernel_launch(void* const* d_in, const int* in_sizes, int n_in,
                              void* d_out, int out_size, void* d_ws, size_t ws_size,
                              hipStream_t stream) {
  char* wsb = (char*)d_ws;
  unsigned short* acc = (unsigned short*)(wsb + OFF_ACC);
  unsigned short* hp  = (unsigned short*)(wsb + OFF_HP);
  unsigned short* wbf = (unsigned short*)(wsb + OFF_WBF);
  int* hist = (int*)(wsb + OFF_HIST);
  int* offs = (int*)(wsb + OFF_OFFS);
  int* part = (int*)(wsb + OFF_PART);
  int* boff = (int*)(wsb + OFF_BOFF);
  int* ccur = (int*)(wsb + OFF_CCUR);
  int2* tmp = (int2*)(wsb + OFF_TMP);
  unsigned* srcw = (unsigned*)(wsb + OFF_SRCW);
  float* out = (float*)d_out;

  // relation order: l2g, g2l, g2d, d2g, l2d, d2l
  const int base[6] = {3, 8, 13, 18, 23, 28};
  const int hidx[6] = {0, 1, 1, 2, 0, 2};              // SOURCE type per relation
  const int nsrc[6] = {NLr, NGr, NGr, NDr, NLr, NDr};
  const int ndst[6] = {NGr, NLr, NDr, NGr, NDr, NLr};
  const size_t accOff[6] = {ACCe_L2G, ACCe_G2L, ACCe_G2D, ACCe_D2G, ACCe_L2D, ACCe_D2L};
  const size_t hpOff[6]  = {HPe_L2G, HPe_G2L, HPe_G2D, HPe_D2G, HPe_L2D, HPe_D2L};

  // weights -> bf16: slots 0..5 = W_rel, 6..8 = Wself_{l,g,d}
  WPtrs wp;
  wp.p[0] = (const float*)d_in[6];  wp.p[1] = (const float*)d_in[11];
  wp.p[2] = (const float*)d_in[16]; wp.p[3] = (const float*)d_in[21];
  wp.p[4] = (const float*)d_in[26]; wp.p[5] = (const float*)d_in[31];
  wp.p[6] = (const float*)d_in[33]; wp.p[7] = (const float*)d_in[36];
  wp.p[8] = (const float*)d_in[39];
  conv_w_kernel<<<dim3(256, 9), 256, 0, stream>>>(wp, wbf);

  // CSR build: hist + fast scan
  (void)hipMemsetAsync(hist, 0, 6 * HSTRIDE * 4, stream);
  RelIdx R; NTab N; PTab P;
  for (int r = 0; r < 6; ++r) {
    R.dst[r] = (const int*)d_in[base[r] + 1];
    N.n[r] = ndst[r];
    P.src[r] = (const int*)d_in[base[r]];
    P.dst[r] = (const int*)d_in[base[r] + 1];
    P.w[r]  = (const float*)d_in[base[r] + 2];
    P.shift[r] = (ndst[r] == NGr) ? 9 : (ndst[r] == NLr ? 8 : 7);  // n>>6 window
  }
  hist6_kernel<<<dim3(NE / 256, 6), 256, 0, stream>>>(R, hist);
  scanA_kernel<<<dim3(8, 6), 256, 0, stream>>>(hist, part, N);
  scanTop_kernel<<<1, 64, 0, stream>>>(part, boff);
  scanC_kernel<<<dim3(8, 6), 256, 0, stream>>>(hist, boff, offs, N);

  // two-pass radix partition (write-amp ~1)
  ccur_init_kernel<<<1, 384, 0, stream>>>(offs, ccur, N);
  partA6_kernel<<<dim3(NE / 1024, 6), 256, 0, stream>>>(P, ccur, tmp);
  partB6_kernel<<<dim3(64, 6), 256, 0, stream>>>(tmp, offs, srcw, N);

  // pre-transform all 6 relations: hp_rel = h_src @ W_rel.T
  TTab T;
  int cumT = 0;
  for (int r = 0; r < 6; ++r) {
    T.h[r] = (const float*)d_in[hidx[r]];
    T.hp[r] = hp + hpOff[r];
    T.cum[r] = cumT;
    cumT += nsrc[r] / 64;
  }
  T.cum[6] = cumT;
  transform6_kernel<<<cumT, 256, 0, stream>>>(T, wbf);

  // gather all 6 relations -> final bf16 messages
  GTab G;
  int cumG = 0;
  for (int r = 0; r < 6; ++r) {
    G.hp[r] = hp + hpOff[r];
    G.acc[r] = acc + accOff[r];
    G.sw[r] = srcw + (size_t)r * NE;
    G.of[r] = offs + r * HSTRIDE;
    G.cum[r] = cumG;
    cumG += ndst[r] / 4;
  }
  G.cum[6] = cumG;
  gather6_kernel<<<cumG, 256, 0, stream>>>(G);

  // type l: msgs [g2l, d2l]
  fuse_kernel<<<NLr / 64, 256, 0, stream>>>(
      (const float*)d_in[0], acc + ACCe_G2L, acc + ACCe_D2L, wbf + 6 * 65536,
      (const float*)d_in[12], (const float*)d_in[32],
      (const float*)d_in[34], (const float*)d_in[35], out);
  // type g: msgs [l2g, d2g]
  fuse_kernel<<<NGr / 64, 256, 0, stream>>>(
      (const float*)d_in[1], acc + ACCe_L2G, acc + ACCe_D2G, wbf + 7 * 65536,
      (const float*)d_in[7], (const float*)d_in[22],
      (const float*)d_in[37], (const float*)d_in[38], out + (size_t)NLr * DIM);
  // type d: msgs [g2d, l2d]
  fuse_kernel<<<NDr / 64, 256, 0, stream>>>(
      (const float*)d_in[2], acc + ACCe_G2D, acc + ACCe_L2D, wbf + 8 * 65536,
      (const float*)d_in[17], (const float*)d_in[27],
      (const float*)d_in[40], (const float*)d_in[41], out + (size_t)(NLr + NGr) * DIM);
}

// Round 10
// 369.742 us; speedup vs baseline: 1.1868x; 1.0010x over previous
//
#include <hip/hip_runtime.h>

#define DIM 256
#define NLr 16384
#define NGr 32768
#define NDr 8192
#define NE  262144
#define HSTRIDE 32772  // hist/offs per-relation stride (16B-aligned)

typedef short bf16x8 __attribute__((ext_vector_type(8)));
typedef float f32x4 __attribute__((ext_vector_type(4)));
typedef unsigned u32x4 __attribute__((ext_vector_type(4)));

__device__ __forceinline__ unsigned short f2bf(float f) {
  unsigned int u = __builtin_bit_cast(unsigned int, f);
  u += 0x7fffu + ((u >> 16) & 1u);
  return (unsigned short)(u >> 16);
}
__device__ __forceinline__ float bf2f(unsigned short b) {
  return __builtin_bit_cast(float, ((unsigned int)b) << 16);
}
__device__ __forceinline__ float bflo(unsigned int u) {
  return __builtin_bit_cast(float, u << 16);
}
__device__ __forceinline__ float bfhi(unsigned int u) {
  return __builtin_bit_cast(float, u & 0xffff0000u);
}

struct WPtrs { const float* p[9]; };
struct NTab { int n[6]; };
struct RelIdx { const int* dst[6]; };
struct PTab { const int* src[6]; const int* dst[6]; const float* w[6]; int shift[6]; };
struct TTy { const float* h[3]; unsigned short* hpA[3]; unsigned short* hpB[3];
             const unsigned short* wA[3]; const unsigned short* wB[3]; int cum[4]; };
struct GTab { const unsigned short* hp[6]; unsigned short* acc[6];
              const unsigned* sw[6]; const int* of[6]; int cum[7]; };

// ---- convert 9 weight matrices (f32 -> bf16), 65536 elems each ----
__global__ __launch_bounds__(256) void conv_w_kernel(WPtrs wp, unsigned short* __restrict__ dst) {
  int m = blockIdx.y;
  int i = blockIdx.x * 256 + threadIdx.x;
  dst[m * 65536 + i] = f2bf(wp.p[m][i]);
}

// ---- CSR build: histogram over dst for all 6 relations ----
__global__ __launch_bounds__(256) void hist6_kernel(RelIdx R, int* __restrict__ hist) {
  int r = blockIdx.y;
  int e = blockIdx.x * 256 + threadIdx.x;
  atomicAdd(&hist[r * HSTRIDE + R.dst[r][e]], 1);
}

// ---- scan stage A: per-block partial sums (4096 bins / block) ----
__global__ __launch_bounds__(256) void scanA_kernel(const int* __restrict__ hist,
                                                    int* __restrict__ partials, NTab N) {
  int r = blockIdx.y, b = blockIdx.x;
  int n = N.n[r], base = b * 4096;
  int s = 0;
  if (base < n) {
    const int4* h4 = reinterpret_cast<const int4*>(hist + r * HSTRIDE + base);
#pragma unroll
    for (int k = 0; k < 4; ++k) {
      int4 v = h4[threadIdx.x * 4 + k];
      s += v.x + v.y + v.z + v.w;
    }
  }
#pragma unroll
  for (int o = 1; o < 64; o <<= 1) s += __shfl_xor(s, o);
  __shared__ int wsum[4];
  if ((threadIdx.x & 63) == 0) wsum[threadIdx.x >> 6] = s;
  __syncthreads();
  if (threadIdx.x == 0) partials[r * 8 + b] = wsum[0] + wsum[1] + wsum[2] + wsum[3];
}

// ---- scan stage B: tiny per-relation exclusive scan of 8 partials ----
__global__ void scanTop_kernel(const int* __restrict__ partials, int* __restrict__ boff) {
  int r = threadIdx.x;
  if (r < 6) {
    int off = 0;
    for (int b = 0; b < 8; ++b) { boff[r * 8 + b] = off; off += partials[r * 8 + b]; }
  }
}

// ---- scan stage C: block-local scan + write offs + offs[n]=NE ----
__global__ __launch_bounds__(256) void scanC_kernel(const int* __restrict__ hist,
                                                    const int* __restrict__ boff,
                                                    int* __restrict__ offs, NTab N) {
  int r = blockIdx.y, b = blockIdx.x;
  int n = N.n[r], base = b * 4096;
  if (b == 0 && threadIdx.x == 0) offs[r * HSTRIDE + n] = NE;
  if (base >= n) return;
  const int tid = threadIdx.x;
  int vals[16];
  int s = 0;
  const int4* h4 = reinterpret_cast<const int4*>(hist + r * HSTRIDE + base);
#pragma unroll
  for (int k = 0; k < 4; ++k) {
    int4 v = h4[tid * 4 + k];
    vals[4 * k] = v.x; vals[4 * k + 1] = v.y; vals[4 * k + 2] = v.z; vals[4 * k + 3] = v.w;
    s += v.x + v.y + v.z + v.w;
  }
  __shared__ int part[256];
  part[tid] = s;
  __syncthreads();
  for (int off = 1; off < 256; off <<= 1) {
    int v = (tid >= off) ? part[tid - off] : 0;
    __syncthreads();
    part[tid] += v;
    __syncthreads();
  }
  int run = part[tid] - s + boff[r * 8 + b];
  int gbase = base + tid * 16;
#pragma unroll
  for (int j = 0; j < 16; ++j) {
    offs[r * HSTRIDE + gbase + j] = run;
    run += vals[j];
  }
}

// ---- init coarse cursors: ccur[r][b] = offs[r][b * (n>>6)] ----
__global__ void ccur_init_kernel(const int* __restrict__ offs, int* __restrict__ ccur, NTab N) {
  int t = threadIdx.x;
  if (t < 384) {
    int r = t >> 6, b = t & 63;
    ccur[t] = offs[r * HSTRIDE + b * (N.n[r] >> 6)];
  }
}

// ---- partition pass A: coarse 64-bucket partition into tmp (dst, packed) ----
__global__ __launch_bounds__(256) void partA6_kernel(PTab P, int* __restrict__ ccur,
                                                     int2* __restrict__ tmp) {
  int r = blockIdx.y;
  const int tid = threadIdx.x;
  __shared__ int hist[64], lbase[64], lcur[64];
  if (tid < 64) { hist[tid] = 0; lcur[tid] = 0; }
  __syncthreads();
  const int ebase = blockIdx.x * 1024;
  const int sh = P.shift[r];
  int dsts[4]; unsigned pk[4]; int bks[4];
#pragma unroll
  for (int k = 0; k < 4; ++k) {
    int e = ebase + k * 256 + tid;
    int d = P.dst[r][e];
    dsts[k] = d;
    pk[k] = (unsigned)P.src[r][e] | ((unsigned)f2bf(P.w[r][e]) << 16);
    bks[k] = d >> sh;
    atomicAdd(&hist[bks[k]], 1);
  }
  __syncthreads();
  if (tid < 64) {
    int c = hist[tid];
    if (c) lbase[tid] = atomicAdd(&ccur[r * 64 + tid], c);
  }
  __syncthreads();
#pragma unroll
  for (int k = 0; k < 4; ++k) {
    int pos = lbase[bks[k]] + atomicAdd(&lcur[bks[k]], 1);
    tmp[(size_t)r * NE + pos] = make_int2(dsts[k], (int)pk[k]);
  }
}

// ---- partition pass B: exact placement with LDS cursors; block owns one window ----
__global__ __launch_bounds__(256) void partB6_kernel(const int2* __restrict__ tmp,
                                                     const int* __restrict__ offs,
                                                     unsigned* __restrict__ srcw, NTab N) {
  int r = blockIdx.y, b = blockIdx.x;
  const int n = N.n[r], s = n >> 6;
  const int tid = threadIdx.x;
  __shared__ int cur[512];
  const int dbase = b * s;
  for (int i = tid; i < s; i += 256) cur[i] = offs[r * HSTRIDE + dbase + i];
  __syncthreads();
  const int wbeg = offs[r * HSTRIDE + dbase];
  const int wend = offs[r * HSTRIDE + dbase + s];  // b==63 hits offs[n]==NE
  for (int i = wbeg + tid; i < wend; i += 256) {
    int2 e = tmp[(size_t)r * NE + i];
    int pos = atomicAdd(&cur[e.x - dbase], 1);
    srcw[(size_t)r * NE + pos] = (unsigned)e.y;
  }
}

// ---- gather: msg[node] = (sum w_e * hp[src_e]) / deg ----
// one wave per node; half-wave handles 4 edges per iter (8/iter/wave);
// lane loads uint4 (8 dims); cross-half shfl_xor(32) combine; nontemporal out.
__global__ __launch_bounds__(256) void gather6_kernel(GTab T) {
  const int bx = blockIdx.x;
  int r = 0;
#pragma unroll
  for (int k = 1; k < 6; ++k) r += (bx >= T.cum[k]);
  const int node = (bx - T.cum[r]) * 4 + (threadIdx.x >> 6);
  const int lane = threadIdx.x & 63;
  const int half = lane >> 5;
  const int c8 = lane & 31;
  const int* of = T.of[r];
  const int beg = of[node], end = of[node + 1];
  const uint4* __restrict__ hv = reinterpret_cast<const uint4*>(T.hp[r]);
  const unsigned* __restrict__ sw = T.sw[r];
  float a0 = 0.f, a1 = 0.f, a2 = 0.f, a3 = 0.f, a4 = 0.f, a5 = 0.f, a6 = 0.f, a7 = 0.f;
  float degw = 0.f;
  for (int j = beg; j < end; j += 8) {
    int ib = j + half * 4;
    unsigned e0 = (ib + 0 < end) ? sw[ib + 0] : 0u;
    unsigned e1 = (ib + 1 < end) ? sw[ib + 1] : 0u;
    unsigned e2 = (ib + 2 < end) ? sw[ib + 2] : 0u;
    unsigned e3 = (ib + 3 < end) ? sw[ib + 3] : 0u;
    float w0 = bfhi(e0), w1 = bfhi(e1), w2 = bfhi(e2), w3 = bfhi(e3);
    int s0 = e0 & 0xffff, s1 = e1 & 0xffff, s2 = e2 & 0xffff, s3 = e3 & 0xffff;
    uint4 x0 = hv[(size_t)s0 * 32 + c8];
    uint4 x1 = hv[(size_t)s1 * 32 + c8];
    uint4 x2 = hv[(size_t)s2 * 32 + c8];
    uint4 x3 = hv[(size_t)s3 * 32 + c8];
    degw += (w0 + w1) + (w2 + w3);
    a0 += w0 * bflo(x0.x) + w1 * bflo(x1.x) + w2 * bflo(x2.x) + w3 * bflo(x3.x);
    a1 += w0 * bfhi(x0.x) + w1 * bfhi(x1.x) + w2 * bfhi(x2.x) + w3 * bfhi(x3.x);
    a2 += w0 * bflo(x0.y) + w1 * bflo(x1.y) + w2 * bflo(x2.y) + w3 * bflo(x3.y);
    a3 += w0 * bfhi(x0.y) + w1 * bfhi(x1.y) + w2 * bfhi(x2.y) + w3 * bfhi(x3.y);
    a4 += w0 * bflo(x0.z) + w1 * bflo(x1.z) + w2 * bflo(x2.z) + w3 * bflo(x3.z);
    a5 += w0 * bfhi(x0.z) + w1 * bfhi(x1.z) + w2 * bfhi(x2.z) + w3 * bfhi(x3.z);
    a6 += w0 * bflo(x0.w) + w1 * bflo(x1.w) + w2 * bflo(x2.w) + w3 * bflo(x3.w);
    a7 += w0 * bfhi(x0.w) + w1 * bfhi(x1.w) + w2 * bfhi(x2.w) + w3 * bfhi(x3.w);
  }
  a0 += __shfl_xor(a0, 32); a1 += __shfl_xor(a1, 32);
  a2 += __shfl_xor(a2, 32); a3 += __shfl_xor(a3, 32);
  a4 += __shfl_xor(a4, 32); a5 += __shfl_xor(a5, 32);
  a6 += __shfl_xor(a6, 32); a7 += __shfl_xor(a7, 32);
  degw += __shfl_xor(degw, 32);
  float inv = (degw == 0.f) ? 1.f : 1.f / degw;
  if (half == 0) {
    u32x4 o;
    o.x = (unsigned)f2bf(a0 * inv) | ((unsigned)f2bf(a1 * inv) << 16);
    o.y = (unsigned)f2bf(a2 * inv) | ((unsigned)f2bf(a3 * inv) << 16);
    o.z = (unsigned)f2bf(a4 * inv) | ((unsigned)f2bf(a5 * inv) << 16);
    o.w = (unsigned)f2bf(a6 * inv) | ((unsigned)f2bf(a7 * inv) << 16);
    __builtin_nontemporal_store(o, reinterpret_cast<u32x4*>(T.acc[r]) + (size_t)node * 32 + c8);
  }
}

// ---- shared GEMM pieces: 64 rows x (256x256) bf16 MFMA (rounds 6-9 proven) ----
__device__ __forceinline__ void stage_x_f32(const float* __restrict__ g, int r0,
                                            unsigned short* xs, int tid) {
#pragma unroll
  for (int it = 0; it < 16; ++it) {
    int i = it * 256 + tid;
    int row = i >> 6, q = i & 63;
    float4 v = reinterpret_cast<const float4*>(g)[(size_t)(r0 + row) * 64 + q];
    ushort4 b;
    b.x = f2bf(v.x); b.y = f2bf(v.y); b.z = f2bf(v.z); b.w = f2bf(v.w);
    *reinterpret_cast<ushort4*>(&xs[row * 264 + q * 4]) = b;
  }
}

__device__ __forceinline__ void gemm_frag(const unsigned short* xs,
                                          const unsigned short* __restrict__ Wg,
                                          unsigned short* wl, int tid,
                                          f32x4 accv[4][4]) {
  const int wid = tid >> 6, lhi = (tid & 63) >> 4, llo = tid & 15;
  for (int ks = 0; ks < 8; ++ks) {
    const int k0 = ks * 32;
    __syncthreads();  // protects xs (first iter) and wl reads from prev iter
    {
      const uint4* gp = reinterpret_cast<const uint4*>(Wg + (size_t)tid * 256 + k0);
      uint4 a0 = gp[0], a1 = gp[1], a2 = gp[2], a3 = gp[3];
      uint4* lp = reinterpret_cast<uint4*>(wl + tid * 56);
      lp[0] = a0; lp[1] = a1; lp[2] = a2; lp[3] = a3;
    }
    __syncthreads();
    bf16x8 afr[4], bfr[4];
#pragma unroll
    for (int rt = 0; rt < 4; ++rt)
      afr[rt] = *reinterpret_cast<const bf16x8*>(&xs[(rt * 16 + llo) * 264 + k0 + lhi * 8]);
#pragma unroll
    for (int nt = 0; nt < 4; ++nt)
      bfr[nt] = *reinterpret_cast<const bf16x8*>(&wl[(wid * 64 + nt * 16 + llo) * 56 + lhi * 8]);
#pragma unroll
    for (int rt = 0; rt < 4; ++rt)
#pragma unroll
      for (int nt = 0; nt < 4; ++nt)
        accv[rt][nt] = __builtin_amdgcn_mfma_f32_16x16x32_bf16(afr[rt], bfr[nt], accv[rt][nt], 0, 0, 0);
  }
}

__device__ __forceinline__ void writeout_hp(unsigned short* __restrict__ hp, int r0, int tid,
                                            f32x4 accv[4][4]) {
  const int wid = tid >> 6, lane = tid & 63, lhi = lane >> 4, llo = lane & 15;
#pragma unroll
  for (int rt = 0; rt < 4; ++rt)
#pragma unroll
    for (int nt = 0; nt < 4; ++nt) {
      int col = wid * 64 + nt * 16 + llo;
#pragma unroll
      for (int rg = 0; rg < 4; ++rg) {
        int row = rt * 16 + lhi * 4 + rg;
        hp[(size_t)(r0 + row) * DIM + col] = f2bf(accv[rt][nt][rg]);
      }
    }
}

// ---- pre-transform by SOURCE TYPE: stage h once, compute BOTH relations ----
__global__ __launch_bounds__(256) void transformT_kernel(TTy T) {
  __shared__ alignas(16) unsigned short xs[64 * 264];
  __shared__ alignas(16) unsigned short wl[256 * 56];
  const int tid = threadIdx.x;
  const int bx = blockIdx.x;
  int t = 0;
#pragma unroll
  for (int k = 1; k < 3; ++k) t += (bx >= T.cum[k]);
  const int r0 = (bx - T.cum[t]) * 64;

  stage_x_f32(T.h[t], r0, xs, tid);

  f32x4 accv[4][4];
#pragma unroll
  for (int a = 0; a < 4; ++a)
#pragma unroll
    for (int b = 0; b < 4; ++b) accv[a][b] = {0.f, 0.f, 0.f, 0.f};
  gemm_frag(xs, T.wA[t], wl, tid, accv);
  writeout_hp(T.hpA[t], r0, tid, accv);

#pragma unroll
  for (int a = 0; a < 4; ++a)
#pragma unroll
    for (int b = 0; b < 4; ++b) accv[a][b] = {0.f, 0.f, 0.f, 0.f};
  gemm_frag(xs, T.wB[t], wl, tid, accv);  // first barrier inside protects wl reuse
  writeout_hp(T.hpB[t], r0, tid, accv);
}

// ---- per node type: self-GEMM + relation attention + residual + LN + leaky ----
__global__ __launch_bounds__(256) void fuse_kernel(
    const float* __restrict__ h, const unsigned short* __restrict__ msg1,
    const unsigned short* __restrict__ msg2, const unsigned short* __restrict__ Wbf,
    const float* __restrict__ A1, const float* __restrict__ A2,
    const float* __restrict__ gamma, const float* __restrict__ beta,
    float* __restrict__ out) {
  __shared__ alignas(16) union SM {
    struct { unsigned short x[64 * 264]; unsigned short w[256 * 56]; } g;
    unsigned short s[64 * 260];  // self result, bf16
  } ov;
  __shared__ float sgb[512];
  const int tid = threadIdx.x;
  const int r0 = blockIdx.x * 64;

  stage_x_f32(h, r0, ov.g.x, tid);
  for (int i = tid; i < 512; i += 256) sgb[i] = (i < 256) ? gamma[i] : beta[i - 256];

  f32x4 accv[4][4];
#pragma unroll
  for (int a = 0; a < 4; ++a)
#pragma unroll
    for (int b = 0; b < 4; ++b) accv[a][b] = {0.f, 0.f, 0.f, 0.f};

  gemm_frag(ov.g.x, Wbf, ov.g.w, tid, accv);

  const int wid = tid >> 6, lane = tid & 63, lhi = lane >> 4, llo = lane & 15;
  const int d0 = lane * 4;

  // snapshot this thread's residual h-fragments from LDS before ov.s overlays ov.g.x
  ushort4 hreg[16];
#pragma unroll
  for (int rl = 0; rl < 16; ++rl)
    hreg[rl] = *reinterpret_cast<const ushort4*>(&ov.g.x[(wid * 16 + rl) * 264 + d0]);

  __syncthreads();  // all MFMA LDS reads + hreg snapshots done before overlaying ov.s
#pragma unroll
  for (int rt = 0; rt < 4; ++rt)
#pragma unroll
    for (int nt = 0; nt < 4; ++nt) {
      int col = wid * 64 + nt * 16 + llo;
#pragma unroll
      for (int rg = 0; rg < 4; ++rg)
        ov.s[(rt * 16 + lhi * 4 + rg) * 260 + col] = f2bf(accv[rt][nt][rg]);
    }
  __syncthreads();

  // epilogue: wave handles 16 rows; lane owns 4 dims
  const float4* A1v = reinterpret_cast<const float4*>(A1);
  const float4* A2v = reinterpret_cast<const float4*>(A2);
  float4 a1f[4], a2f[4];
#pragma unroll
  for (int hh = 0; hh < 4; ++hh) { a1f[hh] = A1v[hh * 64 + lane]; a2f[hh] = A2v[hh * 64 + lane]; }
  const float4 g4 = *reinterpret_cast<const float4*>(&sgb[d0]);
  const float4 b4 = *reinterpret_cast<const float4*>(&sgb[256 + d0]);

  for (int rl = 0; rl < 16; ++rl) {
    int row = wid * 16 + rl;
    size_t gb = (size_t)(r0 + row) * DIM + d0;
    ushort4 m1b = *reinterpret_cast<const ushort4*>(msg1 + gb);
    ushort4 m2b = *reinterpret_cast<const ushort4*>(msg2 + gb);
    float4 m1 = {bf2f(m1b.x), bf2f(m1b.y), bf2f(m1b.z), bf2f(m1b.w)};
    float4 m2 = {bf2f(m2b.x), bf2f(m2b.y), bf2f(m2b.z), bf2f(m2b.w)};
    float4 hvv = {bf2f(hreg[rl].x), bf2f(hreg[rl].y), bf2f(hreg[rl].z), bf2f(hreg[rl].w)};
    ushort4 sb = *reinterpret_cast<const ushort4*>(&ov.s[row * 260 + d0]);
    float4 sv = {bf2f(sb.x), bf2f(sb.y), bf2f(sb.z), bf2f(sb.w)};

    float sc[8];
#pragma unroll
    for (int hh = 0; hh < 4; ++hh) {
      sc[hh]     = m1.x * a1f[hh].x + m1.y * a1f[hh].y + m1.z * a1f[hh].z + m1.w * a1f[hh].w;
      sc[4 + hh] = m2.x * a2f[hh].x + m2.y * a2f[hh].y + m2.z * a2f[hh].z + m2.w * a2f[hh].w;
    }
#pragma unroll
    for (int o = 1; o < 64; o <<= 1) {
#pragma unroll
      for (int j = 0; j < 8; ++j) sc[j] += __shfl_xor(sc[j], o);
    }
    // softmax over the 2 relations per head; scale = 1/(sqrt(256)*0.5) = 0.125
    float c1 = 0.f, c2 = 0.f;
#pragma unroll
    for (int hh = 0; hh < 4; ++hh) {
      float s1 = sc[hh] * 0.125f, s2 = sc[4 + hh] * 0.125f;
      float mx = fmaxf(s1, s2);
      float e1 = __expf(s1 - mx), e2 = __expf(s2 - mx);
      float inv = 1.f / (e1 + e2);
      c1 += e1 * inv; c2 += e2 * inv;
    }
    c1 *= 0.25f; c2 *= 0.25f;  // mean over H=4 heads

    float4 u;
    u.x = sv.x + c1 * m1.x + c2 * m2.x + hvv.x;
    u.y = sv.y + c1 * m1.y + c2 * m2.y + hvv.y;
    u.z = sv.z + c1 * m1.z + c2 * m2.z + hvv.z;
    u.w = sv.w + c1 * m1.w + c2 * m2.w + hvv.w;

    float s1v = u.x + u.y + u.z + u.w;
    float s2v = u.x * u.x + u.y * u.y + u.z * u.z + u.w * u.w;
#pragma unroll
    for (int o = 1; o < 64; o <<= 1) { s1v += __shfl_xor(s1v, o); s2v += __shfl_xor(s2v, o); }
    float mu = s1v * (1.f / 256.f);
    float var = s2v * (1.f / 256.f) - mu * mu;
    float rstd = rsqrtf(var + 1e-5f);

    float4 y;
    y.x = (u.x - mu) * rstd * g4.x + b4.x;
    y.y = (u.y - mu) * rstd * g4.y + b4.y;
    y.z = (u.z - mu) * rstd * g4.z + b4.z;
    y.w = (u.w - mu) * rstd * g4.w + b4.w;
    y.x = fmaxf(y.x, 0.01f * y.x);
    y.y = fmaxf(y.y, 0.01f * y.y);
    y.z = fmaxf(y.z, 0.01f * y.z);
    y.w = fmaxf(y.w, 0.01f * y.w);
    *reinterpret_cast<float4*>(out + gb) = y;
  }
}

// ---- workspace layout (bytes); ~110 MB peak (< round-1-proven ~119 MB) ----
static constexpr size_t AL(size_t x) { return (x + 255) & ~size_t(255); }
// final messages (bf16), sized by DST rows
static constexpr size_t ACCe_L2G = 0;
static constexpr size_t ACCe_G2L = ACCe_L2G + (size_t)NGr * DIM;
static constexpr size_t ACCe_G2D = ACCe_G2L + (size_t)NLr * DIM;
static constexpr size_t ACCe_D2G = ACCe_G2D + (size_t)NDr * DIM;
static constexpr size_t ACCe_L2D = ACCe_D2G + (size_t)NGr * DIM;
static constexpr size_t ACCe_D2L = ACCe_L2D + (size_t)NDr * DIM;
static constexpr size_t ACC_TOT  = ACCe_D2L + (size_t)NLr * DIM;
// transformed embeddings, all 6 relations, sized by SRC rows
static constexpr size_t HPe_L2G = 0;                                  // NLr
static constexpr size_t HPe_G2L = HPe_L2G + (size_t)NLr * DIM;        // NGr
static constexpr size_t HPe_G2D = HPe_G2L + (size_t)NGr * DIM;        // NGr
static constexpr size_t HPe_D2G = HPe_G2D + (size_t)NGr * DIM;        // NDr
static constexpr size_t HPe_L2D = HPe_D2G + (size_t)NDr * DIM;        // NLr
static constexpr size_t HPe_D2L = HPe_L2D + (size_t)NLr * DIM;        // NDr
static constexpr size_t HP_TOT  = HPe_D2L + (size_t)NDr * DIM;
static constexpr size_t OFF_ACC  = 0;
static constexpr size_t OFF_HP   = AL(OFF_ACC + ACC_TOT * 2);
static constexpr size_t OFF_WBF  = AL(OFF_HP + HP_TOT * 2);
static constexpr size_t OFF_HIST = AL(OFF_WBF + 9 * 65536 * 2);
static constexpr size_t OFF_OFFS = AL(OFF_HIST + 6 * HSTRIDE * 4);
static constexpr size_t OFF_PART = AL(OFF_OFFS + 6 * HSTRIDE * 4);
static constexpr size_t OFF_BOFF = AL(OFF_PART + 48 * 4);
static constexpr size_t OFF_CCUR = AL(OFF_BOFF + 48 * 4);
static constexpr size_t OFF_TMP  = AL(OFF_CCUR + 384 * 4);            // 6*NE int2
static constexpr size_t OFF_SRCW = AL(OFF_TMP + (size_t)6 * NE * 8);  // 6*NE u32

extern "C" void kernel_launch(void* const* d_in, const int* in_sizes, int n_in,
                              void* d_out, int out_size, void* d_ws, size_t ws_size,
                              hipStream_t stream) {
  char* wsb = (char*)d_ws;
  unsigned short* acc = (unsigned short*)(wsb + OFF_ACC);
  unsigned short* hp  = (unsigned short*)(wsb + OFF_HP);
  unsigned short* wbf = (unsigned short*)(wsb + OFF_WBF);
  int* hist = (int*)(wsb + OFF_HIST);
  int* offs = (int*)(wsb + OFF_OFFS);
  int* part = (int*)(wsb + OFF_PART);
  int* boff = (int*)(wsb + OFF_BOFF);
  int* ccur = (int*)(wsb + OFF_CCUR);
  int2* tmp = (int2*)(wsb + OFF_TMP);
  unsigned* srcw = (unsigned*)(wsb + OFF_SRCW);
  float* out = (float*)d_out;

  // relation order: l2g, g2l, g2d, d2g, l2d, d2l
  const int base[6] = {3, 8, 13, 18, 23, 28};
  const int ndst[6] = {NGr, NLr, NDr, NGr, NDr, NLr};
  const size_t accOff[6] = {ACCe_L2G, ACCe_G2L, ACCe_G2D, ACCe_D2G, ACCe_L2D, ACCe_D2L};
  const size_t hpOff[6]  = {HPe_L2G, HPe_G2L, HPe_G2D, HPe_D2G, HPe_L2D, HPe_D2L};

  // weights -> bf16: slots 0..5 = W_rel, 6..8 = Wself_{l,g,d}
  WPtrs wp;
  wp.p[0] = (const float*)d_in[6];  wp.p[1] = (const float*)d_in[11];
  wp.p[2] = (const float*)d_in[16]; wp.p[3] = (const float*)d_in[21];
  wp.p[4] = (const float*)d_in[26]; wp.p[5] = (const float*)d_in[31];
  wp.p[6] = (const float*)d_in[33]; wp.p[7] = (const float*)d_in[36];
  wp.p[8] = (const float*)d_in[39];
  conv_w_kernel<<<dim3(256, 9), 256, 0, stream>>>(wp, wbf);

  // CSR build: hist + fast scan
  (void)hipMemsetAsync(hist, 0, 6 * HSTRIDE * 4, stream);
  RelIdx R; NTab N; PTab P;
  for (int r = 0; r < 6; ++r) {
    R.dst[r] = (const int*)d_in[base[r] + 1];
    N.n[r] = ndst[r];
    P.src[r] = (const int*)d_in[base[r]];
    P.dst[r] = (const int*)d_in[base[r] + 1];
    P.w[r]  = (const float*)d_in[base[r] + 2];
    P.shift[r] = (ndst[r] == NGr) ? 9 : (ndst[r] == NLr ? 8 : 7);  // n>>6 window
  }
  hist6_kernel<<<dim3(NE / 256, 6), 256, 0, stream>>>(R, hist);
  scanA_kernel<<<dim3(8, 6), 256, 0, stream>>>(hist, part, N);
  scanTop_kernel<<<1, 64, 0, stream>>>(part, boff);
  scanC_kernel<<<dim3(8, 6), 256, 0, stream>>>(hist, boff, offs, N);

  // two-pass radix partition (write-amp ~1)
  ccur_init_kernel<<<1, 384, 0, stream>>>(offs, ccur, N);
  partA6_kernel<<<dim3(NE / 1024, 6), 256, 0, stream>>>(P, ccur, tmp);
  partB6_kernel<<<dim3(64, 6), 256, 0, stream>>>(tmp, offs, srcw, N);

  // pre-transform by source type: each block computes BOTH relations of its type
  // type l -> {l2g(0), l2d(4)}, type g -> {g2l(1), g2d(2)}, type d -> {d2g(3), d2l(5)}
  TTy T;
  T.h[0] = (const float*)d_in[0]; T.h[1] = (const float*)d_in[1]; T.h[2] = (const float*)d_in[2];
  T.hpA[0] = hp + hpOff[0]; T.hpB[0] = hp + hpOff[4];
  T.hpA[1] = hp + hpOff[1]; T.hpB[1] = hp + hpOff[2];
  T.hpA[2] = hp + hpOff[3]; T.hpB[2] = hp + hpOff[5];
  T.wA[0] = wbf + 0 * 65536; T.wB[0] = wbf + 4 * 65536;
  T.wA[1] = wbf + 1 * 65536; T.wB[1] = wbf + 2 * 65536;
  T.wA[2] = wbf + 3 * 65536; T.wB[2] = wbf + 5 * 65536;
  T.cum[0] = 0; T.cum[1] = NLr / 64; T.cum[2] = (NLr + NGr) / 64; T.cum[3] = (NLr + NGr + NDr) / 64;
  transformT_kernel<<<T.cum[3], 256, 0, stream>>>(T);

  // gather all 6 relations -> final bf16 messages
  GTab G;
  int cumG = 0;
  for (int r = 0; r < 6; ++r) {
    G.hp[r] = hp + hpOff[r];
    G.acc[r] = acc + accOff[r];
    G.sw[r] = srcw + (size_t)r * NE;
    G.of[r] = offs + r * HSTRIDE;
    G.cum[r] = cumG;
    cumG += ndst[r] / 4;
  }
  G.cum[6] = cumG;
  gather6_kernel<<<cumG, 256, 0, stream>>>(G);

  // type l: msgs [g2l, d2l]
  fuse_kernel<<<NLr / 64, 256, 0, stream>>>(
      (const float*)d_in[0], acc + ACCe_G2L, acc + ACCe_D2L, wbf + 6 * 65536,
      (const float*)d_in[12], (const float*)d_in[32],
      (const float*)d_in[34], (const float*)d_in[35], out);
  // type g: msgs [l2g, d2g]
  fuse_kernel<<<NGr / 64, 256, 0, stream>>>(
      (const float*)d_in[1], acc + ACCe_L2G, acc + ACCe_D2G, wbf + 7 * 65536,
      (const float*)d_in[7], (const float*)d_in[22],
      (const float*)d_in[37], (const float*)d_in[38], out + (size_t)NLr * DIM);
  // type d: msgs [g2d, l2d]
  fuse_kernel<<<NDr / 64, 256, 0, stream>>>(
      (const float*)d_in[2], acc + ACCe_G2D, acc + ACCe_L2D, wbf + 8 * 65536,
      (const float*)d_in[17], (const float*)d_in[27],
      (const float*)d_in[40], (const float*)d_in[41], out + (size_t)(NLr + NGr) * DIM);
}

// Round 11
// 307.826 us; speedup vs baseline: 1.4256x; 1.2011x over previous
//
#include <hip/hip_runtime.h>

#define DIM 256
#define NLr 16384
#define NGr 32768
#define NDr 8192
#define NE  262144
#define HSTRIDE 32772  // offs per-relation stride (16B-aligned)

typedef short bf16x8 __attribute__((ext_vector_type(8)));
typedef float f32x4 __attribute__((ext_vector_type(4)));
typedef unsigned u32x4 __attribute__((ext_vector_type(4)));

__device__ __forceinline__ unsigned short f2bf(float f) {
  unsigned int u = __builtin_bit_cast(unsigned int, f);
  u += 0x7fffu + ((u >> 16) & 1u);
  return (unsigned short)(u >> 16);
}
__device__ __forceinline__ float bf2f(unsigned short b) {
  return __builtin_bit_cast(float, ((unsigned int)b) << 16);
}
__device__ __forceinline__ float bflo(unsigned int u) {
  return __builtin_bit_cast(float, u << 16);
}
__device__ __forceinline__ float bfhi(unsigned int u) {
  return __builtin_bit_cast(float, u & 0xffff0000u);
}

struct NTab { int n[6]; };
struct PrepTab { const float* wsrc[9]; const int* dst[6]; int shift[6]; };
struct PTab { const int* src[6]; const int* dst[6]; const float* w[6]; int shift[6]; };
struct TTy { const float* h[3]; unsigned short* hpA[3]; unsigned short* hpB[3];
             const unsigned short* wA[3]; const unsigned short* wB[3]; int cum[4]; };
struct GTab { const unsigned short* hp[6]; unsigned short* acc[6];
              const unsigned* sw[6]; const int* of[6]; int cum[7]; };

// ---- merged prep: blocks [0,2304) convert 9 weight mats; [2304,3840) coarse hist ----
__global__ __launch_bounds__(256) void prep_kernel(PrepTab Q, unsigned short* __restrict__ wbf,
                                                   int* __restrict__ chist) {
  const int bid = blockIdx.x, tid = threadIdx.x;
  __shared__ int h[64];
  if (bid < 2304) {
    int m = bid >> 8;
    int i = (bid & 255) * 256 + tid;
    wbf[m * 65536 + i] = f2bf(Q.wsrc[m][i]);
  } else {
    int b2 = bid - 2304;
    int r = b2 >> 8;          // 256 blocks per relation, 1024 edges each
    int blk = b2 & 255;
    if (tid < 64) h[tid] = 0;
    __syncthreads();
    const int* dp = Q.dst[r] + blk * 1024;
    const int sh = Q.shift[r];
#pragma unroll
    for (int k = 0; k < 4; ++k) atomicAdd(&h[dp[k * 256 + tid] >> sh], 1);
    __syncthreads();
    if (tid < 64) { int c = h[tid]; if (c) atomicAdd(&chist[r * 64 + tid], c); }
  }
}

// ---- tiny coarse scan: ccur (working cursor) + cbase (read-only windows) ----
__global__ void scan384_kernel(const int* __restrict__ chist, int* __restrict__ ccur,
                               int* __restrict__ cbase) {
  int r = threadIdx.x;
  if (r < 6) {
    int off = 0;
    for (int b = 0; b < 64; ++b) {
      ccur[r * 64 + b] = off;
      cbase[r * 65 + b] = off;
      off += chist[r * 64 + b];
    }
    cbase[r * 65 + 64] = off;  // == NE
  }
}

// ---- partition pass A: coarse 64-bucket partition into tmp (dst, packed) ----
__global__ __launch_bounds__(256) void partA6_kernel(PTab P, int* __restrict__ ccur,
                                                     int2* __restrict__ tmp) {
  int r = blockIdx.y;
  const int tid = threadIdx.x;
  __shared__ int hist[64], lbase[64], lcur[64];
  if (tid < 64) { hist[tid] = 0; lcur[tid] = 0; }
  __syncthreads();
  const int ebase = blockIdx.x * 1024;
  const int sh = P.shift[r];
  int dsts[4]; unsigned pk[4]; int bks[4];
#pragma unroll
  for (int k = 0; k < 4; ++k) {
    int e = ebase + k * 256 + tid;
    int d = P.dst[r][e];
    dsts[k] = d;
    pk[k] = (unsigned)P.src[r][e] | ((unsigned)f2bf(P.w[r][e]) << 16);
    bks[k] = d >> sh;
    atomicAdd(&hist[bks[k]], 1);
  }
  __syncthreads();
  if (tid < 64) {
    int c = hist[tid];
    if (c) lbase[tid] = atomicAdd(&ccur[r * 64 + tid], c);
  }
  __syncthreads();
#pragma unroll
  for (int k = 0; k < 4; ++k) {
    int pos = lbase[bks[k]] + atomicAdd(&lcur[bks[k]], 1);
    tmp[(size_t)r * NE + pos] = make_int2(dsts[k], (int)pk[k]);
  }
}

// ---- partition pass B: fine hist + block scan -> offs, then exact placement ----
// block (r,b) owns coarse window [cbase[r,b], cbase[r,b+1]) and node range [b*s,(b+1)*s)
__global__ __launch_bounds__(256) void partB6_kernel(const int2* __restrict__ tmp,
                                                     const int* __restrict__ cbase,
                                                     int* __restrict__ offs,
                                                     unsigned* __restrict__ srcw, NTab N) {
  int r = blockIdx.y, b = blockIdx.x;
  const int n = N.n[r], s = n >> 6;
  const int tid = threadIdx.x;
  const int dbase = b * s;
  __shared__ int hist[512];
  __shared__ int part[256];
  for (int i = tid; i < s; i += 256) hist[i] = 0;
  __syncthreads();
  const int wbeg = cbase[r * 65 + b], wend = cbase[r * 65 + b + 1];
  const int2* __restrict__ tr = tmp + (size_t)r * NE;
  for (int i = wbeg + tid; i < wend; i += 256)
    atomicAdd(&hist[tr[i].x - dbase], 1);
  __syncthreads();
  // exclusive scan of hist[0..s) in place -> start positions; also write global offs
  const int per = (s > 256) ? 2 : 1;
  const int base = tid * per;
  int vals[2];
  int mysum = 0;
#pragma unroll
  for (int j = 0; j < 2; ++j) {
    int idx = base + j;
    vals[j] = (j < per && idx < s) ? hist[idx] : 0;
    mysum += vals[j];
  }
  part[tid] = mysum;
  __syncthreads();
  for (int off = 1; off < 256; off <<= 1) {
    int v = (tid >= off) ? part[tid - off] : 0;
    __syncthreads();
    part[tid] += v;
    __syncthreads();
  }
  int run = part[tid] - mysum + wbeg;
#pragma unroll
  for (int j = 0; j < 2; ++j) {
    int idx = base + j;
    if (j < per && idx < s) {
      hist[idx] = run;                         // becomes the live cursor
      offs[r * HSTRIDE + dbase + idx] = run;   // fine CSR offsets
      run += vals[j];
    }
  }
  if (b == 0 && tid == 0) offs[r * HSTRIDE + n] = NE;
  __syncthreads();
  for (int i = wbeg + tid; i < wend; i += 256) {
    int2 e = tr[i];
    int pos = atomicAdd(&hist[e.x - dbase], 1);
    srcw[(size_t)r * NE + pos] = (unsigned)e.y;
  }
}

// ---- gather: msg[node] = (sum w_e * hp[src_e]) / deg (round-10 proven) ----
__global__ __launch_bounds__(256) void gather6_kernel(GTab T) {
  const int bx = blockIdx.x;
  int r = 0;
#pragma unroll
  for (int k = 1; k < 6; ++k) r += (bx >= T.cum[k]);
  const int node = (bx - T.cum[r]) * 4 + (threadIdx.x >> 6);
  const int lane = threadIdx.x & 63;
  const int half = lane >> 5;
  const int c8 = lane & 31;
  const int* of = T.of[r];
  const int beg = of[node], end = of[node + 1];
  const uint4* __restrict__ hv = reinterpret_cast<const uint4*>(T.hp[r]);
  const unsigned* __restrict__ sw = T.sw[r];
  float a0 = 0.f, a1 = 0.f, a2 = 0.f, a3 = 0.f, a4 = 0.f, a5 = 0.f, a6 = 0.f, a7 = 0.f;
  float degw = 0.f;
  for (int j = beg; j < end; j += 8) {
    int ib = j + half * 4;
    unsigned e0 = (ib + 0 < end) ? sw[ib + 0] : 0u;
    unsigned e1 = (ib + 1 < end) ? sw[ib + 1] : 0u;
    unsigned e2 = (ib + 2 < end) ? sw[ib + 2] : 0u;
    unsigned e3 = (ib + 3 < end) ? sw[ib + 3] : 0u;
    float w0 = bfhi(e0), w1 = bfhi(e1), w2 = bfhi(e2), w3 = bfhi(e3);
    int s0 = e0 & 0xffff, s1 = e1 & 0xffff, s2 = e2 & 0xffff, s3 = e3 & 0xffff;
    uint4 x0 = hv[(size_t)s0 * 32 + c8];
    uint4 x1 = hv[(size_t)s1 * 32 + c8];
    uint4 x2 = hv[(size_t)s2 * 32 + c8];
    uint4 x3 = hv[(size_t)s3 * 32 + c8];
    degw += (w0 + w1) + (w2 + w3);
    a0 += w0 * bflo(x0.x) + w1 * bflo(x1.x) + w2 * bflo(x2.x) + w3 * bflo(x3.x);
    a1 += w0 * bfhi(x0.x) + w1 * bfhi(x1.x) + w2 * bfhi(x2.x) + w3 * bfhi(x3.x);
    a2 += w0 * bflo(x0.y) + w1 * bflo(x1.y) + w2 * bflo(x2.y) + w3 * bflo(x3.y);
    a3 += w0 * bfhi(x0.y) + w1 * bfhi(x1.y) + w2 * bfhi(x2.y) + w3 * bfhi(x3.y);
    a4 += w0 * bflo(x0.z) + w1 * bflo(x1.z) + w2 * bflo(x2.z) + w3 * bflo(x3.z);
    a5 += w0 * bfhi(x0.z) + w1 * bfhi(x1.z) + w2 * bfhi(x2.z) + w3 * bfhi(x3.z);
    a6 += w0 * bflo(x0.w) + w1 * bflo(x1.w) + w2 * bflo(x2.w) + w3 * bflo(x3.w);
    a7 += w0 * bfhi(x0.w) + w1 * bfhi(x1.w) + w2 * bfhi(x2.w) + w3 * bfhi(x3.w);
  }
  a0 += __shfl_xor(a0, 32); a1 += __shfl_xor(a1, 32);
  a2 += __shfl_xor(a2, 32); a3 += __shfl_xor(a3, 32);
  a4 += __shfl_xor(a4, 32); a5 += __shfl_xor(a5, 32);
  a6 += __shfl_xor(a6, 32); a7 += __shfl_xor(a7, 32);
  degw += __shfl_xor(degw, 32);
  float inv = (degw == 0.f) ? 1.f : 1.f / degw;
  if (half == 0) {
    u32x4 o;
    o.x = (unsigned)f2bf(a0 * inv) | ((unsigned)f2bf(a1 * inv) << 16);
    o.y = (unsigned)f2bf(a2 * inv) | ((unsigned)f2bf(a3 * inv) << 16);
    o.z = (unsigned)f2bf(a4 * inv) | ((unsigned)f2bf(a5 * inv) << 16);
    o.w = (unsigned)f2bf(a6 * inv) | ((unsigned)f2bf(a7 * inv) << 16);
    __builtin_nontemporal_store(o, reinterpret_cast<u32x4*>(T.acc[r]) + (size_t)node * 32 + c8);
  }
}

// ---- shared GEMM pieces: 64 rows x (256x256) bf16 MFMA (rounds 6-10 proven) ----
__device__ __forceinline__ void stage_x_f32(const float* __restrict__ g, int r0,
                                            unsigned short* xs, int tid) {
#pragma unroll
  for (int it = 0; it < 16; ++it) {
    int i = it * 256 + tid;
    int row = i >> 6, q = i & 63;
    float4 v = reinterpret_cast<const float4*>(g)[(size_t)(r0 + row) * 64 + q];
    ushort4 b;
    b.x = f2bf(v.x); b.y = f2bf(v.y); b.z = f2bf(v.z); b.w = f2bf(v.w);
    *reinterpret_cast<ushort4*>(&xs[row * 264 + q * 4]) = b;
  }
}

__device__ __forceinline__ void gemm_frag(const unsigned short* xs,
                                          const unsigned short* __restrict__ Wg,
                                          unsigned short* wl, int tid,
                                          f32x4 accv[4][4]) {
  const int wid = tid >> 6, lhi = (tid & 63) >> 4, llo = tid & 15;
  for (int ks = 0; ks < 8; ++ks) {
    const int k0 = ks * 32;
    __syncthreads();  // protects xs (first iter) and wl reads from prev iter
    {
      const uint4* gp = reinterpret_cast<const uint4*>(Wg + (size_t)tid * 256 + k0);
      uint4 a0 = gp[0], a1 = gp[1], a2 = gp[2], a3 = gp[3];
      uint4* lp = reinterpret_cast<uint4*>(wl + tid * 56);
      lp[0] = a0; lp[1] = a1; lp[2] = a2; lp[3] = a3;
    }
    __syncthreads();
    bf16x8 afr[4], bfr[4];
#pragma unroll
    for (int rt = 0; rt < 4; ++rt)
      afr[rt] = *reinterpret_cast<const bf16x8*>(&xs[(rt * 16 + llo) * 264 + k0 + lhi * 8]);
#pragma unroll
    for (int nt = 0; nt < 4; ++nt)
      bfr[nt] = *reinterpret_cast<const bf16x8*>(&wl[(wid * 64 + nt * 16 + llo) * 56 + lhi * 8]);
#pragma unroll
    for (int rt = 0; rt < 4; ++rt)
#pragma unroll
      for (int nt = 0; nt < 4; ++nt)
        accv[rt][nt] = __builtin_amdgcn_mfma_f32_16x16x32_bf16(afr[rt], bfr[nt], accv[rt][nt], 0, 0, 0);
  }
}

__device__ __forceinline__ void writeout_hp(unsigned short* __restrict__ hp, int r0, int tid,
                                            f32x4 accv[4][4]) {
  const int wid = tid >> 6, lane = tid & 63, lhi = lane >> 4, llo = lane & 15;
#pragma unroll
  for (int rt = 0; rt < 4; ++rt)
#pragma unroll
    for (int nt = 0; nt < 4; ++nt) {
      int col = wid * 64 + nt * 16 + llo;
#pragma unroll
      for (int rg = 0; rg < 4; ++rg) {
        int row = rt * 16 + lhi * 4 + rg;
        hp[(size_t)(r0 + row) * DIM + col] = f2bf(accv[rt][nt][rg]);
      }
    }
}

// ---- pre-transform by SOURCE TYPE: stage h once, compute BOTH relations ----
__global__ __launch_bounds__(256) void transformT_kernel(TTy T) {
  __shared__ alignas(16) unsigned short xs[64 * 264];
  __shared__ alignas(16) unsigned short wl[256 * 56];
  const int tid = threadIdx.x;
  const int bx = blockIdx.x;
  int t = 0;
#pragma unroll
  for (int k = 1; k < 3; ++k) t += (bx >= T.cum[k]);
  const int r0 = (bx - T.cum[t]) * 64;

  stage_x_f32(T.h[t], r0, xs, tid);

  f32x4 accv[4][4];
#pragma unroll
  for (int a = 0; a < 4; ++a)
#pragma unroll
    for (int b = 0; b < 4; ++b) accv[a][b] = {0.f, 0.f, 0.f, 0.f};
  gemm_frag(xs, T.wA[t], wl, tid, accv);
  writeout_hp(T.hpA[t], r0, tid, accv);

#pragma unroll
  for (int a = 0; a < 4; ++a)
#pragma unroll
    for (int b = 0; b < 4; ++b) accv[a][b] = {0.f, 0.f, 0.f, 0.f};
  gemm_frag(xs, T.wB[t], wl, tid, accv);  // first barrier inside protects wl reuse
  writeout_hp(T.hpB[t], r0, tid, accv);
}

// ---- per node type: self-GEMM + relation attention + residual + LN + leaky ----
// (round-9-proven body; residual h re-read from global, no LDS snapshot)
__global__ __launch_bounds__(256) void fuse_kernel(
    const float* __restrict__ h, const unsigned short* __restrict__ msg1,
    const unsigned short* __restrict__ msg2, const unsigned short* __restrict__ Wbf,
    const float* __restrict__ A1, const float* __restrict__ A2,
    const float* __restrict__ gamma, const float* __restrict__ beta,
    float* __restrict__ out) {
  __shared__ alignas(16) union SM {
    struct { unsigned short x[64 * 264]; unsigned short w[256 * 56]; } g;
    unsigned short s[64 * 260];  // self result, bf16
  } ov;
  __shared__ float sgb[512];
  const int tid = threadIdx.x;
  const int r0 = blockIdx.x * 64;

  stage_x_f32(h, r0, ov.g.x, tid);
  for (int i = tid; i < 512; i += 256) sgb[i] = (i < 256) ? gamma[i] : beta[i - 256];

  f32x4 accv[4][4];
#pragma unroll
  for (int a = 0; a < 4; ++a)
#pragma unroll
    for (int b = 0; b < 4; ++b) accv[a][b] = {0.f, 0.f, 0.f, 0.f};

  gemm_frag(ov.g.x, Wbf, ov.g.w, tid, accv);

  const int wid = tid >> 6, lane = tid & 63, lhi = lane >> 4, llo = lane & 15;
  __syncthreads();  // all MFMA LDS reads done before overlaying ov.s
#pragma unroll
  for (int rt = 0; rt < 4; ++rt)
#pragma unroll
    for (int nt = 0; nt < 4; ++nt) {
      int col = wid * 64 + nt * 16 + llo;
#pragma unroll
      for (int rg = 0; rg < 4; ++rg)
        ov.s[(rt * 16 + lhi * 4 + rg) * 260 + col] = f2bf(accv[rt][nt][rg]);
    }
  __syncthreads();

  // epilogue: wave handles 16 rows; lane owns 4 dims
  const int d0 = lane * 4;
  const float4* A1v = reinterpret_cast<const float4*>(A1);
  const float4* A2v = reinterpret_cast<const float4*>(A2);
  float4 a1f[4], a2f[4];
#pragma unroll
  for (int hh = 0; hh < 4; ++hh) { a1f[hh] = A1v[hh * 64 + lane]; a2f[hh] = A2v[hh * 64 + lane]; }
  const float4 g4 = *reinterpret_cast<const float4*>(&sgb[d0]);
  const float4 b4 = *reinterpret_cast<const float4*>(&sgb[256 + d0]);

  for (int rl = 0; rl < 16; ++rl) {
    int row = wid * 16 + rl;
    size_t gb = (size_t)(r0 + row) * DIM + d0;
    ushort4 m1b = *reinterpret_cast<const ushort4*>(msg1 + gb);
    ushort4 m2b = *reinterpret_cast<const ushort4*>(msg2 + gb);
    float4 m1 = {bf2f(m1b.x), bf2f(m1b.y), bf2f(m1b.z), bf2f(m1b.w)};
    float4 m2 = {bf2f(m2b.x), bf2f(m2b.y), bf2f(m2b.z), bf2f(m2b.w)};
    float4 hvv = *reinterpret_cast<const float4*>(h + gb);
    ushort4 sb = *reinterpret_cast<const ushort4*>(&ov.s[row * 260 + d0]);
    float4 sv = {bf2f(sb.x), bf2f(sb.y), bf2f(sb.z), bf2f(sb.w)};

    float sc[8];
#pragma unroll
    for (int hh = 0; hh < 4; ++hh) {
      sc[hh]     = m1.x * a1f[hh].x + m1.y * a1f[hh].y + m1.z * a1f[hh].z + m1.w * a1f[hh].w;
      sc[4 + hh] = m2.x * a2f[hh].x + m2.y * a2f[hh].y + m2.z * a2f[hh].z + m2.w * a2f[hh].w;
    }
#pragma unroll
    for (int o = 1; o < 64; o <<= 1) {
#pragma unroll
      for (int j = 0; j < 8; ++j) sc[j] += __shfl_xor(sc[j], o);
    }
    // softmax over the 2 relations per head; scale = 1/(sqrt(256)*0.5) = 0.125
    float c1 = 0.f, c2 = 0.f;
#pragma unroll
    for (int hh = 0; hh < 4; ++hh) {
      float s1 = sc[hh] * 0.125f, s2 = sc[4 + hh] * 0.125f;
      float mx = fmaxf(s1, s2);
      float e1 = __expf(s1 - mx), e2 = __expf(s2 - mx);
      float inv = 1.f / (e1 + e2);
      c1 += e1 * inv; c2 += e2 * inv;
    }
    c1 *= 0.25f; c2 *= 0.25f;  // mean over H=4 heads

    float4 u;
    u.x = sv.x + c1 * m1.x + c2 * m2.x + hvv.x;
    u.y = sv.y + c1 * m1.y + c2 * m2.y + hvv.y;
    u.z = sv.z + c1 * m1.z + c2 * m2.z + hvv.z;
    u.w = sv.w + c1 * m1.w + c2 * m2.w + hvv.w;

    float s1v = u.x + u.y + u.z + u.w;
    float s2v = u.x * u.x + u.y * u.y + u.z * u.z + u.w * u.w;
#pragma unroll
    for (int o = 1; o < 64; o <<= 1) { s1v += __shfl_xor(s1v, o); s2v += __shfl_xor(s2v, o); }
    float mu = s1v * (1.f / 256.f);
    float var = s2v * (1.f / 256.f) - mu * mu;
    float rstd = rsqrtf(var + 1e-5f);

    float4 y;
    y.x = (u.x - mu) * rstd * g4.x + b4.x;
    y.y = (u.y - mu) * rstd * g4.y + b4.y;
    y.z = (u.z - mu) * rstd * g4.z + b4.z;
    y.w = (u.w - mu) * rstd * g4.w + b4.w;
    y.x = fmaxf(y.x, 0.01f * y.x);
    y.y = fmaxf(y.y, 0.01f * y.y);
    y.z = fmaxf(y.z, 0.01f * y.z);
    y.w = fmaxf(y.w, 0.01f * y.w);
    *reinterpret_cast<float4*>(out + gb) = y;
  }
}

// ---- workspace layout (bytes); ~138.5 MB (< round-10-proven ~139.3 MB) ----
static constexpr size_t AL(size_t x) { return (x + 255) & ~size_t(255); }
// final messages (bf16), sized by DST rows
static constexpr size_t ACCe_L2G = 0;
static constexpr size_t ACCe_G2L = ACCe_L2G + (size_t)NGr * DIM;
static constexpr size_t ACCe_G2D = ACCe_G2L + (size_t)NLr * DIM;
static constexpr size_t ACCe_D2G = ACCe_G2D + (size_t)NDr * DIM;
static constexpr size_t ACCe_L2D = ACCe_D2G + (size_t)NGr * DIM;
static constexpr size_t ACCe_D2L = ACCe_L2D + (size_t)NDr * DIM;
static constexpr size_t ACC_TOT  = ACCe_D2L + (size_t)NLr * DIM;
// transformed embeddings, all 6 relations, sized by SRC rows
static constexpr size_t HPe_L2G = 0;                                  // NLr
static constexpr size_t HPe_G2L = HPe_L2G + (size_t)NLr * DIM;        // NGr
static constexpr size_t HPe_G2D = HPe_G2L + (size_t)NGr * DIM;        // NGr
static constexpr size_t HPe_D2G = HPe_G2D + (size_t)NGr * DIM;        // NDr
static constexpr size_t HPe_L2D = HPe_D2G + (size_t)NDr * DIM;        // NLr
static constexpr size_t HPe_D2L = HPe_L2D + (size_t)NLr * DIM;        // NDr
static constexpr size_t HP_TOT  = HPe_D2L + (size_t)NDr * DIM;
static constexpr size_t OFF_ACC   = 0;
static constexpr size_t OFF_HP    = AL(OFF_ACC + ACC_TOT * 2);
static constexpr size_t OFF_WBF   = AL(OFF_HP + HP_TOT * 2);
static constexpr size_t OFF_OFFS  = AL(OFF_WBF + 9 * 65536 * 2);
static constexpr size_t OFF_CHIST = AL(OFF_OFFS + 6 * HSTRIDE * 4);   // 384 ints
static constexpr size_t OFF_CBASE = AL(OFF_CHIST + 384 * 4);          // 6*65 ints
static constexpr size_t OFF_CCUR  = AL(OFF_CBASE + 390 * 4);          // 384 ints
static constexpr size_t OFF_TMP   = AL(OFF_CCUR + 384 * 4);           // 6*NE int2
static constexpr size_t OFF_SRCW  = AL(OFF_TMP + (size_t)6 * NE * 8); // 6*NE u32

extern "C" void kernel_launch(void* const* d_in, const int* in_sizes, int n_in,
                              void* d_out, int out_size, void* d_ws, size_t ws_size,
                              hipStream_t stream) {
  char* wsb = (char*)d_ws;
  unsigned short* acc = (unsigned short*)(wsb + OFF_ACC);
  unsigned short* hp  = (unsigned short*)(wsb + OFF_HP);
  unsigned short* wbf = (unsigned short*)(wsb + OFF_WBF);
  int* offs  = (int*)(wsb + OFF_OFFS);
  int* chist = (int*)(wsb + OFF_CHIST);
  int* cbase = (int*)(wsb + OFF_CBASE);
  int* ccur  = (int*)(wsb + OFF_CCUR);
  int2* tmp  = (int2*)(wsb + OFF_TMP);
  unsigned* srcw = (unsigned*)(wsb + OFF_SRCW);
  float* out = (float*)d_out;

  // relation order: l2g, g2l, g2d, d2g, l2d, d2l
  const int base[6] = {3, 8, 13, 18, 23, 28};
  const int ndst[6] = {NGr, NLr, NDr, NGr, NDr, NLr};
  const size_t accOff[6] = {ACCe_L2G, ACCe_G2L, ACCe_G2D, ACCe_D2G, ACCe_L2D, ACCe_D2L};
  const size_t hpOff[6]  = {HPe_L2G, HPe_G2L, HPe_G2D, HPe_D2G, HPe_L2D, HPe_D2L};

  // merged prep: weight f32->bf16 + coarse dst histogram
  (void)hipMemsetAsync(chist, 0, 384 * 4, stream);
  PrepTab Q; PTab P; NTab N;
  Q.wsrc[0] = (const float*)d_in[6];  Q.wsrc[1] = (const float*)d_in[11];
  Q.wsrc[2] = (const float*)d_in[16]; Q.wsrc[3] = (const float*)d_in[21];
  Q.wsrc[4] = (const float*)d_in[26]; Q.wsrc[5] = (const float*)d_in[31];
  Q.wsrc[6] = (const float*)d_in[33]; Q.wsrc[7] = (const float*)d_in[36];
  Q.wsrc[8] = (const float*)d_in[39];
  for (int r = 0; r < 6; ++r) {
    int sh = (ndst[r] == NGr) ? 9 : (ndst[r] == NLr ? 8 : 7);  // coarse = n>>6
    Q.dst[r] = (const int*)d_in[base[r] + 1];
    Q.shift[r] = sh;
    P.src[r] = (const int*)d_in[base[r]];
    P.dst[r] = (const int*)d_in[base[r] + 1];
    P.w[r]  = (const float*)d_in[base[r] + 2];
    P.shift[r] = sh;
    N.n[r] = ndst[r];
  }
  prep_kernel<<<2304 + 1536, 256, 0, stream>>>(Q, wbf, chist);
  scan384_kernel<<<1, 64, 0, stream>>>(chist, ccur, cbase);

  // two-pass radix partition; partB also derives the fine CSR offsets
  partA6_kernel<<<dim3(NE / 1024, 6), 256, 0, stream>>>(P, ccur, tmp);
  partB6_kernel<<<dim3(64, 6), 256, 0, stream>>>(tmp, cbase, offs, srcw, N);

  // pre-transform by source type: each block computes BOTH relations of its type
  // type l -> {l2g(0), l2d(4)}, type g -> {g2l(1), g2d(2)}, type d -> {d2g(3), d2l(5)}
  TTy T;
  T.h[0] = (const float*)d_in[0]; T.h[1] = (const float*)d_in[1]; T.h[2] = (const float*)d_in[2];
  T.hpA[0] = hp + hpOff[0]; T.hpB[0] = hp + hpOff[4];
  T.hpA[1] = hp + hpOff[1]; T.hpB[1] = hp + hpOff[2];
  T.hpA[2] = hp + hpOff[3]; T.hpB[2] = hp + hpOff[5];
  T.wA[0] = wbf + 0 * 65536; T.wB[0] = wbf + 4 * 65536;
  T.wA[1] = wbf + 1 * 65536; T.wB[1] = wbf + 2 * 65536;
  T.wA[2] = wbf + 3 * 65536; T.wB[2] = wbf + 5 * 65536;
  T.cum[0] = 0; T.cum[1] = NLr / 64; T.cum[2] = (NLr + NGr) / 64; T.cum[3] = (NLr + NGr + NDr) / 64;
  transformT_kernel<<<T.cum[3], 256, 0, stream>>>(T);

  // gather all 6 relations -> final bf16 messages
  GTab G;
  int cumG = 0;
  for (int r = 0; r < 6; ++r) {
    G.hp[r] = hp + hpOff[r];
    G.acc[r] = acc + accOff[r];
    G.sw[r] = srcw + (size_t)r * NE;
    G.of[r] = offs + r * HSTRIDE;
    G.cum[r] = cumG;
    cumG += ndst[r] / 4;
  }
  G.cum[6] = cumG;
  gather6_kernel<<<cumG, 256, 0, stream>>>(G);

  // type l: msgs [g2l, d2l]
  fuse_kernel<<<NLr / 64, 256, 0, stream>>>(
      (const float*)d_in[0], acc + ACCe_G2L, acc + ACCe_D2L, wbf + 6 * 65536,
      (const float*)d_in[12], (const float*)d_in[32],
      (const float*)d_in[34], (const float*)d_in[35], out);
  // type g: msgs [l2g, d2g]
  fuse_kernel<<<NGr / 64, 256, 0, stream>>>(
      (const float*)d_in[1], acc + ACCe_L2G, acc + ACCe_D2G, wbf + 7 * 65536,
      (const float*)d_in[7], (const float*)d_in[22],
      (const float*)d_in[37], (const float*)d_in[38], out + (size_t)NLr * DIM);
  // type d: msgs [g2d, l2d]
  fuse_kernel<<<NDr / 64, 256, 0, stream>>>(
      (const float*)d_in[2], acc + ACCe_G2D, acc + ACCe_L2D, wbf + 8 * 65536,
      (const float*)d_in[17], (const float*)d_in[27],
      (const float*)d_in[40], (const float*)d_in[41], out + (size_t)(NLr + NGr) * DIM);
}

// Round 12
// 291.146 us; speedup vs baseline: 1.5072x; 1.0573x over previous
//
#include <hip/hip_runtime.h>

#define DIM 256
#define NLr 16384
#define NGr 32768
#define NDr 8192
#define NE  262144
#define HSTRIDE 32772  // offs per-relation stride (16B-aligned)

typedef short bf16x8 __attribute__((ext_vector_type(8)));
typedef float f32x4 __attribute__((ext_vector_type(4)));
typedef unsigned u32x4 __attribute__((ext_vector_type(4)));

__device__ __forceinline__ unsigned short f2bf(float f) {
  unsigned int u = __builtin_bit_cast(unsigned int, f);
  u += 0x7fffu + ((u >> 16) & 1u);
  return (unsigned short)(u >> 16);
}
__device__ __forceinline__ float bf2f(unsigned short b) {
  return __builtin_bit_cast(float, ((unsigned int)b) << 16);
}
__device__ __forceinline__ float bflo(unsigned int u) {
  return __builtin_bit_cast(float, u << 16);
}
__device__ __forceinline__ float bfhi(unsigned int u) {
  return __builtin_bit_cast(float, u & 0xffff0000u);
}

struct NTab { int n[6]; };
struct PrepTab { const float* wsrc[9]; const int* dst[6]; int shift[6]; };
struct PTab { const int* src[6]; const int* dst[6]; const float* w[6]; int shift[6]; };
struct TTy { const float* h[3]; unsigned short* hpA[3]; unsigned short* hpB[3];
             const unsigned short* wA[3]; const unsigned short* wB[3]; int cum[4]; };
struct GATab { const unsigned short* hpA[3]; const unsigned short* hpB[3];
               const unsigned* swA[3]; const unsigned* swB[3];
               const int* ofA[3]; const int* ofB[3];
               const float* A1[3]; const float* A2[3];
               unsigned short* agg[3]; int cum[4]; };

// ---- merged prep: blocks [0,2304) convert 9 weight mats; [2304,3840) coarse hist ----
__global__ __launch_bounds__(256) void prep_kernel(PrepTab Q, unsigned short* __restrict__ wbf,
                                                   int* __restrict__ chist) {
  const int bid = blockIdx.x, tid = threadIdx.x;
  __shared__ int h[64];
  if (bid < 2304) {
    int m = bid >> 8;
    int i = (bid & 255) * 256 + tid;
    wbf[m * 65536 + i] = f2bf(Q.wsrc[m][i]);
  } else {
    int b2 = bid - 2304;
    int r = b2 >> 8;          // 256 blocks per relation, 1024 edges each
    int blk = b2 & 255;
    if (tid < 64) h[tid] = 0;
    __syncthreads();
    const int* dp = Q.dst[r] + blk * 1024;
    const int sh = Q.shift[r];
#pragma unroll
    for (int k = 0; k < 4; ++k) atomicAdd(&h[dp[k * 256 + tid] >> sh], 1);
    __syncthreads();
    if (tid < 64) { int c = h[tid]; if (c) atomicAdd(&chist[r * 64 + tid], c); }
  }
}

// ---- tiny coarse scan: ccur (working cursor) + cbase (read-only windows) ----
__global__ void scan384_kernel(const int* __restrict__ chist, int* __restrict__ ccur,
                               int* __restrict__ cbase) {
  int r = threadIdx.x;
  if (r < 6) {
    int off = 0;
    for (int b = 0; b < 64; ++b) {
      ccur[r * 64 + b] = off;
      cbase[r * 65 + b] = off;
      off += chist[r * 64 + b];
    }
    cbase[r * 65 + 64] = off;  // == NE
  }
}

// ---- partition pass A: coarse 64-bucket partition into tmp (dst, packed) ----
__global__ __launch_bounds__(256) void partA6_kernel(PTab P, int* __restrict__ ccur,
                                                     int2* __restrict__ tmp) {
  int r = blockIdx.y;
  const int tid = threadIdx.x;
  __shared__ int hist[64], lbase[64], lcur[64];
  if (tid < 64) { hist[tid] = 0; lcur[tid] = 0; }
  __syncthreads();
  const int ebase = blockIdx.x * 1024;
  const int sh = P.shift[r];
  int dsts[4]; unsigned pk[4]; int bks[4];
#pragma unroll
  for (int k = 0; k < 4; ++k) {
    int e = ebase + k * 256 + tid;
    int d = P.dst[r][e];
    dsts[k] = d;
    pk[k] = (unsigned)P.src[r][e] | ((unsigned)f2bf(P.w[r][e]) << 16);
    bks[k] = d >> sh;
    atomicAdd(&hist[bks[k]], 1);
  }
  __syncthreads();
  if (tid < 64) {
    int c = hist[tid];
    if (c) lbase[tid] = atomicAdd(&ccur[r * 64 + tid], c);
  }
  __syncthreads();
#pragma unroll
  for (int k = 0; k < 4; ++k) {
    int pos = lbase[bks[k]] + atomicAdd(&lcur[bks[k]], 1);
    tmp[(size_t)r * NE + pos] = make_int2(dsts[k], (int)pk[k]);
  }
}

// ---- partition pass B: fine hist + block scan -> offs, then exact placement ----
__global__ __launch_bounds__(256) void partB6_kernel(const int2* __restrict__ tmp,
                                                     const int* __restrict__ cbase,
                                                     int* __restrict__ offs,
                                                     unsigned* __restrict__ srcw, NTab N) {
  int r = blockIdx.y, b = blockIdx.x;
  const int n = N.n[r], s = n >> 6;
  const int tid = threadIdx.x;
  const int dbase = b * s;
  __shared__ int hist[512];
  __shared__ int part[256];
  for (int i = tid; i < s; i += 256) hist[i] = 0;
  __syncthreads();
  const int wbeg = cbase[r * 65 + b], wend = cbase[r * 65 + b + 1];
  const int2* __restrict__ tr = tmp + (size_t)r * NE;
  for (int i = wbeg + tid; i < wend; i += 256)
    atomicAdd(&hist[tr[i].x - dbase], 1);
  __syncthreads();
  const int per = (s > 256) ? 2 : 1;
  const int base = tid * per;
  int vals[2];
  int mysum = 0;
#pragma unroll
  for (int j = 0; j < 2; ++j) {
    int idx = base + j;
    vals[j] = (j < per && idx < s) ? hist[idx] : 0;
    mysum += vals[j];
  }
  part[tid] = mysum;
  __syncthreads();
  for (int off = 1; off < 256; off <<= 1) {
    int v = (tid >= off) ? part[tid - off] : 0;
    __syncthreads();
    part[tid] += v;
    __syncthreads();
  }
  int run = part[tid] - mysum + wbeg;
#pragma unroll
  for (int j = 0; j < 2; ++j) {
    int idx = base + j;
    if (j < per && idx < s) {
      hist[idx] = run;                         // becomes the live cursor
      offs[r * HSTRIDE + dbase + idx] = run;   // fine CSR offsets
      run += vals[j];
    }
  }
  if (b == 0 && tid == 0) offs[r * HSTRIDE + n] = NE;
  __syncthreads();
  for (int i = wbeg + tid; i < wend; i += 256) {
    int2 e = tr[i];
    int pos = atomicAdd(&hist[e.x - dbase], 1);
    srcw[(size_t)r * NE + pos] = (unsigned)e.y;
  }
}

// ---- bucket walk: m = (sum w_e * hp[src_e]) / deg  (round-10/11-proven body) ----
__device__ __forceinline__ void bucket_msg(const unsigned* __restrict__ sw,
                                           const uint4* __restrict__ hv,
                                           int beg, int end, int half, int c8,
                                           float& m0, float& m1, float& m2, float& m3,
                                           float& m4, float& m5, float& m6, float& m7) {
  float a0 = 0.f, a1 = 0.f, a2 = 0.f, a3 = 0.f, a4 = 0.f, a5 = 0.f, a6 = 0.f, a7 = 0.f;
  float degw = 0.f;
  for (int j = beg; j < end; j += 8) {
    int ib = j + half * 4;
    unsigned e0 = (ib + 0 < end) ? sw[ib + 0] : 0u;
    unsigned e1 = (ib + 1 < end) ? sw[ib + 1] : 0u;
    unsigned e2 = (ib + 2 < end) ? sw[ib + 2] : 0u;
    unsigned e3 = (ib + 3 < end) ? sw[ib + 3] : 0u;
    float w0 = bfhi(e0), w1 = bfhi(e1), w2 = bfhi(e2), w3 = bfhi(e3);
    int s0 = e0 & 0xffff, s1 = e1 & 0xffff, s2 = e2 & 0xffff, s3 = e3 & 0xffff;
    uint4 x0 = hv[(size_t)s0 * 32 + c8];
    uint4 x1 = hv[(size_t)s1 * 32 + c8];
    uint4 x2 = hv[(size_t)s2 * 32 + c8];
    uint4 x3 = hv[(size_t)s3 * 32 + c8];
    degw += (w0 + w1) + (w2 + w3);
    a0 += w0 * bflo(x0.x) + w1 * bflo(x1.x) + w2 * bflo(x2.x) + w3 * bflo(x3.x);
    a1 += w0 * bfhi(x0.x) + w1 * bfhi(x1.x) + w2 * bfhi(x2.x) + w3 * bfhi(x3.x);
    a2 += w0 * bflo(x0.y) + w1 * bflo(x1.y) + w2 * bflo(x2.y) + w3 * bflo(x3.y);
    a3 += w0 * bfhi(x0.y) + w1 * bfhi(x1.y) + w2 * bfhi(x2.y) + w3 * bfhi(x3.y);
    a4 += w0 * bflo(x0.z) + w1 * bflo(x1.z) + w2 * bflo(x2.z) + w3 * bflo(x3.z);
    a5 += w0 * bfhi(x0.z) + w1 * bfhi(x1.z) + w2 * bfhi(x2.z) + w3 * bfhi(x3.z);
    a6 += w0 * bflo(x0.w) + w1 * bflo(x1.w) + w2 * bflo(x2.w) + w3 * bflo(x3.w);
    a7 += w0 * bfhi(x0.w) + w1 * bfhi(x1.w) + w2 * bfhi(x2.w) + w3 * bfhi(x3.w);
  }
  a0 += __shfl_xor(a0, 32); a1 += __shfl_xor(a1, 32);
  a2 += __shfl_xor(a2, 32); a3 += __shfl_xor(a3, 32);
  a4 += __shfl_xor(a4, 32); a5 += __shfl_xor(a5, 32);
  a6 += __shfl_xor(a6, 32); a7 += __shfl_xor(a7, 32);
  degw += __shfl_xor(degw, 32);
  float inv = (degw == 0.f) ? 1.f : 1.f / degw;
  m0 = a0 * inv; m1 = a1 * inv; m2 = a2 * inv; m3 = a3 * inv;
  m4 = a4 * inv; m5 = a5 * inv; m6 = a6 * inv; m7 = a7 * inv;
}

// ---- gather + relation attention: agg[node] = c1*m1 + c2*m2 (bf16) ----
// one wave per node (per dest TYPE); walks BOTH relation buckets of the node.
__global__ __launch_bounds__(256) void gatherAtt_kernel(GATab T) {
  const int bx = blockIdx.x;
  int t = 0;
#pragma unroll
  for (int k = 1; k < 3; ++k) t += (bx >= T.cum[k]);
  const int node = (bx - T.cum[t]) * 4 + (threadIdx.x >> 6);
  const int lane = threadIdx.x & 63;
  const int half = lane >> 5;
  const int c8 = lane & 31;

  const int* ofA = T.ofA[t];
  const int* ofB = T.ofB[t];
  float mA0, mA1, mA2, mA3, mA4, mA5, mA6, mA7;
  float mB0, mB1, mB2, mB3, mB4, mB5, mB6, mB7;
  bucket_msg(T.swA[t], reinterpret_cast<const uint4*>(T.hpA[t]),
             ofA[node], ofA[node + 1], half, c8,
             mA0, mA1, mA2, mA3, mA4, mA5, mA6, mA7);
  bucket_msg(T.swB[t], reinterpret_cast<const uint4*>(T.hpB[t]),
             ofB[node], ofB[node + 1], half, c8,
             mB0, mB1, mB2, mB3, mB4, mB5, mB6, mB7);

  // attention: scores via in-register dots + intra-half shfl reduce, then softmax
  const float4* A1v = reinterpret_cast<const float4*>(T.A1[t]);  // [4][64] float4
  const float4* A2v = reinterpret_cast<const float4*>(T.A2[t]);
  float c1 = 0.f, c2 = 0.f;
#pragma unroll
  for (int hh = 0; hh < 4; ++hh) {
    float4 qa = A1v[hh * 64 + c8 * 2], qb = A1v[hh * 64 + c8 * 2 + 1];
    float4 ra = A2v[hh * 64 + c8 * 2], rb = A2v[hh * 64 + c8 * 2 + 1];
    float sA = mA0 * qa.x + mA1 * qa.y + mA2 * qa.z + mA3 * qa.w
             + mA4 * qb.x + mA5 * qb.y + mA6 * qb.z + mA7 * qb.w;
    float sB = mB0 * ra.x + mB1 * ra.y + mB2 * ra.z + mB3 * ra.w
             + mB4 * rb.x + mB5 * rb.y + mB6 * rb.z + mB7 * rb.w;
#pragma unroll
    for (int o = 1; o <= 16; o <<= 1) { sA += __shfl_xor(sA, o); sB += __shfl_xor(sB, o); }
    // softmax over the 2 relations; scale = 1/(sqrt(256)*0.5) = 0.125
    float s1 = sA * 0.125f, s2 = sB * 0.125f;
    float mx = fmaxf(s1, s2);
    float e1 = __expf(s1 - mx), e2 = __expf(s2 - mx);
    float inv = 1.f / (e1 + e2);
    c1 += e1 * inv; c2 += e2 * inv;
  }
  c1 *= 0.25f; c2 *= 0.25f;  // mean over H=4 heads

  if (half == 0) {
    u32x4 o;
    o.x = (unsigned)f2bf(c1 * mA0 + c2 * mB0) | ((unsigned)f2bf(c1 * mA1 + c2 * mB1) << 16);
    o.y = (unsigned)f2bf(c1 * mA2 + c2 * mB2) | ((unsigned)f2bf(c1 * mA3 + c2 * mB3) << 16);
    o.z = (unsigned)f2bf(c1 * mA4 + c2 * mB4) | ((unsigned)f2bf(c1 * mA5 + c2 * mB5) << 16);
    o.w = (unsigned)f2bf(c1 * mA6 + c2 * mB6) | ((unsigned)f2bf(c1 * mA7 + c2 * mB7) << 16);
    __builtin_nontemporal_store(o, reinterpret_cast<u32x4*>(T.agg[t]) + (size_t)node * 32 + c8);
  }
}

// ---- shared GEMM pieces: 64 rows x (256x256) bf16 MFMA (rounds 6-11 proven) ----
__device__ __forceinline__ void stage_x_f32(const float* __restrict__ g, int r0,
                                            unsigned short* xs, int tid) {
#pragma unroll
  for (int it = 0; it < 16; ++it) {
    int i = it * 256 + tid;
    int row = i >> 6, q = i & 63;
    float4 v = reinterpret_cast<const float4*>(g)[(size_t)(r0 + row) * 64 + q];
    ushort4 b;
    b.x = f2bf(v.x); b.y = f2bf(v.y); b.z = f2bf(v.z); b.w = f2bf(v.w);
    *reinterpret_cast<ushort4*>(&xs[row * 264 + q * 4]) = b;
  }
}

__device__ __forceinline__ void gemm_frag(const unsigned short* xs,
                                          const unsigned short* __restrict__ Wg,
                                          unsigned short* wl, int tid,
                                          f32x4 accv[4][4]) {
  const int wid = tid >> 6, lhi = (tid & 63) >> 4, llo = tid & 15;
  for (int ks = 0; ks < 8; ++ks) {
    const int k0 = ks * 32;
    __syncthreads();  // protects xs (first iter) and wl reads from prev iter
    {
      const uint4* gp = reinterpret_cast<const uint4*>(Wg + (size_t)tid * 256 + k0);
      uint4 a0 = gp[0], a1 = gp[1], a2 = gp[2], a3 = gp[3];
      uint4* lp = reinterpret_cast<uint4*>(wl + tid * 56);
      lp[0] = a0; lp[1] = a1; lp[2] = a2; lp[3] = a3;
    }
    __syncthreads();
    bf16x8 afr[4], bfr[4];
#pragma unroll
    for (int rt = 0; rt < 4; ++rt)
      afr[rt] = *reinterpret_cast<const bf16x8*>(&xs[(rt * 16 + llo) * 264 + k0 + lhi * 8]);
#pragma unroll
    for (int nt = 0; nt < 4; ++nt)
      bfr[nt] = *reinterpret_cast<const bf16x8*>(&wl[(wid * 64 + nt * 16 + llo) * 56 + lhi * 8]);
#pragma unroll
    for (int rt = 0; rt < 4; ++rt)
#pragma unroll
      for (int nt = 0; nt < 4; ++nt)
        accv[rt][nt] = __builtin_amdgcn_mfma_f32_16x16x32_bf16(afr[rt], bfr[nt], accv[rt][nt], 0, 0, 0);
  }
}

__device__ __forceinline__ void writeout_hp(unsigned short* __restrict__ hp, int r0, int tid,
                                            f32x4 accv[4][4]) {
  const int wid = tid >> 6, lane = tid & 63, lhi = lane >> 4, llo = lane & 15;
#pragma unroll
  for (int rt = 0; rt < 4; ++rt)
#pragma unroll
    for (int nt = 0; nt < 4; ++nt) {
      int col = wid * 64 + nt * 16 + llo;
#pragma unroll
      for (int rg = 0; rg < 4; ++rg) {
        int row = rt * 16 + lhi * 4 + rg;
        hp[(size_t)(r0 + row) * DIM + col] = f2bf(accv[rt][nt][rg]);
      }
    }
}

// ---- pre-transform by SOURCE TYPE: stage h once, compute BOTH relations ----
__global__ __launch_bounds__(256) void transformT_kernel(TTy T) {
  __shared__ alignas(16) unsigned short xs[64 * 264];
  __shared__ alignas(16) unsigned short wl[256 * 56];
  const int tid = threadIdx.x;
  const int bx = blockIdx.x;
  int t = 0;
#pragma unroll
  for (int k = 1; k < 3; ++k) t += (bx >= T.cum[k]);
  const int r0 = (bx - T.cum[t]) * 64;

  stage_x_f32(T.h[t], r0, xs, tid);

  f32x4 accv[4][4];
#pragma unroll
  for (int a = 0; a < 4; ++a)
#pragma unroll
    for (int b = 0; b < 4; ++b) accv[a][b] = {0.f, 0.f, 0.f, 0.f};
  gemm_frag(xs, T.wA[t], wl, tid, accv);
  writeout_hp(T.hpA[t], r0, tid, accv);

#pragma unroll
  for (int a = 0; a < 4; ++a)
#pragma unroll
    for (int b = 0; b < 4; ++b) accv[a][b] = {0.f, 0.f, 0.f, 0.f};
  gemm_frag(xs, T.wB[t], wl, tid, accv);  // first barrier inside protects wl reuse
  writeout_hp(T.hpB[t], r0, tid, accv);
}

// ---- per node type: self-GEMM + agg + residual + LN + leaky ----
// (attention already folded into gatherAtt; epilogue reads agg only)
__global__ __launch_bounds__(256) void fuse_kernel(
    const float* __restrict__ h, const unsigned short* __restrict__ agg,
    const unsigned short* __restrict__ Wbf,
    const float* __restrict__ gamma, const float* __restrict__ beta,
    float* __restrict__ out) {
  __shared__ alignas(16) union SM {
    struct { unsigned short x[64 * 264]; unsigned short w[256 * 56]; } g;
    unsigned short s[64 * 260];  // self result, bf16
  } ov;
  __shared__ float sgb[512];
  const int tid = threadIdx.x;
  const int r0 = blockIdx.x * 64;

  stage_x_f32(h, r0, ov.g.x, tid);
  for (int i = tid; i < 512; i += 256) sgb[i] = (i < 256) ? gamma[i] : beta[i - 256];

  f32x4 accv[4][4];
#pragma unroll
  for (int a = 0; a < 4; ++a)
#pragma unroll
    for (int b = 0; b < 4; ++b) accv[a][b] = {0.f, 0.f, 0.f, 0.f};

  gemm_frag(ov.g.x, Wbf, ov.g.w, tid, accv);

  const int wid = tid >> 6, lane = tid & 63, lhi = lane >> 4, llo = lane & 15;
  __syncthreads();  // all MFMA LDS reads done before overlaying ov.s
#pragma unroll
  for (int rt = 0; rt < 4; ++rt)
#pragma unroll
    for (int nt = 0; nt < 4; ++nt) {
      int col = wid * 64 + nt * 16 + llo;
#pragma unroll
      for (int rg = 0; rg < 4; ++rg)
        ov.s[(rt * 16 + lhi * 4 + rg) * 260 + col] = f2bf(accv[rt][nt][rg]);
    }
  __syncthreads();

  // epilogue: wave handles 16 rows; lane owns 4 dims
  const int d0 = lane * 4;
  const float4 g4 = *reinterpret_cast<const float4*>(&sgb[d0]);
  const float4 b4 = *reinterpret_cast<const float4*>(&sgb[256 + d0]);

  for (int rl = 0; rl < 16; ++rl) {
    int row = wid * 16 + rl;
    size_t gb = (size_t)(r0 + row) * DIM + d0;
    ushort4 ab = *reinterpret_cast<const ushort4*>(agg + gb);
    float4 av = {bf2f(ab.x), bf2f(ab.y), bf2f(ab.z), bf2f(ab.w)};
    float4 hvv = *reinterpret_cast<const float4*>(h + gb);
    ushort4 sb = *reinterpret_cast<const ushort4*>(&ov.s[row * 260 + d0]);
    float4 sv = {bf2f(sb.x), bf2f(sb.y), bf2f(sb.z), bf2f(sb.w)};

    float4 u;
    u.x = sv.x + av.x + hvv.x;
    u.y = sv.y + av.y + hvv.y;
    u.z = sv.z + av.z + hvv.z;
    u.w = sv.w + av.w + hvv.w;

    float s1v = u.x + u.y + u.z + u.w;
    float s2v = u.x * u.x + u.y * u.y + u.z * u.z + u.w * u.w;
#pragma unroll
    for (int o = 1; o < 64; o <<= 1) { s1v += __shfl_xor(s1v, o); s2v += __shfl_xor(s2v, o); }
    float mu = s1v * (1.f / 256.f);
    float var = s2v * (1.f / 256.f) - mu * mu;
    float rstd = rsqrtf(var + 1e-5f);

    float4 y;
    y.x = (u.x - mu) * rstd * g4.x + b4.x;
    y.y = (u.y - mu) * rstd * g4.y + b4.y;
    y.z = (u.z - mu) * rstd * g4.z + b4.z;
    y.w = (u.w - mu) * rstd * g4.w + b4.w;
    y.x = fmaxf(y.x, 0.01f * y.x);
    y.y = fmaxf(y.y, 0.01f * y.y);
    y.z = fmaxf(y.z, 0.01f * y.z);
    y.w = fmaxf(y.w, 0.01f * y.w);
    *reinterpret_cast<float4*>(out + gb) = y;
  }
}

// ---- workspace layout (bytes); ~109 MB (< round-11-proven ~138.5 MB) ----
static constexpr size_t AL(size_t x) { return (x + 255) & ~size_t(255); }
// aggregated messages (bf16), one row per node, type-major l|g|d
static constexpr size_t AGG_TOT = (size_t)(NLr + NGr + NDr) * DIM;
// transformed embeddings, all 6 relations, sized by SRC rows
static constexpr size_t HPe_L2G = 0;                                  // NLr
static constexpr size_t HPe_G2L = HPe_L2G + (size_t)NLr * DIM;        // NGr
static constexpr size_t HPe_G2D = HPe_G2L + (size_t)NGr * DIM;        // NGr
static constexpr size_t HPe_D2G = HPe_G2D + (size_t)NGr * DIM;        // NDr
static constexpr size_t HPe_L2D = HPe_D2G + (size_t)NDr * DIM;        // NLr
static constexpr size_t HPe_D2L = HPe_L2D + (size_t)NLr * DIM;        // NDr
static constexpr size_t HP_TOT  = HPe_D2L + (size_t)NDr * DIM;
static constexpr size_t OFF_AGG   = 0;
static constexpr size_t OFF_HP    = AL(OFF_AGG + AGG_TOT * 2);
static constexpr size_t OFF_WBF   = AL(OFF_HP + HP_TOT * 2);
static constexpr size_t OFF_OFFS  = AL(OFF_WBF + 9 * 65536 * 2);
static constexpr size_t OFF_CHIST = AL(OFF_OFFS + 6 * HSTRIDE * 4);   // 384 ints
static constexpr size_t OFF_CBASE = AL(OFF_CHIST + 384 * 4);          // 6*65 ints
static constexpr size_t OFF_CCUR  = AL(OFF_CBASE + 390 * 4);          // 384 ints
static constexpr size_t OFF_TMP   = AL(OFF_CCUR + 384 * 4);           // 6*NE int2
static constexpr size_t OFF_SRCW  = AL(OFF_TMP + (size_t)6 * NE * 8); // 6*NE u32

extern "C" void kernel_launch(void* const* d_in, const int* in_sizes, int n_in,
                              void* d_out, int out_size, void* d_ws, size_t ws_size,
                              hipStream_t stream) {
  char* wsb = (char*)d_ws;
  unsigned short* agg = (unsigned short*)(wsb + OFF_AGG);
  unsigned short* hp  = (unsigned short*)(wsb + OFF_HP);
  unsigned short* wbf = (unsigned short*)(wsb + OFF_WBF);
  int* offs  = (int*)(wsb + OFF_OFFS);
  int* chist = (int*)(wsb + OFF_CHIST);
  int* cbase = (int*)(wsb + OFF_CBASE);
  int* ccur  = (int*)(wsb + OFF_CCUR);
  int2* tmp  = (int2*)(wsb + OFF_TMP);
  unsigned* srcw = (unsigned*)(wsb + OFF_SRCW);
  float* out = (float*)d_out;

  // relation order: l2g, g2l, g2d, d2g, l2d, d2l
  const int base[6] = {3, 8, 13, 18, 23, 28};
  const int ndst[6] = {NGr, NLr, NDr, NGr, NDr, NLr};
  const size_t hpOff[6]  = {HPe_L2G, HPe_G2L, HPe_G2D, HPe_D2G, HPe_L2D, HPe_D2L};

  // merged prep: weight f32->bf16 + coarse dst histogram
  (void)hipMemsetAsync(chist, 0, 384 * 4, stream);
  PrepTab Q; PTab P; NTab N;
  Q.wsrc[0] = (const float*)d_in[6];  Q.wsrc[1] = (const float*)d_in[11];
  Q.wsrc[2] = (const float*)d_in[16]; Q.wsrc[3] = (const float*)d_in[21];
  Q.wsrc[4] = (const float*)d_in[26]; Q.wsrc[5] = (const float*)d_in[31];
  Q.wsrc[6] = (const float*)d_in[33]; Q.wsrc[7] = (const float*)d_in[36];
  Q.wsrc[8] = (const float*)d_in[39];
  for (int r = 0; r < 6; ++r) {
    int sh = (ndst[r] == NGr) ? 9 : (ndst[r] == NLr ? 8 : 7);  // coarse = n>>6
    Q.dst[r] = (const int*)d_in[base[r] + 1];
    Q.shift[r] = sh;
    P.src[r] = (const int*)d_in[base[r]];
    P.dst[r] = (const int*)d_in[base[r] + 1];
    P.w[r]  = (const float*)d_in[base[r] + 2];
    P.shift[r] = sh;
    N.n[r] = ndst[r];
  }
  prep_kernel<<<2304 + 1536, 256, 0, stream>>>(Q, wbf, chist);
  scan384_kernel<<<1, 64, 0, stream>>>(chist, ccur, cbase);

  // two-pass radix partition; partB also derives the fine CSR offsets
  partA6_kernel<<<dim3(NE / 1024, 6), 256, 0, stream>>>(P, ccur, tmp);
  partB6_kernel<<<dim3(64, 6), 256, 0, stream>>>(tmp, cbase, offs, srcw, N);

  // pre-transform by source type: each block computes BOTH relations of its type
  // type l -> {l2g(0), l2d(4)}, type g -> {g2l(1), g2d(2)}, type d -> {d2g(3), d2l(5)}
  TTy T;
  T.h[0] = (const float*)d_in[0]; T.h[1] = (const float*)d_in[1]; T.h[2] = (const float*)d_in[2];
  T.hpA[0] = hp + hpOff[0]; T.hpB[0] = hp + hpOff[4];
  T.hpA[1] = hp + hpOff[1]; T.hpB[1] = hp + hpOff[2];
  T.hpA[2] = hp + hpOff[3]; T.hpB[2] = hp + hpOff[5];
  T.wA[0] = wbf + 0 * 65536; T.wB[0] = wbf + 4 * 65536;
  T.wA[1] = wbf + 1 * 65536; T.wB[1] = wbf + 2 * 65536;
  T.wA[2] = wbf + 3 * 65536; T.wB[2] = wbf + 5 * 65536;
  T.cum[0] = 0; T.cum[1] = NLr / 64; T.cum[2] = (NLr + NGr) / 64; T.cum[3] = (NLr + NGr + NDr) / 64;
  transformT_kernel<<<T.cum[3], 256, 0, stream>>>(T);

  // gather + attention per dest type: l <- {g2l(1), d2l(5)}, g <- {l2g(0), d2g(3)},
  // d <- {g2d(2), l2d(4)}; one wave per node walks both buckets
  GATab G;
  const int relA[3] = {1, 0, 2}, relB[3] = {5, 3, 4};
  const int aA[3] = {12, 7, 17}, aB[3] = {32, 22, 27};
  const size_t aggBase[3] = {0, (size_t)NLr * DIM, (size_t)(NLr + NGr) * DIM};
  for (int t = 0; t < 3; ++t) {
    G.hpA[t] = hp + hpOff[relA[t]];
    G.hpB[t] = hp + hpOff[relB[t]];
    G.swA[t] = srcw + (size_t)relA[t] * NE;
    G.swB[t] = srcw + (size_t)relB[t] * NE;
    G.ofA[t] = offs + relA[t] * HSTRIDE;
    G.ofB[t] = offs + relB[t] * HSTRIDE;
    G.A1[t] = (const float*)d_in[aA[t]];
    G.A2[t] = (const float*)d_in[aB[t]];
    G.agg[t] = agg + aggBase[t];
  }
  G.cum[0] = 0; G.cum[1] = NLr / 4; G.cum[2] = (NLr + NGr) / 4; G.cum[3] = (NLr + NGr + NDr) / 4;
  gatherAtt_kernel<<<G.cum[3], 256, 0, stream>>>(G);

  // fused update per type
  fuse_kernel<<<NLr / 64, 256, 0, stream>>>(
      (const float*)d_in[0], agg + aggBase[0], wbf + 6 * 65536,
      (const float*)d_in[34], (const float*)d_in[35], out);
  fuse_kernel<<<NGr / 64, 256, 0, stream>>>(
      (const float*)d_in[1], agg + aggBase[1], wbf + 7 * 65536,
      (const float*)d_in[37], (const float*)d_in[38], out + (size_t)NLr * DIM);
  fuse_kernel<<<NDr / 64, 256, 0, stream>>>(
      (const float*)d_in[2], agg + aggBase[2], wbf + 8 * 65536,
      (const float*)d_in[40], (const float*)d_in[41], out + (size_t)(NLr + NGr) * DIM);
}

// Round 13
// 289.397 us; speedup vs baseline: 1.5163x; 1.0060x over previous
//
#include <hip/hip_runtime.h>

#define DIM 256
#define NLr 16384
#define NGr 32768
#define NDr 8192
#define NE  262144
#define HSTRIDE 32772  // offs per-relation stride (16B-aligned)

typedef short bf16x8 __attribute__((ext_vector_type(8)));
typedef float f32x4 __attribute__((ext_vector_type(4)));
typedef unsigned u32x4 __attribute__((ext_vector_type(4)));

__device__ __forceinline__ unsigned short f2bf(float f) {
  unsigned int u = __builtin_bit_cast(unsigned int, f);
  u += 0x7fffu + ((u >> 16) & 1u);
  return (unsigned short)(u >> 16);
}
__device__ __forceinline__ float bf2f(unsigned short b) {
  return __builtin_bit_cast(float, ((unsigned int)b) << 16);
}
__device__ __forceinline__ float bflo(unsigned int u) {
  return __builtin_bit_cast(float, u << 16);
}
__device__ __forceinline__ float bfhi(unsigned int u) {
  return __builtin_bit_cast(float, u & 0xffff0000u);
}

struct NTab { int n[6]; };
struct PrepTab { const float* wsrc[9]; const int* dst[6]; int shift[6]; };
struct PTab { const int* src[6]; const int* dst[6]; const float* w[6]; int shift[6]; };
struct TTy { const float* h[3]; unsigned short* hpA[3]; unsigned short* hpB[3];
             const unsigned short* wA[3]; const unsigned short* wB[3]; int cum[4]; };
struct GATab { const unsigned short* hpA[3]; const unsigned short* hpB[3];
               const unsigned* swA[3]; const unsigned* swB[3];
               const int* ofA[3]; const int* ofB[3];
               const float* A1[3]; const float* A2[3];
               unsigned short* agg[3]; int cum[4]; };

// ---- merged prep: blocks [0,2304) convert 9 weight mats; [2304,3840) coarse hist ----
__global__ __launch_bounds__(256) void prep_kernel(PrepTab Q, unsigned short* __restrict__ wbf,
                                                   int* __restrict__ chist) {
  const int bid = blockIdx.x, tid = threadIdx.x;
  __shared__ int h[64];
  if (bid < 2304) {
    int m = bid >> 8;
    int i = (bid & 255) * 256 + tid;
    wbf[m * 65536 + i] = f2bf(Q.wsrc[m][i]);
  } else {
    int b2 = bid - 2304;
    int r = b2 >> 8;          // 256 blocks per relation, 1024 edges each
    int blk = b2 & 255;
    if (tid < 64) h[tid] = 0;
    __syncthreads();
    const int* dp = Q.dst[r] + blk * 1024;
    const int sh = Q.shift[r];
#pragma unroll
    for (int k = 0; k < 4; ++k) atomicAdd(&h[dp[k * 256 + tid] >> sh], 1);
    __syncthreads();
    if (tid < 64) { int c = h[tid]; if (c) atomicAdd(&chist[r * 64 + tid], c); }
  }
}

// ---- tiny coarse scan: ccur (working cursor) + cbase (read-only windows) ----
__global__ void scan384_kernel(const int* __restrict__ chist, int* __restrict__ ccur,
                               int* __restrict__ cbase) {
  int r = threadIdx.x;
  if (r < 6) {
    int off = 0;
    for (int b = 0; b < 64; ++b) {
      ccur[r * 64 + b] = off;
      cbase[r * 65 + b] = off;
      off += chist[r * 64 + b];
    }
    cbase[r * 65 + 64] = off;  // == NE
  }
}

// ---- partition pass A: coarse 64-bucket partition into tmp (dst, packed) ----
__global__ __launch_bounds__(256) void partA6_kernel(PTab P, int* __restrict__ ccur,
                                                     int2* __restrict__ tmp) {
  int r = blockIdx.y;
  const int tid = threadIdx.x;
  __shared__ int hist[64], lbase[64], lcur[64];
  if (tid < 64) { hist[tid] = 0; lcur[tid] = 0; }
  __syncthreads();
  const int ebase = blockIdx.x * 1024;
  const int sh = P.shift[r];
  int dsts[4]; unsigned pk[4]; int bks[4];
#pragma unroll
  for (int k = 0; k < 4; ++k) {
    int e = ebase + k * 256 + tid;
    int d = P.dst[r][e];
    dsts[k] = d;
    pk[k] = (unsigned)P.src[r][e] | ((unsigned)f2bf(P.w[r][e]) << 16);
    bks[k] = d >> sh;
    atomicAdd(&hist[bks[k]], 1);
  }
  __syncthreads();
  if (tid < 64) {
    int c = hist[tid];
    if (c) lbase[tid] = atomicAdd(&ccur[r * 64 + tid], c);
  }
  __syncthreads();
#pragma unroll
  for (int k = 0; k < 4; ++k) {
    int pos = lbase[bks[k]] + atomicAdd(&lcur[bks[k]], 1);
    tmp[(size_t)r * NE + pos] = make_int2(dsts[k], (int)pk[k]);
  }
}

// ---- shared GEMM pieces: 64 rows x (256x256) bf16 MFMA (rounds 6-12 proven) ----
__device__ __forceinline__ void stage_x_f32(const float* __restrict__ g, int r0,
                                            unsigned short* xs, int tid) {
#pragma unroll
  for (int it = 0; it < 16; ++it) {
    int i = it * 256 + tid;
    int row = i >> 6, q = i & 63;
    float4 v = reinterpret_cast<const float4*>(g)[(size_t)(r0 + row) * 64 + q];
    ushort4 b;
    b.x = f2bf(v.x); b.y = f2bf(v.y); b.z = f2bf(v.z); b.w = f2bf(v.w);
    *reinterpret_cast<ushort4*>(&xs[row * 264 + q * 4]) = b;
  }
}

__device__ __forceinline__ void gemm_frag(const unsigned short* xs,
                                          const unsigned short* __restrict__ Wg,
                                          unsigned short* wl, int tid,
                                          f32x4 accv[4][4]) {
  const int wid = tid >> 6, lhi = (tid & 63) >> 4, llo = tid & 15;
  for (int ks = 0; ks < 8; ++ks) {
    const int k0 = ks * 32;
    __syncthreads();  // protects xs (first iter) and wl reads from prev iter
    {
      const uint4* gp = reinterpret_cast<const uint4*>(Wg + (size_t)tid * 256 + k0);
      uint4 a0 = gp[0], a1 = gp[1], a2 = gp[2], a3 = gp[3];
      uint4* lp = reinterpret_cast<uint4*>(wl + tid * 56);
      lp[0] = a0; lp[1] = a1; lp[2] = a2; lp[3] = a3;
    }
    __syncthreads();
    bf16x8 afr[4], bfr[4];
#pragma unroll
    for (int rt = 0; rt < 4; ++rt)
      afr[rt] = *reinterpret_cast<const bf16x8*>(&xs[(rt * 16 + llo) * 264 + k0 + lhi * 8]);
#pragma unroll
    for (int nt = 0; nt < 4; ++nt)
      bfr[nt] = *reinterpret_cast<const bf16x8*>(&wl[(wid * 64 + nt * 16 + llo) * 56 + lhi * 8]);
#pragma unroll
    for (int rt = 0; rt < 4; ++rt)
#pragma unroll
      for (int nt = 0; nt < 4; ++nt)
        accv[rt][nt] = __builtin_amdgcn_mfma_f32_16x16x32_bf16(afr[rt], bfr[nt], accv[rt][nt], 0, 0, 0);
  }
}

__device__ __forceinline__ void writeout_hp(unsigned short* __restrict__ hp, int r0, int tid,
                                            f32x4 accv[4][4]) {
  const int wid = tid >> 6, lane = tid & 63, lhi = lane >> 4, llo = lane & 15;
#pragma unroll
  for (int rt = 0; rt < 4; ++rt)
#pragma unroll
    for (int nt = 0; nt < 4; ++nt) {
      int col = wid * 64 + nt * 16 + llo;
#pragma unroll
      for (int rg = 0; rg < 4; ++rg) {
        int row = rt * 16 + lhi * 4 + rg;
        hp[(size_t)(r0 + row) * DIM + col] = f2bf(accv[rt][nt][rg]);
      }
    }
}

// ---- mid kernel: partB (blocks [0,384)) ∥ transformT (blocks [384,1280)) ----
// partB: fine hist + block scan -> offs, then exact placement (round-11 proven)
// transformT: hp = h_src @ W.T for both relations of the source type (round-10 proven)
__global__ __launch_bounds__(256) void mid_kernel(const int2* __restrict__ tmp,
                                                  const int* __restrict__ cbase,
                                                  int* __restrict__ offs,
                                                  unsigned* __restrict__ srcw,
                                                  NTab N, TTy T) {
  __shared__ union alignas(16) SM {
    struct { unsigned short xs[64 * 264]; unsigned short wl[256 * 56]; } t;
    struct { int hist[512]; int part[256]; } p;
  } sm;
  const int bid = blockIdx.x, tid = threadIdx.x;

  if (bid < 384) {
    // ---------------- partB path ----------------
    int r = bid >> 6, b = bid & 63;
    const int n = N.n[r], s = n >> 6;
    const int dbase = b * s;
    int* hist = sm.p.hist;
    int* part = sm.p.part;
    for (int i = tid; i < s; i += 256) hist[i] = 0;
    __syncthreads();
    const int wbeg = cbase[r * 65 + b], wend = cbase[r * 65 + b + 1];
    const int2* __restrict__ tr = tmp + (size_t)r * NE;
    for (int i = wbeg + tid; i < wend; i += 256)
      atomicAdd(&hist[tr[i].x - dbase], 1);
    __syncthreads();
    const int per = (s > 256) ? 2 : 1;
    const int base = tid * per;
    int vals[2];
    int mysum = 0;
#pragma unroll
    for (int j = 0; j < 2; ++j) {
      int idx = base + j;
      vals[j] = (j < per && idx < s) ? hist[idx] : 0;
      mysum += vals[j];
    }
    part[tid] = mysum;
    __syncthreads();
    for (int off = 1; off < 256; off <<= 1) {
      int v = (tid >= off) ? part[tid - off] : 0;
      __syncthreads();
      part[tid] += v;
      __syncthreads();
    }
    int run = part[tid] - mysum + wbeg;
#pragma unroll
    for (int j = 0; j < 2; ++j) {
      int idx = base + j;
      if (j < per && idx < s) {
        hist[idx] = run;                         // becomes the live cursor
        offs[r * HSTRIDE + dbase + idx] = run;   // fine CSR offsets
        run += vals[j];
      }
    }
    if (b == 0 && tid == 0) offs[r * HSTRIDE + n] = NE;
    __syncthreads();
    for (int i = wbeg + tid; i < wend; i += 256) {
      int2 e = tr[i];
      int pos = atomicAdd(&hist[e.x - dbase], 1);
      srcw[(size_t)r * NE + pos] = (unsigned)e.y;
    }
  } else {
    // ---------------- transformT path ----------------
    const int bx = bid - 384;
    int t = 0;
#pragma unroll
    for (int k = 1; k < 3; ++k) t += (bx >= T.cum[k]);
    const int r0 = (bx - T.cum[t]) * 64;

    stage_x_f32(T.h[t], r0, sm.t.xs, tid);

    f32x4 accv[4][4];
#pragma unroll
    for (int a = 0; a < 4; ++a)
#pragma unroll
      for (int b2 = 0; b2 < 4; ++b2) accv[a][b2] = {0.f, 0.f, 0.f, 0.f};
    gemm_frag(sm.t.xs, T.wA[t], sm.t.wl, tid, accv);
    writeout_hp(T.hpA[t], r0, tid, accv);

#pragma unroll
    for (int a = 0; a < 4; ++a)
#pragma unroll
      for (int b2 = 0; b2 < 4; ++b2) accv[a][b2] = {0.f, 0.f, 0.f, 0.f};
    gemm_frag(sm.t.xs, T.wB[t], sm.t.wl, tid, accv);  // first barrier inside protects wl reuse
    writeout_hp(T.hpB[t], r0, tid, accv);
  }
}

// ---- gather + relation attention: agg[node] = c1*mA + c2*mB (bf16) ----
// one wave per node; walks BOTH relation buckets INTERLEAVED (loads co-issued).
__global__ __launch_bounds__(256) void gatherAtt_kernel(GATab T) {
  const int bx = blockIdx.x;
  int t = 0;
#pragma unroll
  for (int k = 1; k < 3; ++k) t += (bx >= T.cum[k]);
  const int node = (bx - T.cum[t]) * 4 + (threadIdx.x >> 6);
  const int lane = threadIdx.x & 63;
  const int half = lane >> 5;
  const int c8 = lane & 31;

  const int* ofA = T.ofA[t];
  const int* ofB = T.ofB[t];
  const int begA = ofA[node], endA = ofA[node + 1];
  const int begB = ofB[node], endB = ofB[node + 1];
  const unsigned* __restrict__ swA = T.swA[t];
  const unsigned* __restrict__ swB = T.swB[t];
  const uint4* __restrict__ hvA = reinterpret_cast<const uint4*>(T.hpA[t]);
  const uint4* __restrict__ hvB = reinterpret_cast<const uint4*>(T.hpB[t]);

  float aA0 = 0.f, aA1 = 0.f, aA2 = 0.f, aA3 = 0.f, aA4 = 0.f, aA5 = 0.f, aA6 = 0.f, aA7 = 0.f;
  float aB0 = 0.f, aB1 = 0.f, aB2 = 0.f, aB3 = 0.f, aB4 = 0.f, aB5 = 0.f, aB6 = 0.f, aB7 = 0.f;
  float degA = 0.f, degB = 0.f;
  int jA = begA, jB = begB;
  while (jA < endA || jB < endB) {
    // issue ALL edge-word loads first, then ALL row loads, then FMAs —
    // keeps 8 row loads in flight per iteration across both buckets.
    int iA = jA + half * 4, iB = jB + half * 4;
    unsigned eA0 = (iA + 0 < endA) ? swA[iA + 0] : 0u;
    unsigned eA1 = (iA + 1 < endA) ? swA[iA + 1] : 0u;
    unsigned eA2 = (iA + 2 < endA) ? swA[iA + 2] : 0u;
    unsigned eA3 = (iA + 3 < endA) ? swA[iA + 3] : 0u;
    unsigned eB0 = (iB + 0 < endB) ? swB[iB + 0] : 0u;
    unsigned eB1 = (iB + 1 < endB) ? swB[iB + 1] : 0u;
    unsigned eB2 = (iB + 2 < endB) ? swB[iB + 2] : 0u;
    unsigned eB3 = (iB + 3 < endB) ? swB[iB + 3] : 0u;
    uint4 xA0 = hvA[(size_t)(eA0 & 0xffff) * 32 + c8];
    uint4 xA1 = hvA[(size_t)(eA1 & 0xffff) * 32 + c8];
    uint4 xA2 = hvA[(size_t)(eA2 & 0xffff) * 32 + c8];
    uint4 xA3 = hvA[(size_t)(eA3 & 0xffff) * 32 + c8];
    uint4 xB0 = hvB[(size_t)(eB0 & 0xffff) * 32 + c8];
    uint4 xB1 = hvB[(size_t)(eB1 & 0xffff) * 32 + c8];
    uint4 xB2 = hvB[(size_t)(eB2 & 0xffff) * 32 + c8];
    uint4 xB3 = hvB[(size_t)(eB3 & 0xffff) * 32 + c8];
    float wA0 = bfhi(eA0), wA1 = bfhi(eA1), wA2 = bfhi(eA2), wA3 = bfhi(eA3);
    float wB0 = bfhi(eB0), wB1 = bfhi(eB1), wB2 = bfhi(eB2), wB3 = bfhi(eB3);
    degA += (wA0 + wA1) + (wA2 + wA3);
    degB += (wB0 + wB1) + (wB2 + wB3);
    aA0 += wA0 * bflo(xA0.x) + wA1 * bflo(xA1.x) + wA2 * bflo(xA2.x) + wA3 * bflo(xA3.x);
    aA1 += wA0 * bfhi(xA0.x) + wA1 * bfhi(xA1.x) + wA2 * bfhi(xA2.x) + wA3 * bfhi(xA3.x);
    aA2 += wA0 * bflo(xA0.y) + wA1 * bflo(xA1.y) + wA2 * bflo(xA2.y) + wA3 * bflo(xA3.y);
    aA3 += wA0 * bfhi(xA0.y) + wA1 * bfhi(xA1.y) + wA2 * bfhi(xA2.y) + wA3 * bfhi(xA3.y);
    aA4 += wA0 * bflo(xA0.z) + wA1 * bflo(xA1.z) + wA2 * bflo(xA2.z) + wA3 * bflo(xA3.z);
    aA5 += wA0 * bfhi(xA0.z) + wA1 * bfhi(xA1.z) + wA2 * bfhi(xA2.z) + wA3 * bfhi(xA3.z);
    aA6 += wA0 * bflo(xA0.w) + wA1 * bflo(xA1.w) + wA2 * bflo(xA2.w) + wA3 * bflo(xA3.w);
    aA7 += wA0 * bfhi(xA0.w) + wA1 * bfhi(xA1.w) + wA2 * bfhi(xA2.w) + wA3 * bfhi(xA3.w);
    aB0 += wB0 * bflo(xB0.x) + wB1 * bflo(xB1.x) + wB2 * bflo(xB2.x) + wB3 * bflo(xB3.x);
    aB1 += wB0 * bfhi(xB0.x) + wB1 * bfhi(xB1.x) + wB2 * bfhi(xB2.x) + wB3 * bfhi(xB3.x);
    aB2 += wB0 * bflo(xB0.y) + wB1 * bflo(xB1.y) + wB2 * bflo(xB2.y) + wB3 * bflo(xB3.y);
    aB3 += wB0 * bfhi(xB0.y) + wB1 * bfhi(xB1.y) + wB2 * bfhi(xB2.y) + wB3 * bfhi(xB3.y);
    aB4 += wB0 * bflo(xB0.z) + wB1 * bflo(xB1.z) + wB2 * bflo(xB2.z) + wB3 * bflo(xB3.z);
    aB5 += wB0 * bfhi(xB0.z) + wB1 * bfhi(xB1.z) + wB2 * bfhi(xB2.z) + wB3 * bfhi(xB3.z);
    aB6 += wB0 * bflo(xB0.w) + wB1 * bflo(xB1.w) + wB2 * bflo(xB2.w) + wB3 * bflo(xB3.w);
    aB7 += wB0 * bfhi(xB0.w) + wB1 * bfhi(xB1.w) + wB2 * bfhi(xB2.w) + wB3 * bfhi(xB3.w);
    jA += 8; jB += 8;
  }
  aA0 += __shfl_xor(aA0, 32); aA1 += __shfl_xor(aA1, 32);
  aA2 += __shfl_xor(aA2, 32); aA3 += __shfl_xor(aA3, 32);
  aA4 += __shfl_xor(aA4, 32); aA5 += __shfl_xor(aA5, 32);
  aA6 += __shfl_xor(aA6, 32); aA7 += __shfl_xor(aA7, 32);
  aB0 += __shfl_xor(aB0, 32); aB1 += __shfl_xor(aB1, 32);
  aB2 += __shfl_xor(aB2, 32); aB3 += __shfl_xor(aB3, 32);
  aB4 += __shfl_xor(aB4, 32); aB5 += __shfl_xor(aB5, 32);
  aB6 += __shfl_xor(aB6, 32); aB7 += __shfl_xor(aB7, 32);
  degA += __shfl_xor(degA, 32);
  degB += __shfl_xor(degB, 32);
  float invA = (degA == 0.f) ? 1.f : 1.f / degA;
  float invB = (degB == 0.f) ? 1.f : 1.f / degB;
  float mA0 = aA0 * invA, mA1 = aA1 * invA, mA2 = aA2 * invA, mA3 = aA3 * invA;
  float mA4 = aA4 * invA, mA5 = aA5 * invA, mA6 = aA6 * invA, mA7 = aA7 * invA;
  float mB0 = aB0 * invB, mB1 = aB1 * invB, mB2 = aB2 * invB, mB3 = aB3 * invB;
  float mB4 = aB4 * invB, mB5 = aB5 * invB, mB6 = aB6 * invB, mB7 = aB7 * invB;

  // attention: scores via in-register dots + intra-half shfl reduce, then softmax
  const float4* A1v = reinterpret_cast<const float4*>(T.A1[t]);  // [4][64] float4
  const float4* A2v = reinterpret_cast<const float4*>(T.A2[t]);
  float c1 = 0.f, c2 = 0.f;
#pragma unroll
  for (int hh = 0; hh < 4; ++hh) {
    float4 qa = A1v[hh * 64 + c8 * 2], qb = A1v[hh * 64 + c8 * 2 + 1];
    float4 ra = A2v[hh * 64 + c8 * 2], rb = A2v[hh * 64 + c8 * 2 + 1];
    float sA = mA0 * qa.x + mA1 * qa.y + mA2 * qa.z + mA3 * qa.w
             + mA4 * qb.x + mA5 * qb.y + mA6 * qb.z + mA7 * qb.w;
    float sB = mB0 * ra.x + mB1 * ra.y + mB2 * ra.z + mB3 * ra.w
             + mB4 * rb.x + mB5 * rb.y + mB6 * rb.z + mB7 * rb.w;
#pragma unroll
    for (int o = 1; o <= 16; o <<= 1) { sA += __shfl_xor(sA, o); sB += __shfl_xor(sB, o); }
    // softmax over the 2 relations; scale = 1/(sqrt(256)*0.5) = 0.125
    float s1 = sA * 0.125f, s2 = sB * 0.125f;
    float mx = fmaxf(s1, s2);
    float e1 = __expf(s1 - mx), e2 = __expf(s2 - mx);
    float inv = 1.f / (e1 + e2);
    c1 += e1 * inv; c2 += e2 * inv;
  }
  c1 *= 0.25f; c2 *= 0.25f;  // mean over H=4 heads

  if (half == 0) {
    u32x4 o;
    o.x = (unsigned)f2bf(c1 * mA0 + c2 * mB0) | ((unsigned)f2bf(c1 * mA1 + c2 * mB1) << 16);
    o.y = (unsigned)f2bf(c1 * mA2 + c2 * mB2) | ((unsigned)f2bf(c1 * mA3 + c2 * mB3) << 16);
    o.z = (unsigned)f2bf(c1 * mA4 + c2 * mB4) | ((unsigned)f2bf(c1 * mA5 + c2 * mB5) << 16);
    o.w = (unsigned)f2bf(c1 * mA6 + c2 * mB6) | ((unsigned)f2bf(c1 * mA7 + c2 * mB7) << 16);
    __builtin_nontemporal_store(o, reinterpret_cast<u32x4*>(T.agg[t]) + (size_t)node * 32 + c8);
  }
}

// ---- per node type: self-GEMM + agg + residual + LN + leaky (round-12 proven) ----
__global__ __launch_bounds__(256) void fuse_kernel(
    const float* __restrict__ h, const unsigned short* __restrict__ agg,
    const unsigned short* __restrict__ Wbf,
    const float* __restrict__ gamma, const float* __restrict__ beta,
    float* __restrict__ out) {
  __shared__ alignas(16) union SM {
    struct { unsigned short x[64 * 264]; unsigned short w[256 * 56]; } g;
    unsigned short s[64 * 260];  // self result, bf16
  } ov;
  __shared__ float sgb[512];
  const int tid = threadIdx.x;
  const int r0 = blockIdx.x * 64;

  stage_x_f32(h, r0, ov.g.x, tid);
  for (int i = tid; i < 512; i += 256) sgb[i] = (i < 256) ? gamma[i] : beta[i - 256];

  f32x4 accv[4][4];
#pragma unroll
  for (int a = 0; a < 4; ++a)
#pragma unroll
    for (int b = 0; b < 4; ++b) accv[a][b] = {0.f, 0.f, 0.f, 0.f};

  gemm_frag(ov.g.x, Wbf, ov.g.w, tid, accv);

  const int wid = tid >> 6, lane = tid & 63, lhi = lane >> 4, llo = lane & 15;
  __syncthreads();  // all MFMA LDS reads done before overlaying ov.s
#pragma unroll
  for (int rt = 0; rt < 4; ++rt)
#pragma unroll
    for (int nt = 0; nt < 4; ++nt) {
      int col = wid * 64 + nt * 16 + llo;
#pragma unroll
      for (int rg = 0; rg < 4; ++rg)
        ov.s[(rt * 16 + lhi * 4 + rg) * 260 + col] = f2bf(accv[rt][nt][rg]);
    }
  __syncthreads();

  // epilogue: wave handles 16 rows; lane owns 4 dims
  const int d0 = lane * 4;
  const float4 g4 = *reinterpret_cast<const float4*>(&sgb[d0]);
  const float4 b4 = *reinterpret_cast<const float4*>(&sgb[256 + d0]);

  for (int rl = 0; rl < 16; ++rl) {
    int row = wid * 16 + rl;
    size_t gb = (size_t)(r0 + row) * DIM + d0;
    ushort4 ab = *reinterpret_cast<const ushort4*>(agg + gb);
    float4 av = {bf2f(ab.x), bf2f(ab.y), bf2f(ab.z), bf2f(ab.w)};
    float4 hvv = *reinterpret_cast<const float4*>(h + gb);
    ushort4 sb = *reinterpret_cast<const ushort4*>(&ov.s[row * 260 + d0]);
    float4 sv = {bf2f(sb.x), bf2f(sb.y), bf2f(sb.z), bf2f(sb.w)};

    float4 u;
    u.x = sv.x + av.x + hvv.x;
    u.y = sv.y + av.y + hvv.y;
    u.z = sv.z + av.z + hvv.z;
    u.w = sv.w + av.w + hvv.w;

    float s1v = u.x + u.y + u.z + u.w;
    float s2v = u.x * u.x + u.y * u.y + u.z * u.z + u.w * u.w;
#pragma unroll
    for (int o = 1; o < 64; o <<= 1) { s1v += __shfl_xor(s1v, o); s2v += __shfl_xor(s2v, o); }
    float mu = s1v * (1.f / 256.f);
    float var = s2v * (1.f / 256.f) - mu * mu;
    float rstd = rsqrtf(var + 1e-5f);

    float4 y;
    y.x = (u.x - mu) * rstd * g4.x + b4.x;
    y.y = (u.y - mu) * rstd * g4.y + b4.y;
    y.z = (u.z - mu) * rstd * g4.z + b4.z;
    y.w = (u.w - mu) * rstd * g4.w + b4.w;
    y.x = fmaxf(y.x, 0.01f * y.x);
    y.y = fmaxf(y.y, 0.01f * y.y);
    y.z = fmaxf(y.z, 0.01f * y.z);
    y.w = fmaxf(y.w, 0.01f * y.w);
    *reinterpret_cast<float4*>(out + gb) = y;
  }
}

// ---- workspace layout (bytes); ~109 MB (< proven ~139 MB) ----
static constexpr size_t AL(size_t x) { return (x + 255) & ~size_t(255); }
// aggregated messages (bf16), one row per node, type-major l|g|d
static constexpr size_t AGG_TOT = (size_t)(NLr + NGr + NDr) * DIM;
// transformed embeddings, all 6 relations, sized by SRC rows
static constexpr size_t HPe_L2G = 0;                                  // NLr
static constexpr size_t HPe_G2L = HPe_L2G + (size_t)NLr * DIM;        // NGr
static constexpr size_t HPe_G2D = HPe_G2L + (size_t)NGr * DIM;        // NGr
static constexpr size_t HPe_D2G = HPe_G2D + (size_t)NGr * DIM;        // NDr
static constexpr size_t HPe_L2D = HPe_D2G + (size_t)NDr * DIM;        // NLr
static constexpr size_t HPe_D2L = HPe_L2D + (size_t)NLr * DIM;        // NDr
static constexpr size_t HP_TOT  = HPe_D2L + (size_t)NDr * DIM;
static constexpr size_t OFF_AGG   = 0;
static constexpr size_t OFF_HP    = AL(OFF_AGG + AGG_TOT * 2);
static constexpr size_t OFF_WBF   = AL(OFF_HP + HP_TOT * 2);
static constexpr size_t OFF_OFFS  = AL(OFF_WBF + 9 * 65536 * 2);
static constexpr size_t OFF_CHIST = AL(OFF_OFFS + 6 * HSTRIDE * 4);   // 384 ints
static constexpr size_t OFF_CBASE = AL(OFF_CHIST + 384 * 4);          // 6*65 ints
static constexpr size_t OFF_CCUR  = AL(OFF_CBASE + 390 * 4);          // 384 ints
static constexpr size_t OFF_TMP   = AL(OFF_CCUR + 384 * 4);           // 6*NE int2
static constexpr size_t OFF_SRCW  = AL(OFF_TMP + (size_t)6 * NE * 8); // 6*NE u32

extern "C" void kernel_launch(void* const* d_in, const int* in_sizes, int n_in,
                              void* d_out, int out_size, void* d_ws, size_t ws_size,
                              hipStream_t stream) {
  char* wsb = (char*)d_ws;
  unsigned short* agg = (unsigned short*)(wsb + OFF_AGG);
  unsigned short* hp  = (unsigned short*)(wsb + OFF_HP);
  unsigned short* wbf = (unsigned short*)(wsb + OFF_WBF);
  int* offs  = (int*)(wsb + OFF_OFFS);
  int* chist = (int*)(wsb + OFF_CHIST);
  int* cbase = (int*)(wsb + OFF_CBASE);
  int* ccur  = (int*)(wsb + OFF_CCUR);
  int2* tmp  = (int2*)(wsb + OFF_TMP);
  unsigned* srcw = (unsigned*)(wsb + OFF_SRCW);
  float* out = (float*)d_out;

  // relation order: l2g, g2l, g2d, d2g, l2d, d2l
  const int base[6] = {3, 8, 13, 18, 23, 28};
  const int ndst[6] = {NGr, NLr, NDr, NGr, NDr, NLr};
  const size_t hpOff[6]  = {HPe_L2G, HPe_G2L, HPe_G2D, HPe_D2G, HPe_L2D, HPe_D2L};

  // merged prep: weight f32->bf16 + coarse dst histogram
  (void)hipMemsetAsync(chist, 0, 384 * 4, stream);
  PrepTab Q; PTab P; NTab N;
  Q.wsrc[0] = (const float*)d_in[6];  Q.wsrc[1] = (const float*)d_in[11];
  Q.wsrc[2] = (const float*)d_in[16]; Q.wsrc[3] = (const float*)d_in[21];
  Q.wsrc[4] = (const float*)d_in[26]; Q.wsrc[5] = (const float*)d_in[31];
  Q.wsrc[6] = (const float*)d_in[33]; Q.wsrc[7] = (const float*)d_in[36];
  Q.wsrc[8] = (const float*)d_in[39];
  for (int r = 0; r < 6; ++r) {
    int sh = (ndst[r] == NGr) ? 9 : (ndst[r] == NLr ? 8 : 7);  // coarse = n>>6
    Q.dst[r] = (const int*)d_in[base[r] + 1];
    Q.shift[r] = sh;
    P.src[r] = (const int*)d_in[base[r]];
    P.dst[r] = (const int*)d_in[base[r] + 1];
    P.w[r]  = (const float*)d_in[base[r] + 2];
    P.shift[r] = sh;
    N.n[r] = ndst[r];
  }
  prep_kernel<<<2304 + 1536, 256, 0, stream>>>(Q, wbf, chist);
  scan384_kernel<<<1, 64, 0, stream>>>(chist, ccur, cbase);

  // partition pass A (coarse)
  partA6_kernel<<<dim3(NE / 1024, 6), 256, 0, stream>>>(P, ccur, tmp);

  // mid: partB (fine placement + offs) OVERLAPPED with transformT (independent)
  // type l -> {l2g(0), l2d(4)}, type g -> {g2l(1), g2d(2)}, type d -> {d2g(3), d2l(5)}
  TTy T;
  T.h[0] = (const float*)d_in[0]; T.h[1] = (const float*)d_in[1]; T.h[2] = (const float*)d_in[2];
  T.hpA[0] = hp + hpOff[0]; T.hpB[0] = hp + hpOff[4];
  T.hpA[1] = hp + hpOff[1]; T.hpB[1] = hp + hpOff[2];
  T.hpA[2] = hp + hpOff[3]; T.hpB[2] = hp + hpOff[5];
  T.wA[0] = wbf + 0 * 65536; T.wB[0] = wbf + 4 * 65536;
  T.wA[1] = wbf + 1 * 65536; T.wB[1] = wbf + 2 * 65536;
  T.wA[2] = wbf + 3 * 65536; T.wB[2] = wbf + 5 * 65536;
  T.cum[0] = 0; T.cum[1] = NLr / 64; T.cum[2] = (NLr + NGr) / 64; T.cum[3] = (NLr + NGr + NDr) / 64;
  mid_kernel<<<384 + 896, 256, 0, stream>>>(tmp, cbase, offs, srcw, N, T);

  // gather + attention per dest type: l <- {g2l(1), d2l(5)}, g <- {l2g(0), d2g(3)},
  // d <- {g2d(2), l2d(4)}; one wave per node walks both buckets interleaved
  GATab G;
  const int relA[3] = {1, 0, 2}, relB[3] = {5, 3, 4};
  const int aA[3] = {12, 7, 17}, aB[3] = {32, 22, 27};
  const size_t aggBase[3] = {0, (size_t)NLr * DIM, (size_t)(NLr + NGr) * DIM};
  for (int t = 0; t < 3; ++t) {
    G.hpA[t] = hp + hpOff[relA[t]];
    G.hpB[t] = hp + hpOff[relB[t]];
    G.swA[t] = srcw + (size_t)relA[t] * NE;
    G.swB[t] = srcw + (size_t)relB[t] * NE;
    G.ofA[t] = offs + relA[t] * HSTRIDE;
    G.ofB[t] = offs + relB[t] * HSTRIDE;
    G.A1[t] = (const float*)d_in[aA[t]];
    G.A2[t] = (const float*)d_in[aB[t]];
    G.agg[t] = agg + aggBase[t];
  }
  G.cum[0] = 0; G.cum[1] = NLr / 4; G.cum[2] = (NLr + NGr) / 4; G.cum[3] = (NLr + NGr + NDr) / 4;
  gatherAtt_kernel<<<G.cum[3], 256, 0, stream>>>(G);

  // fused update per type
  fuse_kernel<<<NLr / 64, 256, 0, stream>>>(
      (const float*)d_in[0], agg + aggBase[0], wbf + 6 * 65536,
      (const float*)d_in[34], (const float*)d_in[35], out);
  fuse_kernel<<<NGr / 64, 256, 0, stream>>>(
      (const float*)d_in[1], agg + aggBase[1], wbf + 7 * 65536,
      (const float*)d_in[37], (const float*)d_in[38], out + (size_t)NLr * DIM);
  fuse_kernel<<<NDr / 64, 256, 0, stream>>>(
      (const float*)d_in[2], agg + aggBase[2], wbf + 8 * 65536,
      (const float*)d_in[40], (const float*)d_in[41], out + (size_t)(NLr + NGr) * DIM);
}

// Round 14
// 266.560 us; speedup vs baseline: 1.6462x; 1.0857x over previous
//
#include <hip/hip_runtime.h>

#define DIM 256
#define NLr 16384
#define NGr 32768
#define NDr 8192
#define NE  262144
#define HSTRIDE 32772  // offs per-relation stride (16B-aligned)

typedef short bf16x8 __attribute__((ext_vector_type(8)));
typedef float f32x4 __attribute__((ext_vector_type(4)));
typedef float f32x2 __attribute__((ext_vector_type(2)));
typedef unsigned u32x4 __attribute__((ext_vector_type(4)));

__device__ __forceinline__ unsigned short f2bf(float f) {
  unsigned int u = __builtin_bit_cast(unsigned int, f);
  u += 0x7fffu + ((u >> 16) & 1u);
  return (unsigned short)(u >> 16);
}
__device__ __forceinline__ float bf2f(unsigned short b) {
  return __builtin_bit_cast(float, ((unsigned int)b) << 16);
}
__device__ __forceinline__ float bflo(unsigned int u) {
  return __builtin_bit_cast(float, u << 16);
}
__device__ __forceinline__ float bfhi(unsigned int u) {
  return __builtin_bit_cast(float, u & 0xffff0000u);
}

struct NTab { int n[6]; };
struct PrepTab { const float* wsrc[9]; const int* dst[6]; int shift[6]; };
struct PTab { const int* src[6]; const int* dst[6]; const float* w[6]; int shift[6]; };
struct TTy { const float* h[3]; unsigned char* hpA[3]; unsigned char* hpB[3];
             const unsigned short* wA[3]; const unsigned short* wB[3]; int cum[4]; };
struct GATab { const unsigned char* hpA[3]; const unsigned char* hpB[3];
               const unsigned* swA[3]; const unsigned* swB[3];
               const int* ofA[3]; const int* ofB[3];
               const float* A1[3]; const float* A2[3];
               unsigned short* agg[3]; int cum[4]; };

// ---- merged prep: blocks [0,2304) convert 9 weight mats; [2304,3840) coarse hist ----
__global__ __launch_bounds__(256) void prep_kernel(PrepTab Q, unsigned short* __restrict__ wbf,
                                                   int* __restrict__ chist) {
  const int bid = blockIdx.x, tid = threadIdx.x;
  __shared__ int h[64];
  if (bid < 2304) {
    int m = bid >> 8;
    int i = (bid & 255) * 256 + tid;
    wbf[m * 65536 + i] = f2bf(Q.wsrc[m][i]);
  } else {
    int b2 = bid - 2304;
    int r = b2 >> 8;          // 256 blocks per relation, 1024 edges each
    int blk = b2 & 255;
    if (tid < 64) h[tid] = 0;
    __syncthreads();
    const int* dp = Q.dst[r] + blk * 1024;
    const int sh = Q.shift[r];
#pragma unroll
    for (int k = 0; k < 4; ++k) atomicAdd(&h[dp[k * 256 + tid] >> sh], 1);
    __syncthreads();
    if (tid < 64) { int c = h[tid]; if (c) atomicAdd(&chist[r * 64 + tid], c); }
  }
}

// ---- tiny coarse scan: ccur (working cursor) + cbase (read-only windows) ----
__global__ void scan384_kernel(const int* __restrict__ chist, int* __restrict__ ccur,
                               int* __restrict__ cbase) {
  int r = threadIdx.x;
  if (r < 6) {
    int off = 0;
    for (int b = 0; b < 64; ++b) {
      ccur[r * 64 + b] = off;
      cbase[r * 65 + b] = off;
      off += chist[r * 64 + b];
    }
    cbase[r * 65 + 64] = off;  // == NE
  }
}

// ---- partition pass A: coarse 64-bucket partition into tmp (dst, packed) ----
__global__ __launch_bounds__(256) void partA6_kernel(PTab P, int* __restrict__ ccur,
                                                     int2* __restrict__ tmp) {
  int r = blockIdx.y;
  const int tid = threadIdx.x;
  __shared__ int hist[64], lbase[64], lcur[64];
  if (tid < 64) { hist[tid] = 0; lcur[tid] = 0; }
  __syncthreads();
  const int ebase = blockIdx.x * 1024;
  const int sh = P.shift[r];
  int dsts[4]; unsigned pk[4]; int bks[4];
#pragma unroll
  for (int k = 0; k < 4; ++k) {
    int e = ebase + k * 256 + tid;
    int d = P.dst[r][e];
    dsts[k] = d;
    pk[k] = (unsigned)P.src[r][e] | ((unsigned)f2bf(P.w[r][e]) << 16);
    bks[k] = d >> sh;
    atomicAdd(&hist[bks[k]], 1);
  }
  __syncthreads();
  if (tid < 64) {
    int c = hist[tid];
    if (c) lbase[tid] = atomicAdd(&ccur[r * 64 + tid], c);
  }
  __syncthreads();
#pragma unroll
  for (int k = 0; k < 4; ++k) {
    int pos = lbase[bks[k]] + atomicAdd(&lcur[bks[k]], 1);
    tmp[(size_t)r * NE + pos] = make_int2(dsts[k], (int)pk[k]);
  }
}

// ---- shared GEMM pieces: 64 rows x (256x256) bf16 MFMA (rounds 6-13 proven) ----
__device__ __forceinline__ void stage_x_f32(const float* __restrict__ g, int r0,
                                            unsigned short* xs, int tid) {
#pragma unroll
  for (int it = 0; it < 16; ++it) {
    int i = it * 256 + tid;
    int row = i >> 6, q = i & 63;
    float4 v = reinterpret_cast<const float4*>(g)[(size_t)(r0 + row) * 64 + q];
    ushort4 b;
    b.x = f2bf(v.x); b.y = f2bf(v.y); b.z = f2bf(v.z); b.w = f2bf(v.w);
    *reinterpret_cast<ushort4*>(&xs[row * 264 + q * 4]) = b;
  }
}

__device__ __forceinline__ void gemm_frag(const unsigned short* xs,
                                          const unsigned short* __restrict__ Wg,
                                          unsigned short* wl, int tid,
                                          f32x4 accv[4][4]) {
  const int wid = tid >> 6, lhi = (tid & 63) >> 4, llo = tid & 15;
  for (int ks = 0; ks < 8; ++ks) {
    const int k0 = ks * 32;
    __syncthreads();  // protects xs (first iter) and wl reads from prev iter
    {
      const uint4* gp = reinterpret_cast<const uint4*>(Wg + (size_t)tid * 256 + k0);
      uint4 a0 = gp[0], a1 = gp[1], a2 = gp[2], a3 = gp[3];
      uint4* lp = reinterpret_cast<uint4*>(wl + tid * 56);
      lp[0] = a0; lp[1] = a1; lp[2] = a2; lp[3] = a3;
    }
    __syncthreads();
    bf16x8 afr[4], bfr[4];
#pragma unroll
    for (int rt = 0; rt < 4; ++rt)
      afr[rt] = *reinterpret_cast<const bf16x8*>(&xs[(rt * 16 + llo) * 264 + k0 + lhi * 8]);
#pragma unroll
    for (int nt = 0; nt < 4; ++nt)
      bfr[nt] = *reinterpret_cast<const bf16x8*>(&wl[(wid * 64 + nt * 16 + llo) * 56 + lhi * 8]);
#pragma unroll
    for (int rt = 0; rt < 4; ++rt)
#pragma unroll
      for (int nt = 0; nt < 4; ++nt)
        accv[rt][nt] = __builtin_amdgcn_mfma_f32_16x16x32_bf16(afr[rt], bfr[nt], accv[rt][nt], 0, 0, 0);
  }
}

// ---- writeout: accv -> fp8 e4m3 bytes (hp row = 256 B) ----
__device__ __forceinline__ void writeout_hp(unsigned char* __restrict__ hp, int r0, int tid,
                                            f32x4 accv[4][4]) {
  const int wid = tid >> 6, lane = tid & 63, lhi = lane >> 4, llo = lane & 15;
#pragma unroll
  for (int rt = 0; rt < 4; ++rt)
#pragma unroll
    for (int nt = 0; nt < 4; ++nt) {
      int col = wid * 64 + nt * 16 + llo;
#pragma unroll
      for (int rg = 0; rg < 4; ++rg) {
        int row = rt * 16 + lhi * 4 + rg;
        int pk = __builtin_amdgcn_cvt_pk_fp8_f32(accv[rt][nt][rg], accv[rt][nt][rg], 0, false);
        hp[(size_t)(r0 + row) * DIM + col] = (unsigned char)(pk & 0xff);
      }
    }
}

// ---- mid kernel: partB (blocks [0,384)) ∥ transformT (blocks [384,1280)) ----
__global__ __launch_bounds__(256) void mid_kernel(const int2* __restrict__ tmp,
                                                  const int* __restrict__ cbase,
                                                  int* __restrict__ offs,
                                                  unsigned* __restrict__ srcw,
                                                  NTab N, TTy T) {
  __shared__ union alignas(16) SM {
    struct { unsigned short xs[64 * 264]; unsigned short wl[256 * 56]; } t;
    struct { int hist[512]; int part[256]; } p;
  } sm;
  const int bid = blockIdx.x, tid = threadIdx.x;

  if (bid < 384) {
    // ---------------- partB path (round-11 proven) ----------------
    int r = bid >> 6, b = bid & 63;
    const int n = N.n[r], s = n >> 6;
    const int dbase = b * s;
    int* hist = sm.p.hist;
    int* part = sm.p.part;
    for (int i = tid; i < s; i += 256) hist[i] = 0;
    __syncthreads();
    const int wbeg = cbase[r * 65 + b], wend = cbase[r * 65 + b + 1];
    const int2* __restrict__ tr = tmp + (size_t)r * NE;
    for (int i = wbeg + tid; i < wend; i += 256)
      atomicAdd(&hist[tr[i].x - dbase], 1);
    __syncthreads();
    const int per = (s > 256) ? 2 : 1;
    const int base = tid * per;
    int vals[2];
    int mysum = 0;
#pragma unroll
    for (int j = 0; j < 2; ++j) {
      int idx = base + j;
      vals[j] = (j < per && idx < s) ? hist[idx] : 0;
      mysum += vals[j];
    }
    part[tid] = mysum;
    __syncthreads();
    for (int off = 1; off < 256; off <<= 1) {
      int v = (tid >= off) ? part[tid - off] : 0;
      __syncthreads();
      part[tid] += v;
      __syncthreads();
    }
    int run = part[tid] - mysum + wbeg;
#pragma unroll
    for (int j = 0; j < 2; ++j) {
      int idx = base + j;
      if (j < per && idx < s) {
        hist[idx] = run;                         // becomes the live cursor
        offs[r * HSTRIDE + dbase + idx] = run;   // fine CSR offsets
        run += vals[j];
      }
    }
    if (b == 0 && tid == 0) offs[r * HSTRIDE + n] = NE;
    __syncthreads();
    for (int i = wbeg + tid; i < wend; i += 256) {
      int2 e = tr[i];
      int pos = atomicAdd(&hist[e.x - dbase], 1);
      srcw[(size_t)r * NE + pos] = (unsigned)e.y;
    }
  } else {
    // ---------------- transformT path (round-10 proven, fp8 writeout) ----------------
    const int bx = bid - 384;
    int t = 0;
#pragma unroll
    for (int k = 1; k < 3; ++k) t += (bx >= T.cum[k]);
    const int r0 = (bx - T.cum[t]) * 64;

    stage_x_f32(T.h[t], r0, sm.t.xs, tid);

    f32x4 accv[4][4];
#pragma unroll
    for (int a = 0; a < 4; ++a)
#pragma unroll
      for (int b2 = 0; b2 < 4; ++b2) accv[a][b2] = {0.f, 0.f, 0.f, 0.f};
    gemm_frag(sm.t.xs, T.wA[t], sm.t.wl, tid, accv);
    writeout_hp(T.hpA[t], r0, tid, accv);

#pragma unroll
    for (int a = 0; a < 4; ++a)
#pragma unroll
      for (int b2 = 0; b2 < 4; ++b2) accv[a][b2] = {0.f, 0.f, 0.f, 0.f};
    gemm_frag(sm.t.xs, T.wB[t], sm.t.wl, tid, accv);  // first barrier inside protects wl reuse
    writeout_hp(T.hpB[t], r0, tid, accv);
  }
}

// ---- bucket walk (round-12-proven serial shape, fp8 rows): m = (Σ w·hp[src]) / Σw ----
__device__ __forceinline__ void bucket_msg(const unsigned* __restrict__ sw,
                                           const unsigned char* __restrict__ hp,
                                           int beg, int end, int half, int c8,
                                           float& m0, float& m1, float& m2, float& m3,
                                           float& m4, float& m5, float& m6, float& m7) {
  float a0 = 0.f, a1 = 0.f, a2 = 0.f, a3 = 0.f, a4 = 0.f, a5 = 0.f, a6 = 0.f, a7 = 0.f;
  float degw = 0.f;
  const int boff = c8 * 8;
  for (int j = beg; j < end; j += 8) {
    int ib = j + half * 4;
    unsigned e0 = (ib + 0 < end) ? sw[ib + 0] : 0u;
    unsigned e1 = (ib + 1 < end) ? sw[ib + 1] : 0u;
    unsigned e2 = (ib + 2 < end) ? sw[ib + 2] : 0u;
    unsigned e3 = (ib + 3 < end) ? sw[ib + 3] : 0u;
    float w0 = bfhi(e0), w1 = bfhi(e1), w2 = bfhi(e2), w3 = bfhi(e3);
    uint2 x0 = *reinterpret_cast<const uint2*>(hp + (size_t)(e0 & 0xffff) * DIM + boff);
    uint2 x1 = *reinterpret_cast<const uint2*>(hp + (size_t)(e1 & 0xffff) * DIM + boff);
    uint2 x2 = *reinterpret_cast<const uint2*>(hp + (size_t)(e2 & 0xffff) * DIM + boff);
    uint2 x3 = *reinterpret_cast<const uint2*>(hp + (size_t)(e3 & 0xffff) * DIM + boff);
    degw += (w0 + w1) + (w2 + w3);
    f32x2 p;
    p = __builtin_amdgcn_cvt_pk_f32_fp8(x0.x, false); a0 += w0 * p.x; a1 += w0 * p.y;
    p = __builtin_amdgcn_cvt_pk_f32_fp8(x0.x, true);  a2 += w0 * p.x; a3 += w0 * p.y;
    p = __builtin_amdgcn_cvt_pk_f32_fp8(x0.y, false); a4 += w0 * p.x; a5 += w0 * p.y;
    p = __builtin_amdgcn_cvt_pk_f32_fp8(x0.y, true);  a6 += w0 * p.x; a7 += w0 * p.y;
    p = __builtin_amdgcn_cvt_pk_f32_fp8(x1.x, false); a0 += w1 * p.x; a1 += w1 * p.y;
    p = __builtin_amdgcn_cvt_pk_f32_fp8(x1.x, true);  a2 += w1 * p.x; a3 += w1 * p.y;
    p = __builtin_amdgcn_cvt_pk_f32_fp8(x1.y, false); a4 += w1 * p.x; a5 += w1 * p.y;
    p = __builtin_amdgcn_cvt_pk_f32_fp8(x1.y, true);  a6 += w1 * p.x; a7 += w1 * p.y;
    p = __builtin_amdgcn_cvt_pk_f32_fp8(x2.x, false); a0 += w2 * p.x; a1 += w2 * p.y;
    p = __builtin_amdgcn_cvt_pk_f32_fp8(x2.x, true);  a2 += w2 * p.x; a3 += w2 * p.y;
    p = __builtin_amdgcn_cvt_pk_f32_fp8(x2.y, false); a4 += w2 * p.x; a5 += w2 * p.y;
    p = __builtin_amdgcn_cvt_pk_f32_fp8(x2.y, true);  a6 += w2 * p.x; a7 += w2 * p.y;
    p = __builtin_amdgcn_cvt_pk_f32_fp8(x3.x, false); a0 += w3 * p.x; a1 += w3 * p.y;
    p = __builtin_amdgcn_cvt_pk_f32_fp8(x3.x, true);  a2 += w3 * p.x; a3 += w3 * p.y;
    p = __builtin_amdgcn_cvt_pk_f32_fp8(x3.y, false); a4 += w3 * p.x; a5 += w3 * p.y;
    p = __builtin_amdgcn_cvt_pk_f32_fp8(x3.y, true);  a6 += w3 * p.x; a7 += w3 * p.y;
  }
  a0 += __shfl_xor(a0, 32); a1 += __shfl_xor(a1, 32);
  a2 += __shfl_xor(a2, 32); a3 += __shfl_xor(a3, 32);
  a4 += __shfl_xor(a4, 32); a5 += __shfl_xor(a5, 32);
  a6 += __shfl_xor(a6, 32); a7 += __shfl_xor(a7, 32);
  degw += __shfl_xor(degw, 32);
  float inv = (degw == 0.f) ? 1.f : 1.f / degw;
  m0 = a0 * inv; m1 = a1 * inv; m2 = a2 * inv; m3 = a3 * inv;
  m4 = a4 * inv; m5 = a5 * inv; m6 = a6 * inv; m7 = a7 * inv;
}

// ---- gather + relation attention: agg[node] = c1*mA + c2*mB (bf16) ----
// one wave per node (per dest TYPE); serial two-bucket walk (round-12 proven shape).
__global__ __launch_bounds__(256) void gatherAtt_kernel(GATab T) {
  const int bx = blockIdx.x;
  int t = 0;
#pragma unroll
  for (int k = 1; k < 3; ++k) t += (bx >= T.cum[k]);
  const int node = (bx - T.cum[t]) * 4 + (threadIdx.x >> 6);
  const int lane = threadIdx.x & 63;
  const int half = lane >> 5;
  const int c8 = lane & 31;

  const int* ofA = T.ofA[t];
  const int* ofB = T.ofB[t];
  float mA0, mA1, mA2, mA3, mA4, mA5, mA6, mA7;
  float mB0, mB1, mB2, mB3, mB4, mB5, mB6, mB7;
  bucket_msg(T.swA[t], T.hpA[t], ofA[node], ofA[node + 1], half, c8,
             mA0, mA1, mA2, mA3, mA4, mA5, mA6, mA7);
  bucket_msg(T.swB[t], T.hpB[t], ofB[node], ofB[node + 1], half, c8,
             mB0, mB1, mB2, mB3, mB4, mB5, mB6, mB7);

  // attention: scores via in-register dots + intra-half shfl reduce, then softmax
  const float4* A1v = reinterpret_cast<const float4*>(T.A1[t]);  // [4][64] float4
  const float4* A2v = reinterpret_cast<const float4*>(T.A2[t]);
  float c1 = 0.f, c2 = 0.f;
#pragma unroll
  for (int hh = 0; hh < 4; ++hh) {
    float4 qa = A1v[hh * 64 + c8 * 2], qb = A1v[hh * 64 + c8 * 2 + 1];
    float4 ra = A2v[hh * 64 + c8 * 2], rb = A2v[hh * 64 + c8 * 2 + 1];
    float sA = mA0 * qa.x + mA1 * qa.y + mA2 * qa.z + mA3 * qa.w
             + mA4 * qb.x + mA5 * qb.y + mA6 * qb.z + mA7 * qb.w;
    float sB = mB0 * ra.x + mB1 * ra.y + mB2 * ra.z + mB3 * ra.w
             + mB4 * rb.x + mB5 * rb.y + mB6 * rb.z + mB7 * rb.w;
#pragma unroll
    for (int o = 1; o <= 16; o <<= 1) { sA += __shfl_xor(sA, o); sB += __shfl_xor(sB, o); }
    // softmax over the 2 relations; scale = 1/(sqrt(256)*0.5) = 0.125
    float s1 = sA * 0.125f, s2 = sB * 0.125f;
    float mx = fmaxf(s1, s2);
    float e1 = __expf(s1 - mx), e2 = __expf(s2 - mx);
    float inv = 1.f / (e1 + e2);
    c1 += e1 * inv; c2 += e2 * inv;
  }
  c1 *= 0.25f; c2 *= 0.25f;  // mean over H=4 heads

  if (half == 0) {
    u32x4 o;
    o.x = (unsigned)f2bf(c1 * mA0 + c2 * mB0) | ((unsigned)f2bf(c1 * mA1 + c2 * mB1) << 16);
    o.y = (unsigned)f2bf(c1 * mA2 + c2 * mB2) | ((unsigned)f2bf(c1 * mA3 + c2 * mB3) << 16);
    o.z = (unsigned)f2bf(c1 * mA4 + c2 * mB4) | ((unsigned)f2bf(c1 * mA5 + c2 * mB5) << 16);
    o.w = (unsigned)f2bf(c1 * mA6 + c2 * mB6) | ((unsigned)f2bf(c1 * mA7 + c2 * mB7) << 16);
    __builtin_nontemporal_store(o, reinterpret_cast<u32x4*>(T.agg[t]) + (size_t)node * 32 + c8);
  }
}

// ---- per node type: self-GEMM + agg + residual + LN + leaky (round-12 proven) ----
__global__ __launch_bounds__(256) void fuse_kernel(
    const float* __restrict__ h, const unsigned short* __restrict__ agg,
    const unsigned short* __restrict__ Wbf,
    const float* __restrict__ gamma, const float* __restrict__ beta,
    float* __restrict__ out) {
  __shared__ alignas(16) union SM {
    struct { unsigned short x[64 * 264]; unsigned short w[256 * 56]; } g;
    unsigned short s[64 * 260];  // self result, bf16
  } ov;
  __shared__ float sgb[512];
  const int tid = threadIdx.x;
  const int r0 = blockIdx.x * 64;

  stage_x_f32(h, r0, ov.g.x, tid);
  for (int i = tid; i < 512; i += 256) sgb[i] = (i < 256) ? gamma[i] : beta[i - 256];

  f32x4 accv[4][4];
#pragma unroll
  for (int a = 0; a < 4; ++a)
#pragma unroll
    for (int b = 0; b < 4; ++b) accv[a][b] = {0.f, 0.f, 0.f, 0.f};

  gemm_frag(ov.g.x, Wbf, ov.g.w, tid, accv);

  const int wid = tid >> 6, lane = tid & 63, lhi = lane >> 4, llo = lane & 15;
  __syncthreads();  // all MFMA LDS reads done before overlaying ov.s
#pragma unroll
  for (int rt = 0; rt < 4; ++rt)
#pragma unroll
    for (int nt = 0; nt < 4; ++nt) {
      int col = wid * 64 + nt * 16 + llo;
#pragma unroll
      for (int rg = 0; rg < 4; ++rg)
        ov.s[(rt * 16 + lhi * 4 + rg) * 260 + col] = f2bf(accv[rt][nt][rg]);
    }
  __syncthreads();

  // epilogue: wave handles 16 rows; lane owns 4 dims
  const int d0 = lane * 4;
  const float4 g4 = *reinterpret_cast<const float4*>(&sgb[d0]);
  const float4 b4 = *reinterpret_cast<const float4*>(&sgb[256 + d0]);

  for (int rl = 0; rl < 16; ++rl) {
    int row = wid * 16 + rl;
    size_t gb = (size_t)(r0 + row) * DIM + d0;
    ushort4 ab = *reinterpret_cast<const ushort4*>(agg + gb);
    float4 av = {bf2f(ab.x), bf2f(ab.y), bf2f(ab.z), bf2f(ab.w)};
    float4 hvv = *reinterpret_cast<const float4*>(h + gb);
    ushort4 sb = *reinterpret_cast<const ushort4*>(&ov.s[row * 260 + d0]);
    float4 sv = {bf2f(sb.x), bf2f(sb.y), bf2f(sb.z), bf2f(sb.w)};

    float4 u;
    u.x = sv.x + av.x + hvv.x;
    u.y = sv.y + av.y + hvv.y;
    u.z = sv.z + av.z + hvv.z;
    u.w = sv.w + av.w + hvv.w;

    float s1v = u.x + u.y + u.z + u.w;
    float s2v = u.x * u.x + u.y * u.y + u.z * u.z + u.w * u.w;
#pragma unroll
    for (int o = 1; o < 64; o <<= 1) { s1v += __shfl_xor(s1v, o); s2v += __shfl_xor(s2v, o); }
    float mu = s1v * (1.f / 256.f);
    float var = s2v * (1.f / 256.f) - mu * mu;
    float rstd = rsqrtf(var + 1e-5f);

    float4 y;
    y.x = (u.x - mu) * rstd * g4.x + b4.x;
    y.y = (u.y - mu) * rstd * g4.y + b4.y;
    y.z = (u.z - mu) * rstd * g4.z + b4.z;
    y.w = (u.w - mu) * rstd * g4.w + b4.w;
    y.x = fmaxf(y.x, 0.01f * y.x);
    y.y = fmaxf(y.y, 0.01f * y.y);
    y.z = fmaxf(y.z, 0.01f * y.z);
    y.w = fmaxf(y.w, 0.01f * y.w);
    *reinterpret_cast<float4*>(out + gb) = y;
  }
}

// ---- workspace layout (bytes); ~80 MB (< proven ~139 MB) ----
static constexpr size_t AL(size_t x) { return (x + 255) & ~size_t(255); }
// aggregated messages (bf16), one row per node, type-major l|g|d
static constexpr size_t AGG_TOT = (size_t)(NLr + NGr + NDr) * DIM;      // ushorts
// transformed embeddings (fp8, 1 byte/elem), all 6 relations, sized by SRC rows
static constexpr size_t HPe_L2G = 0;                                    // NLr rows
static constexpr size_t HPe_G2L = HPe_L2G + (size_t)NLr * DIM;          // NGr
static constexpr size_t HPe_G2D = HPe_G2L + (size_t)NGr * DIM;          // NGr
static constexpr size_t HPe_D2G = HPe_G2D + (size_t)NGr * DIM;          // NDr
static constexpr size_t HPe_L2D = HPe_D2G + (size_t)NDr * DIM;          // NLr
static constexpr size_t HPe_D2L = HPe_L2D + (size_t)NLr * DIM;          // NDr
static constexpr size_t HP_TOT  = HPe_D2L + (size_t)NDr * DIM;          // bytes
static constexpr size_t OFF_AGG   = 0;
static constexpr size_t OFF_HP    = AL(OFF_AGG + AGG_TOT * 2);
static constexpr size_t OFF_WBF   = AL(OFF_HP + HP_TOT);
static constexpr size_t OFF_OFFS  = AL(OFF_WBF + 9 * 65536 * 2);
static constexpr size_t OFF_CHIST = AL(OFF_OFFS + 6 * HSTRIDE * 4);     // 384 ints
static constexpr size_t OFF_CBASE = AL(OFF_CHIST + 384 * 4);            // 6*65 ints
static constexpr size_t OFF_CCUR  = AL(OFF_CBASE + 390 * 4);            // 384 ints
static constexpr size_t OFF_TMP   = AL(OFF_CCUR + 384 * 4);             // 6*NE int2
static constexpr size_t OFF_SRCW  = AL(OFF_TMP + (size_t)6 * NE * 8);   // 6*NE u32

extern "C" void kernel_launch(void* const* d_in, const int* in_sizes, int n_in,
                              void* d_out, int out_size, void* d_ws, size_t ws_size,
                              hipStream_t stream) {
  char* wsb = (char*)d_ws;
  unsigned short* agg = (unsigned short*)(wsb + OFF_AGG);
  unsigned char* hp   = (unsigned char*)(wsb + OFF_HP);
  unsigned short* wbf = (unsigned short*)(wsb + OFF_WBF);
  int* offs  = (int*)(wsb + OFF_OFFS);
  int* chist = (int*)(wsb + OFF_CHIST);
  int* cbase = (int*)(wsb + OFF_CBASE);
  int* ccur  = (int*)(wsb + OFF_CCUR);
  int2* tmp  = (int2*)(wsb + OFF_TMP);
  unsigned* srcw = (unsigned*)(wsb + OFF_SRCW);
  float* out = (float*)d_out;

  // relation order: l2g, g2l, g2d, d2g, l2d, d2l
  const int base[6] = {3, 8, 13, 18, 23, 28};
  const int ndst[6] = {NGr, NLr, NDr, NGr, NDr, NLr};
  const size_t hpOff[6]  = {HPe_L2G, HPe_G2L, HPe_G2D, HPe_D2G, HPe_L2D, HPe_D2L};

  // merged prep: weight f32->bf16 + coarse dst histogram
  (void)hipMemsetAsync(chist, 0, 384 * 4, stream);
  PrepTab Q; PTab P; NTab N;
  Q.wsrc[0] = (const float*)d_in[6];  Q.wsrc[1] = (const float*)d_in[11];
  Q.wsrc[2] = (const float*)d_in[16]; Q.wsrc[3] = (const float*)d_in[21];
  Q.wsrc[4] = (const float*)d_in[26]; Q.wsrc[5] = (const float*)d_in[31];
  Q.wsrc[6] = (const float*)d_in[33]; Q.wsrc[7] = (const float*)d_in[36];
  Q.wsrc[8] = (const float*)d_in[39];
  for (int r = 0; r < 6; ++r) {
    int sh = (ndst[r] == NGr) ? 9 : (ndst[r] == NLr ? 8 : 7);  // coarse = n>>6
    Q.dst[r] = (const int*)d_in[base[r] + 1];
    Q.shift[r] = sh;
    P.src[r] = (const int*)d_in[base[r]];
    P.dst[r] = (const int*)d_in[base[r] + 1];
    P.w[r]  = (const float*)d_in[base[r] + 2];
    P.shift[r] = sh;
    N.n[r] = ndst[r];
  }
  prep_kernel<<<2304 + 1536, 256, 0, stream>>>(Q, wbf, chist);
  scan384_kernel<<<1, 64, 0, stream>>>(chist, ccur, cbase);

  // partition pass A (coarse)
  partA6_kernel<<<dim3(NE / 1024, 6), 256, 0, stream>>>(P, ccur, tmp);

  // mid: partB (fine placement + offs) OVERLAPPED with transformT (independent)
  // type l -> {l2g(0), l2d(4)}, type g -> {g2l(1), g2d(2)}, type d -> {d2g(3), d2l(5)}
  TTy T;
  T.h[0] = (const float*)d_in[0]; T.h[1] = (const float*)d_in[1]; T.h[2] = (const float*)d_in[2];
  T.hpA[0] = hp + hpOff[0]; T.hpB[0] = hp + hpOff[4];
  T.hpA[1] = hp + hpOff[1]; T.hpB[1] = hp + hpOff[2];
  T.hpA[2] = hp + hpOff[3]; T.hpB[2] = hp + hpOff[5];
  T.wA[0] = wbf + 0 * 65536; T.wB[0] = wbf + 4 * 65536;
  T.wA[1] = wbf + 1 * 65536; T.wB[1] = wbf + 2 * 65536;
  T.wA[2] = wbf + 3 * 65536; T.wB[2] = wbf + 5 * 65536;
  T.cum[0] = 0; T.cum[1] = NLr / 64; T.cum[2] = (NLr + NGr) / 64; T.cum[3] = (NLr + NGr + NDr) / 64;
  mid_kernel<<<384 + 896, 256, 0, stream>>>(tmp, cbase, offs, srcw, N, T);

  // gather + attention per dest type: l <- {g2l(1), d2l(5)}, g <- {l2g(0), d2g(3)},
  // d <- {g2d(2), l2d(4)}; one wave per node, serial two-bucket walk (fp8 rows)
  GATab G;
  const int relA[3] = {1, 0, 2}, relB[3] = {5, 3, 4};
  const int aA[3] = {12, 7, 17}, aB[3] = {32, 22, 27};
  const size_t aggBase[3] = {0, (size_t)NLr * DIM, (size_t)(NLr + NGr) * DIM};
  for (int t = 0; t < 3; ++t) {
    G.hpA[t] = hp + hpOff[relA[t]];
    G.hpB[t] = hp + hpOff[relB[t]];
    G.swA[t] = srcw + (size_t)relA[t] * NE;
    G.swB[t] = srcw + (size_t)relB[t] * NE;
    G.ofA[t] = offs + relA[t] * HSTRIDE;
    G.ofB[t] = offs + relB[t] * HSTRIDE;
    G.A1[t] = (const float*)d_in[aA[t]];
    G.A2[t] = (const float*)d_in[aB[t]];
    G.agg[t] = agg + aggBase[t];
  }
  G.cum[0] = 0; G.cum[1] = NLr / 4; G.cum[2] = (NLr + NGr) / 4; G.cum[3] = (NLr + NGr + NDr) / 4;
  gatherAtt_kernel<<<G.cum[3], 256, 0, stream>>>(G);

  // fused update per type
  fuse_kernel<<<NLr / 64, 256, 0, stream>>>(
      (const float*)d_in[0], agg + aggBase[0], wbf + 6 * 65536,
      (const float*)d_in[34], (const float*)d_in[35], out);
  fuse_kernel<<<NGr / 64, 256, 0, stream>>>(
      (const float*)d_in[1], agg + aggBase[1], wbf + 7 * 65536,
      (const float*)d_in[37], (const float*)d_in[38], out + (size_t)NLr * DIM);
  fuse_kernel<<<NDr / 64, 256, 0, stream>>>(
      (const float*)d_in[2], agg + aggBase[2], wbf + 8 * 65536,
      (const float*)d_in[40], (const float*)d_in[41], out + (size_t)(NLr + NGr) * DIM);
}

// Round 15
// 251.128 us; speedup vs baseline: 1.7474x; 1.0615x over previous
//
#include <hip/hip_runtime.h>

#define DIM 256
#define NLr 16384
#define NGr 32768
#define NDr 8192
#define NE  262144
#define HSTRIDE 32772  // offs per-relation stride (16B-aligned)

typedef short bf16x8 __attribute__((ext_vector_type(8)));
typedef float f32x4 __attribute__((ext_vector_type(4)));
typedef float f32x2 __attribute__((ext_vector_type(2)));
typedef unsigned u32x4 __attribute__((ext_vector_type(4)));

__device__ __forceinline__ unsigned short f2bf(float f) {
  unsigned int u = __builtin_bit_cast(unsigned int, f);
  u += 0x7fffu + ((u >> 16) & 1u);
  return (unsigned short)(u >> 16);
}
__device__ __forceinline__ float bf2f(unsigned short b) {
  return __builtin_bit_cast(float, ((unsigned int)b) << 16);
}
__device__ __forceinline__ float bflo(unsigned int u) {
  return __builtin_bit_cast(float, u << 16);
}
__device__ __forceinline__ float bfhi(unsigned int u) {
  return __builtin_bit_cast(float, u & 0xffff0000u);
}

struct NTab { int n[6]; };
struct PrepTab { const float* wsrc[9]; const int* dst[6]; int shift[6]; };
struct PTab { const int* src[6]; const int* dst[6]; const float* w[6]; int shift[6]; };
struct TTy { const float* h[3]; unsigned char* hpA[3]; unsigned char* hpB[3];
             const unsigned short* wA[3]; const unsigned short* wB[3]; int cum[4]; };
struct GATab { const unsigned char* hpA[3]; const unsigned char* hpB[3];
               const unsigned* swA[3]; const unsigned* swB[3];
               const int* ofA[3]; const int* ofB[3];
               const float* A1[3]; const float* A2[3];
               unsigned short* agg[3]; int cum[4]; };
struct FTab { const float* h[3]; const unsigned short* agg[3];
              const unsigned short* wbf[3]; const float* gm[3]; const float* bt[3];
              float* out[3]; int cum[4]; };

// ---- merged prep: blocks [0,2304) convert 9 weight mats; [2304,3840) coarse hist ----
__global__ __launch_bounds__(256) void prep_kernel(PrepTab Q, unsigned short* __restrict__ wbf,
                                                   int* __restrict__ chist) {
  const int bid = blockIdx.x, tid = threadIdx.x;
  __shared__ int h[64];
  if (bid < 2304) {
    int m = bid >> 8;
    int i = (bid & 255) * 256 + tid;
    wbf[m * 65536 + i] = f2bf(Q.wsrc[m][i]);
  } else {
    int b2 = bid - 2304;
    int r = b2 >> 8;          // 256 blocks per relation, 1024 edges each
    int blk = b2 & 255;
    if (tid < 64) h[tid] = 0;
    __syncthreads();
    const int* dp = Q.dst[r] + blk * 1024;
    const int sh = Q.shift[r];
#pragma unroll
    for (int k = 0; k < 4; ++k) atomicAdd(&h[dp[k * 256 + tid] >> sh], 1);
    __syncthreads();
    if (tid < 64) { int c = h[tid]; if (c) atomicAdd(&chist[r * 64 + tid], c); }
  }
}

// ---- tiny coarse scan: ccur (working cursor) + cbase (read-only windows) ----
__global__ void scan384_kernel(const int* __restrict__ chist, int* __restrict__ ccur,
                               int* __restrict__ cbase) {
  int r = threadIdx.x;
  if (r < 6) {
    int off = 0;
    for (int b = 0; b < 64; ++b) {
      ccur[r * 64 + b] = off;
      cbase[r * 65 + b] = off;
      off += chist[r * 64 + b];
    }
    cbase[r * 65 + 64] = off;  // == NE
  }
}

// ---- partition pass A: coarse 64-bucket partition into tmp (dst, packed) ----
__global__ __launch_bounds__(256) void partA6_kernel(PTab P, int* __restrict__ ccur,
                                                     int2* __restrict__ tmp) {
  int r = blockIdx.y;
  const int tid = threadIdx.x;
  __shared__ int hist[64], lbase[64], lcur[64];
  if (tid < 64) { hist[tid] = 0; lcur[tid] = 0; }
  __syncthreads();
  const int ebase = blockIdx.x * 1024;
  const int sh = P.shift[r];
  int dsts[4]; unsigned pk[4]; int bks[4];
#pragma unroll
  for (int k = 0; k < 4; ++k) {
    int e = ebase + k * 256 + tid;
    int d = P.dst[r][e];
    dsts[k] = d;
    pk[k] = (unsigned)P.src[r][e] | ((unsigned)f2bf(P.w[r][e]) << 16);
    bks[k] = d >> sh;
    atomicAdd(&hist[bks[k]], 1);
  }
  __syncthreads();
  if (tid < 64) {
    int c = hist[tid];
    if (c) lbase[tid] = atomicAdd(&ccur[r * 64 + tid], c);
  }
  __syncthreads();
#pragma unroll
  for (int k = 0; k < 4; ++k) {
    int pos = lbase[bks[k]] + atomicAdd(&lcur[bks[k]], 1);
    tmp[(size_t)r * NE + pos] = make_int2(dsts[k], (int)pk[k]);
  }
}

// ---- shared GEMM pieces: 64 rows x (256x256) bf16 MFMA (rounds 6-14 proven) ----
__device__ __forceinline__ void stage_x_f32(const float* __restrict__ g, int r0,
                                            unsigned short* xs, int tid) {
#pragma unroll
  for (int it = 0; it < 16; ++it) {
    int i = it * 256 + tid;
    int row = i >> 6, q = i & 63;
    float4 v = reinterpret_cast<const float4*>(g)[(size_t)(r0 + row) * 64 + q];
    ushort4 b;
    b.x = f2bf(v.x); b.y = f2bf(v.y); b.z = f2bf(v.z); b.w = f2bf(v.w);
    *reinterpret_cast<ushort4*>(&xs[row * 264 + q * 4]) = b;
  }
}

__device__ __forceinline__ void gemm_frag(const unsigned short* xs,
                                          const unsigned short* __restrict__ Wg,
                                          unsigned short* wl, int tid,
                                          f32x4 accv[4][4]) {
  const int wid = tid >> 6, lhi = (tid & 63) >> 4, llo = tid & 15;
  for (int ks = 0; ks < 8; ++ks) {
    const int k0 = ks * 32;
    __syncthreads();  // protects xs (first iter) and wl reads from prev iter
    {
      const uint4* gp = reinterpret_cast<const uint4*>(Wg + (size_t)tid * 256 + k0);
      uint4 a0 = gp[0], a1 = gp[1], a2 = gp[2], a3 = gp[3];
      uint4* lp = reinterpret_cast<uint4*>(wl + tid * 56);
      lp[0] = a0; lp[1] = a1; lp[2] = a2; lp[3] = a3;
    }
    __syncthreads();
    bf16x8 afr[4], bfr[4];
#pragma unroll
    for (int rt = 0; rt < 4; ++rt)
      afr[rt] = *reinterpret_cast<const bf16x8*>(&xs[(rt * 16 + llo) * 264 + k0 + lhi * 8]);
#pragma unroll
    for (int nt = 0; nt < 4; ++nt)
      bfr[nt] = *reinterpret_cast<const bf16x8*>(&wl[(wid * 64 + nt * 16 + llo) * 56 + lhi * 8]);
#pragma unroll
    for (int rt = 0; rt < 4; ++rt)
#pragma unroll
      for (int nt = 0; nt < 4; ++nt)
        accv[rt][nt] = __builtin_amdgcn_mfma_f32_16x16x32_bf16(afr[rt], bfr[nt], accv[rt][nt], 0, 0, 0);
  }
}

// ---- writeout: accv -> fp8 e4m3 bytes (hp row = 256 B) ----
__device__ __forceinline__ void writeout_hp(unsigned char* __restrict__ hp, int r0, int tid,
                                            f32x4 accv[4][4]) {
  const int wid = tid >> 6, lane = tid & 63, lhi = lane >> 4, llo = lane & 15;
#pragma unroll
  for (int rt = 0; rt < 4; ++rt)
#pragma unroll
    for (int nt = 0; nt < 4; ++nt) {
      int col = wid * 64 + nt * 16 + llo;
#pragma unroll
      for (int rg = 0; rg < 4; ++rg) {
        int row = rt * 16 + lhi * 4 + rg;
        int pk = __builtin_amdgcn_cvt_pk_fp8_f32(accv[rt][nt][rg], accv[rt][nt][rg], 0, false);
        hp[(size_t)(r0 + row) * DIM + col] = (unsigned char)(pk & 0xff);
      }
    }
}

// ---- mid kernel: partB (blocks [0,384)) ∥ transformT (blocks [384,1280)) ----
__global__ __launch_bounds__(256) void mid_kernel(const int2* __restrict__ tmp,
                                                  const int* __restrict__ cbase,
                                                  int* __restrict__ offs,
                                                  unsigned* __restrict__ srcw,
                                                  NTab N, TTy T) {
  __shared__ union alignas(16) SM {
    struct { unsigned short xs[64 * 264]; unsigned short wl[256 * 56]; } t;
    struct { int hist[512]; int part[256]; } p;
  } sm;
  const int bid = blockIdx.x, tid = threadIdx.x;

  if (bid < 384) {
    // ---------------- partB path (round-11 proven) ----------------
    int r = bid >> 6, b = bid & 63;
    const int n = N.n[r], s = n >> 6;
    const int dbase = b * s;
    int* hist = sm.p.hist;
    int* part = sm.p.part;
    for (int i = tid; i < s; i += 256) hist[i] = 0;
    __syncthreads();
    const int wbeg = cbase[r * 65 + b], wend = cbase[r * 65 + b + 1];
    const int2* __restrict__ tr = tmp + (size_t)r * NE;
    for (int i = wbeg + tid; i < wend; i += 256)
      atomicAdd(&hist[tr[i].x - dbase], 1);
    __syncthreads();
    const int per = (s > 256) ? 2 : 1;
    const int base = tid * per;
    int vals[2];
    int mysum = 0;
#pragma unroll
    for (int j = 0; j < 2; ++j) {
      int idx = base + j;
      vals[j] = (j < per && idx < s) ? hist[idx] : 0;
      mysum += vals[j];
    }
    part[tid] = mysum;
    __syncthreads();
    for (int off = 1; off < 256; off <<= 1) {
      int v = (tid >= off) ? part[tid - off] : 0;
      __syncthreads();
      part[tid] += v;
      __syncthreads();
    }
    int run = part[tid] - mysum + wbeg;
#pragma unroll
    for (int j = 0; j < 2; ++j) {
      int idx = base + j;
      if (j < per && idx < s) {
        hist[idx] = run;                         // becomes the live cursor
        offs[r * HSTRIDE + dbase + idx] = run;   // fine CSR offsets
        run += vals[j];
      }
    }
    if (b == 0 && tid == 0) offs[r * HSTRIDE + n] = NE;
    __syncthreads();
    for (int i = wbeg + tid; i < wend; i += 256) {
      int2 e = tr[i];
      int pos = atomicAdd(&hist[e.x - dbase], 1);
      srcw[(size_t)r * NE + pos] = (unsigned)e.y;
    }
  } else {
    // ---------------- transformT path (fp8 writeout) ----------------
    const int bx = bid - 384;
    int t = 0;
#pragma unroll
    for (int k = 1; k < 3; ++k) t += (bx >= T.cum[k]);
    const int r0 = (bx - T.cum[t]) * 64;

    stage_x_f32(T.h[t], r0, sm.t.xs, tid);

    f32x4 accv[4][4];
#pragma unroll
    for (int a = 0; a < 4; ++a)
#pragma unroll
      for (int b2 = 0; b2 < 4; ++b2) accv[a][b2] = {0.f, 0.f, 0.f, 0.f};
    gemm_frag(sm.t.xs, T.wA[t], sm.t.wl, tid, accv);
    writeout_hp(T.hpA[t], r0, tid, accv);

#pragma unroll
    for (int a = 0; a < 4; ++a)
#pragma unroll
      for (int b2 = 0; b2 < 4; ++b2) accv[a][b2] = {0.f, 0.f, 0.f, 0.f};
    gemm_frag(sm.t.xs, T.wB[t], sm.t.wl, tid, accv);  // first barrier inside protects wl reuse
    writeout_hp(T.hpB[t], r0, tid, accv);
  }
}

// ---- bucket walk (fp8 rows): m = (Σ w·hp[src]) / Σw ----
// guard-free main loop + single guarded remainder (round-15 change)
__device__ __forceinline__ void bucket_msg(const unsigned* __restrict__ sw,
                                           const unsigned char* __restrict__ hp,
                                           int beg, int end, int half, int c8,
                                           float& m0, float& m1, float& m2, float& m3,
                                           float& m4, float& m5, float& m6, float& m7) {
  float a0 = 0.f, a1 = 0.f, a2 = 0.f, a3 = 0.f, a4 = 0.f, a5 = 0.f, a6 = 0.f, a7 = 0.f;
  float degw = 0.f;
  const int boff = c8 * 8;
  int j = beg;
  for (; j + 8 <= end; j += 8) {      // full iterations: no per-edge guards
    int ib = j + half * 4;
    unsigned e0 = sw[ib + 0], e1 = sw[ib + 1], e2 = sw[ib + 2], e3 = sw[ib + 3];
    float w0 = bfhi(e0), w1 = bfhi(e1), w2 = bfhi(e2), w3 = bfhi(e3);
    uint2 x0 = *reinterpret_cast<const uint2*>(hp + (size_t)(e0 & 0xffff) * DIM + boff);
    uint2 x1 = *reinterpret_cast<const uint2*>(hp + (size_t)(e1 & 0xffff) * DIM + boff);
    uint2 x2 = *reinterpret_cast<const uint2*>(hp + (size_t)(e2 & 0xffff) * DIM + boff);
    uint2 x3 = *reinterpret_cast<const uint2*>(hp + (size_t)(e3 & 0xffff) * DIM + boff);
    degw += (w0 + w1) + (w2 + w3);
    f32x2 p;
    p = __builtin_amdgcn_cvt_pk_f32_fp8(x0.x, false); a0 += w0 * p.x; a1 += w0 * p.y;
    p = __builtin_amdgcn_cvt_pk_f32_fp8(x0.x, true);  a2 += w0 * p.x; a3 += w0 * p.y;
    p = __builtin_amdgcn_cvt_pk_f32_fp8(x0.y, false); a4 += w0 * p.x; a5 += w0 * p.y;
    p = __builtin_amdgcn_cvt_pk_f32_fp8(x0.y, true);  a6 += w0 * p.x; a7 += w0 * p.y;
    p = __builtin_amdgcn_cvt_pk_f32_fp8(x1.x, false); a0 += w1 * p.x; a1 += w1 * p.y;
    p = __builtin_amdgcn_cvt_pk_f32_fp8(x1.x, true);  a2 += w1 * p.x; a3 += w1 * p.y;
    p = __builtin_amdgcn_cvt_pk_f32_fp8(x1.y, false); a4 += w1 * p.x; a5 += w1 * p.y;
    p = __builtin_amdgcn_cvt_pk_f32_fp8(x1.y, true);  a6 += w1 * p.x; a7 += w1 * p.y;
    p = __builtin_amdgcn_cvt_pk_f32_fp8(x2.x, false); a0 += w2 * p.x; a1 += w2 * p.y;
    p = __builtin_amdgcn_cvt_pk_f32_fp8(x2.x, true);  a2 += w2 * p.x; a3 += w2 * p.y;
    p = __builtin_amdgcn_cvt_pk_f32_fp8(x2.y, false); a4 += w2 * p.x; a5 += w2 * p.y;
    p = __builtin_amdgcn_cvt_pk_f32_fp8(x2.y, true);  a6 += w2 * p.x; a7 += w2 * p.y;
    p = __builtin_amdgcn_cvt_pk_f32_fp8(x3.x, false); a0 += w3 * p.x; a1 += w3 * p.y;
    p = __builtin_amdgcn_cvt_pk_f32_fp8(x3.x, true);  a2 += w3 * p.x; a3 += w3 * p.y;
    p = __builtin_amdgcn_cvt_pk_f32_fp8(x3.y, false); a4 += w3 * p.x; a5 += w3 * p.y;
    p = __builtin_amdgcn_cvt_pk_f32_fp8(x3.y, true);  a6 += w3 * p.x; a7 += w3 * p.y;
  }
  if (j < end) {                      // single guarded remainder
    int ib = j + half * 4;
    unsigned e0 = (ib + 0 < end) ? sw[ib + 0] : 0u;
    unsigned e1 = (ib + 1 < end) ? sw[ib + 1] : 0u;
    unsigned e2 = (ib + 2 < end) ? sw[ib + 2] : 0u;
    unsigned e3 = (ib + 3 < end) ? sw[ib + 3] : 0u;
    float w0 = bfhi(e0), w1 = bfhi(e1), w2 = bfhi(e2), w3 = bfhi(e3);
    uint2 x0 = *reinterpret_cast<const uint2*>(hp + (size_t)(e0 & 0xffff) * DIM + boff);
    uint2 x1 = *reinterpret_cast<const uint2*>(hp + (size_t)(e1 & 0xffff) * DIM + boff);
    uint2 x2 = *reinterpret_cast<const uint2*>(hp + (size_t)(e2 & 0xffff) * DIM + boff);
    uint2 x3 = *reinterpret_cast<const uint2*>(hp + (size_t)(e3 & 0xffff) * DIM + boff);
    degw += (w0 + w1) + (w2 + w3);
    f32x2 p;
    p = __builtin_amdgcn_cvt_pk_f32_fp8(x0.x, false); a0 += w0 * p.x; a1 += w0 * p.y;
    p = __builtin_amdgcn_cvt_pk_f32_fp8(x0.x, true);  a2 += w0 * p.x; a3 += w0 * p.y;
    p = __builtin_amdgcn_cvt_pk_f32_fp8(x0.y, false); a4 += w0 * p.x; a5 += w0 * p.y;
    p = __builtin_amdgcn_cvt_pk_f32_fp8(x0.y, true);  a6 += w0 * p.x; a7 += w0 * p.y;
    p = __builtin_amdgcn_cvt_pk_f32_fp8(x1.x, false); a0 += w1 * p.x; a1 += w1 * p.y;
    p = __builtin_amdgcn_cvt_pk_f32_fp8(x1.x, true);  a2 += w1 * p.x; a3 += w1 * p.y;
    p = __builtin_amdgcn_cvt_pk_f32_fp8(x1.y, false); a4 += w1 * p.x; a5 += w1 * p.y;
    p = __builtin_amdgcn_cvt_pk_f32_fp8(x1.y, true);  a6 += w1 * p.x; a7 += w1 * p.y;
    p = __builtin_amdgcn_cvt_pk_f32_fp8(x2.x, false); a0 += w2 * p.x; a1 += w2 * p.y;
    p = __builtin_amdgcn_cvt_pk_f32_fp8(x2.x, true);  a2 += w2 * p.x; a3 += w2 * p.y;
    p = __builtin_amdgcn_cvt_pk_f32_fp8(x2.y, false); a4 += w2 * p.x; a5 += w2 * p.y;
    p = __builtin_amdgcn_cvt_pk_f32_fp8(x2.y, true);  a6 += w2 * p.x; a7 += w2 * p.y;
    p = __builtin_amdgcn_cvt_pk_f32_fp8(x3.x, false); a0 += w3 * p.x; a1 += w3 * p.y;
    p = __builtin_amdgcn_cvt_pk_f32_fp8(x3.x, true);  a2 += w3 * p.x; a3 += w3 * p.y;
    p = __builtin_amdgcn_cvt_pk_f32_fp8(x3.y, false); a4 += w3 * p.x; a5 += w3 * p.y;
    p = __builtin_amdgcn_cvt_pk_f32_fp8(x3.y, true);  a6 += w3 * p.x; a7 += w3 * p.y;
  }
  a0 += __shfl_xor(a0, 32); a1 += __shfl_xor(a1, 32);
  a2 += __shfl_xor(a2, 32); a3 += __shfl_xor(a3, 32);
  a4 += __shfl_xor(a4, 32); a5 += __shfl_xor(a5, 32);
  a6 += __shfl_xor(a6, 32); a7 += __shfl_xor(a7, 32);
  degw += __shfl_xor(degw, 32);
  float inv = (degw == 0.f) ? 1.f : 1.f / degw;
  m0 = a0 * inv; m1 = a1 * inv; m2 = a2 * inv; m3 = a3 * inv;
  m4 = a4 * inv; m5 = a5 * inv; m6 = a6 * inv; m7 = a7 * inv;
}

// ---- gather + relation attention: agg[node] = c1*mA + c2*mB (bf16) ----
__global__ __launch_bounds__(256) void gatherAtt_kernel(GATab T) {
  const int bx = blockIdx.x;
  int t = 0;
#pragma unroll
  for (int k = 1; k < 3; ++k) t += (bx >= T.cum[k]);
  const int node = (bx - T.cum[t]) * 4 + (threadIdx.x >> 6);
  const int lane = threadIdx.x & 63;
  const int half = lane >> 5;
  const int c8 = lane & 31;

  const int* ofA = T.ofA[t];
  const int* ofB = T.ofB[t];
  float mA0, mA1, mA2, mA3, mA4, mA5, mA6, mA7;
  float mB0, mB1, mB2, mB3, mB4, mB5, mB6, mB7;
  bucket_msg(T.swA[t], T.hpA[t], ofA[node], ofA[node + 1], half, c8,
             mA0, mA1, mA2, mA3, mA4, mA5, mA6, mA7);
  bucket_msg(T.swB[t], T.hpB[t], ofB[node], ofB[node + 1], half, c8,
             mB0, mB1, mB2, mB3, mB4, mB5, mB6, mB7);

  // attention: scores via in-register dots + intra-half shfl reduce, then softmax
  const float4* A1v = reinterpret_cast<const float4*>(T.A1[t]);  // [4][64] float4
  const float4* A2v = reinterpret_cast<const float4*>(T.A2[t]);
  float c1 = 0.f, c2 = 0.f;
#pragma unroll
  for (int hh = 0; hh < 4; ++hh) {
    float4 qa = A1v[hh * 64 + c8 * 2], qb = A1v[hh * 64 + c8 * 2 + 1];
    float4 ra = A2v[hh * 64 + c8 * 2], rb = A2v[hh * 64 + c8 * 2 + 1];
    float sA = mA0 * qa.x + mA1 * qa.y + mA2 * qa.z + mA3 * qa.w
             + mA4 * qb.x + mA5 * qb.y + mA6 * qb.z + mA7 * qb.w;
    float sB = mB0 * ra.x + mB1 * ra.y + mB2 * ra.z + mB3 * ra.w
             + mB4 * rb.x + mB5 * rb.y + mB6 * rb.z + mB7 * rb.w;
#pragma unroll
    for (int o = 1; o <= 16; o <<= 1) { sA += __shfl_xor(sA, o); sB += __shfl_xor(sB, o); }
    // softmax over the 2 relations; scale = 1/(sqrt(256)*0.5) = 0.125
    float s1 = sA * 0.125f, s2 = sB * 0.125f;
    float mx = fmaxf(s1, s2);
    float e1 = __expf(s1 - mx), e2 = __expf(s2 - mx);
    float inv = 1.f / (e1 + e2);
    c1 += e1 * inv; c2 += e2 * inv;
  }
  c1 *= 0.25f; c2 *= 0.25f;  // mean over H=4 heads

  if (half == 0) {
    u32x4 o;
    o.x = (unsigned)f2bf(c1 * mA0 + c2 * mB0) | ((unsigned)f2bf(c1 * mA1 + c2 * mB1) << 16);
    o.y = (unsigned)f2bf(c1 * mA2 + c2 * mB2) | ((unsigned)f2bf(c1 * mA3 + c2 * mB3) << 16);
    o.z = (unsigned)f2bf(c1 * mA4 + c2 * mB4) | ((unsigned)f2bf(c1 * mA5 + c2 * mB5) << 16);
    o.w = (unsigned)f2bf(c1 * mA6 + c2 * mB6) | ((unsigned)f2bf(c1 * mA7 + c2 * mB7) << 16);
    __builtin_nontemporal_store(o, reinterpret_cast<u32x4*>(T.agg[t]) + (size_t)node * 32 + c8);
  }
}

// ---- all 3 types merged: self-GEMM + agg + residual + LN + leaky ----
__global__ __launch_bounds__(256) void fuse3_kernel(FTab F) {
  __shared__ alignas(16) union SM {
    struct { unsigned short x[64 * 264]; unsigned short w[256 * 56]; } g;
    unsigned short s[64 * 260];  // self result, bf16
  } ov;
  __shared__ float sgb[512];
  const int tid = threadIdx.x;
  const int bx = blockIdx.x;
  int t = 0;
#pragma unroll
  for (int k = 1; k < 3; ++k) t += (bx >= F.cum[k]);
  const int r0 = (bx - F.cum[t]) * 64;
  const float* __restrict__ h = F.h[t];
  const unsigned short* __restrict__ agg = F.agg[t];

  stage_x_f32(h, r0, ov.g.x, tid);
  for (int i = tid; i < 512; i += 256) sgb[i] = (i < 256) ? F.gm[t][i] : F.bt[t][i - 256];

  f32x4 accv[4][4];
#pragma unroll
  for (int a = 0; a < 4; ++a)
#pragma unroll
    for (int b = 0; b < 4; ++b) accv[a][b] = {0.f, 0.f, 0.f, 0.f};

  gemm_frag(ov.g.x, F.wbf[t], ov.g.w, tid, accv);

  const int wid = tid >> 6, lane = tid & 63, lhi = lane >> 4, llo = lane & 15;
  __syncthreads();  // all MFMA LDS reads done before overlaying ov.s
#pragma unroll
  for (int rt = 0; rt < 4; ++rt)
#pragma unroll
    for (int nt = 0; nt < 4; ++nt) {
      int col = wid * 64 + nt * 16 + llo;
#pragma unroll
      for (int rg = 0; rg < 4; ++rg)
        ov.s[(rt * 16 + lhi * 4 + rg) * 260 + col] = f2bf(accv[rt][nt][rg]);
    }
  __syncthreads();

  // epilogue: wave handles 16 rows; lane owns 4 dims
  const int d0 = lane * 4;
  const float4 g4 = *reinterpret_cast<const float4*>(&sgb[d0]);
  const float4 b4 = *reinterpret_cast<const float4*>(&sgb[256 + d0]);
  float* __restrict__ outp = F.out[t];

  for (int rl = 0; rl < 16; ++rl) {
    int row = wid * 16 + rl;
    size_t gb = (size_t)(r0 + row) * DIM + d0;
    ushort4 ab = *reinterpret_cast<const ushort4*>(agg + gb);
    float4 av = {bf2f(ab.x), bf2f(ab.y), bf2f(ab.z), bf2f(ab.w)};
    float4 hvv = *reinterpret_cast<const float4*>(h + gb);
    ushort4 sb = *reinterpret_cast<const ushort4*>(&ov.s[row * 260 + d0]);
    float4 sv = {bf2f(sb.x), bf2f(sb.y), bf2f(sb.z), bf2f(sb.w)};

    float4 u;
    u.x = sv.x + av.x + hvv.x;
    u.y = sv.y + av.y + hvv.y;
    u.z = sv.z + av.z + hvv.z;
    u.w = sv.w + av.w + hvv.w;

    float s1v = u.x + u.y + u.z + u.w;
    float s2v = u.x * u.x + u.y * u.y + u.z * u.z + u.w * u.w;
#pragma unroll
    for (int o = 1; o < 64; o <<= 1) { s1v += __shfl_xor(s1v, o); s2v += __shfl_xor(s2v, o); }
    float mu = s1v * (1.f / 256.f);
    float var = s2v * (1.f / 256.f) - mu * mu;
    float rstd = rsqrtf(var + 1e-5f);

    float4 y;
    y.x = (u.x - mu) * rstd * g4.x + b4.x;
    y.y = (u.y - mu) * rstd * g4.y + b4.y;
    y.z = (u.z - mu) * rstd * g4.z + b4.z;
    y.w = (u.w - mu) * rstd * g4.w + b4.w;
    y.x = fmaxf(y.x, 0.01f * y.x);
    y.y = fmaxf(y.y, 0.01f * y.y);
    y.z = fmaxf(y.z, 0.01f * y.z);
    y.w = fmaxf(y.w, 0.01f * y.w);
    *reinterpret_cast<float4*>(outp + gb) = y;
  }
}

// ---- workspace layout (bytes); ~80 MB (< proven ~139 MB) ----
static constexpr size_t AL(size_t x) { return (x + 255) & ~size_t(255); }
// aggregated messages (bf16), one row per node, type-major l|g|d
static constexpr size_t AGG_TOT = (size_t)(NLr + NGr + NDr) * DIM;      // ushorts
// transformed embeddings (fp8, 1 byte/elem), all 6 relations, sized by SRC rows
static constexpr size_t HPe_L2G = 0;                                    // NLr rows
static constexpr size_t HPe_G2L = HPe_L2G + (size_t)NLr * DIM;          // NGr
static constexpr size_t HPe_G2D = HPe_G2L + (size_t)NGr * DIM;          // NGr
static constexpr size_t HPe_D2G = HPe_G2D + (size_t)NGr * DIM;          // NDr
static constexpr size_t HPe_L2D = HPe_D2G + (size_t)NDr * DIM;          // NLr
static constexpr size_t HPe_D2L = HPe_L2D + (size_t)NLr * DIM;          // NDr
static constexpr size_t HP_TOT  = HPe_D2L + (size_t)NDr * DIM;          // bytes
static constexpr size_t OFF_AGG   = 0;
static constexpr size_t OFF_HP    = AL(OFF_AGG + AGG_TOT * 2);
static constexpr size_t OFF_WBF   = AL(OFF_HP + HP_TOT);
static constexpr size_t OFF_OFFS  = AL(OFF_WBF + 9 * 65536 * 2);
static constexpr size_t OFF_CHIST = AL(OFF_OFFS + 6 * HSTRIDE * 4);     // 384 ints
static constexpr size_t OFF_CBASE = AL(OFF_CHIST + 384 * 4);            // 6*65 ints
static constexpr size_t OFF_CCUR  = AL(OFF_CBASE + 390 * 4);            // 384 ints
static constexpr size_t OFF_TMP   = AL(OFF_CCUR + 384 * 4);             // 6*NE int2
static constexpr size_t OFF_SRCW  = AL(OFF_TMP + (size_t)6 * NE * 8);   // 6*NE u32

extern "C" void kernel_launch(void* const* d_in, const int* in_sizes, int n_in,
                              void* d_out, int out_size, void* d_ws, size_t ws_size,
                              hipStream_t stream) {
  char* wsb = (char*)d_ws;
  unsigned short* agg = (unsigned short*)(wsb + OFF_AGG);
  unsigned char* hp   = (unsigned char*)(wsb + OFF_HP);
  unsigned short* wbf = (unsigned short*)(wsb + OFF_WBF);
  int* offs  = (int*)(wsb + OFF_OFFS);
  int* chist = (int*)(wsb + OFF_CHIST);
  int* cbase = (int*)(wsb + OFF_CBASE);
  int* ccur  = (int*)(wsb + OFF_CCUR);
  int2* tmp  = (int2*)(wsb + OFF_TMP);
  unsigned* srcw = (unsigned*)(wsb + OFF_SRCW);
  float* out = (float*)d_out;

  // relation order: l2g, g2l, g2d, d2g, l2d, d2l
  const int base[6] = {3, 8, 13, 18, 23, 28};
  const int ndst[6] = {NGr, NLr, NDr, NGr, NDr, NLr};
  const size_t hpOff[6]  = {HPe_L2G, HPe_G2L, HPe_G2D, HPe_D2G, HPe_L2D, HPe_D2L};

  // merged prep: weight f32->bf16 + coarse dst histogram
  (void)hipMemsetAsync(chist, 0, 384 * 4, stream);
  PrepTab Q; PTab P; NTab N;
  Q.wsrc[0] = (const float*)d_in[6];  Q.wsrc[1] = (const float*)d_in[11];
  Q.wsrc[2] = (const float*)d_in[16]; Q.wsrc[3] = (const float*)d_in[21];
  Q.wsrc[4] = (const float*)d_in[26]; Q.wsrc[5] = (const float*)d_in[31];
  Q.wsrc[6] = (const float*)d_in[33]; Q.wsrc[7] = (const float*)d_in[36];
  Q.wsrc[8] = (const float*)d_in[39];
  for (int r = 0; r < 6; ++r) {
    int sh = (ndst[r] == NGr) ? 9 : (ndst[r] == NLr ? 8 : 7);  // coarse = n>>6
    Q.dst[r] = (const int*)d_in[base[r] + 1];
    Q.shift[r] = sh;
    P.src[r] = (const int*)d_in[base[r]];
    P.dst[r] = (const int*)d_in[base[r] + 1];
    P.w[r]  = (const float*)d_in[base[r] + 2];
    P.shift[r] = sh;
    N.n[r] = ndst[r];
  }
  prep_kernel<<<2304 + 1536, 256, 0, stream>>>(Q, wbf, chist);
  scan384_kernel<<<1, 64, 0, stream>>>(chist, ccur, cbase);

  // partition pass A (coarse)
  partA6_kernel<<<dim3(NE / 1024, 6), 256, 0, stream>>>(P, ccur, tmp);

  // mid: partB (fine placement + offs) OVERLAPPED with transformT (independent)
  // type l -> {l2g(0), l2d(4)}, type g -> {g2l(1), g2d(2)}, type d -> {d2g(3), d2l(5)}
  TTy T;
  T.h[0] = (const float*)d_in[0]; T.h[1] = (const float*)d_in[1]; T.h[2] = (const float*)d_in[2];
  T.hpA[0] = hp + hpOff[0]; T.hpB[0] = hp + hpOff[4];
  T.hpA[1] = hp + hpOff[1]; T.hpB[1] = hp + hpOff[2];
  T.hpA[2] = hp + hpOff[3]; T.hpB[2] = hp + hpOff[5];
  T.wA[0] = wbf + 0 * 65536; T.wB[0] = wbf + 4 * 65536;
  T.wA[1] = wbf + 1 * 65536; T.wB[1] = wbf + 2 * 65536;
  T.wA[2] = wbf + 3 * 65536; T.wB[2] = wbf + 5 * 65536;
  T.cum[0] = 0; T.cum[1] = NLr / 64; T.cum[2] = (NLr + NGr) / 64; T.cum[3] = (NLr + NGr + NDr) / 64;
  mid_kernel<<<384 + 896, 256, 0, stream>>>(tmp, cbase, offs, srcw, N, T);

  // gather + attention per dest type: l <- {g2l(1), d2l(5)}, g <- {l2g(0), d2g(3)},
  // d <- {g2d(2), l2d(4)}; one wave per node, serial two-bucket walk (fp8 rows)
  GATab G;
  const int relA[3] = {1, 0, 2}, relB[3] = {5, 3, 4};
  const int aA[3] = {12, 7, 17}, aB[3] = {32, 22, 27};
  const size_t aggBase[3] = {0, (size_t)NLr * DIM, (size_t)(NLr + NGr) * DIM};
  for (int t = 0; t < 3; ++t) {
    G.hpA[t] = hp + hpOff[relA[t]];
    G.hpB[t] = hp + hpOff[relB[t]];
    G.swA[t] = srcw + (size_t)relA[t] * NE;
    G.swB[t] = srcw + (size_t)relB[t] * NE;
    G.ofA[t] = offs + relA[t] * HSTRIDE;
    G.ofB[t] = offs + relB[t] * HSTRIDE;
    G.A1[t] = (const float*)d_in[aA[t]];
    G.A2[t] = (const float*)d_in[aB[t]];
    G.agg[t] = agg + aggBase[t];
  }
  G.cum[0] = 0; G.cum[1] = NLr / 4; G.cum[2] = (NLr + NGr) / 4; G.cum[3] = (NLr + NGr + NDr) / 4;
  gatherAtt_kernel<<<G.cum[3], 256, 0, stream>>>(G);

  // fused update, all 3 types in one launch
  FTab F;
  F.h[0] = (const float*)d_in[0]; F.h[1] = (const float*)d_in[1]; F.h[2] = (const float*)d_in[2];
  F.agg[0] = agg + aggBase[0]; F.agg[1] = agg + aggBase[1]; F.agg[2] = agg + aggBase[2];
  F.wbf[0] = wbf + 6 * 65536; F.wbf[1] = wbf + 7 * 65536; F.wbf[2] = wbf + 8 * 65536;
  F.gm[0] = (const float*)d_in[34]; F.bt[0] = (const float*)d_in[35];
  F.gm[1] = (const float*)d_in[37]; F.bt[1] = (const float*)d_in[38];
  F.gm[2] = (const float*)d_in[40]; F.bt[2] = (const float*)d_in[41];
  F.out[0] = out;
  F.out[1] = out + (size_t)NLr * DIM;
  F.out[2] = out + (size_t)(NLr + NGr) * DIM;
  F.cum[0] = 0; F.cum[1] = NLr / 64; F.cum[2] = (NLr + NGr) / 64; F.cum[3] = (NLr + NGr + NDr) / 64;
  fuse3_kernel<<<F.cum[3], 256, 0, stream>>>(F);
}

// Round 16
// 236.854 us; speedup vs baseline: 1.8527x; 1.0603x over previous
//
#include <hip/hip_runtime.h>

#define DIM 256
#define NLr 16384
#define NGr 32768
#define NDr 8192
#define NE  262144
#define HSTRIDE 32772  // offs per-relation stride (16B-aligned)

typedef short bf16x8 __attribute__((ext_vector_type(8)));
typedef float f32x4 __attribute__((ext_vector_type(4)));
typedef float f32x2 __attribute__((ext_vector_type(2)));
typedef unsigned u32x4 __attribute__((ext_vector_type(4)));

__device__ __forceinline__ unsigned short f2bf(float f) {
  unsigned int u = __builtin_bit_cast(unsigned int, f);
  u += 0x7fffu + ((u >> 16) & 1u);
  return (unsigned short)(u >> 16);
}
__device__ __forceinline__ float bf2f(unsigned short b) {
  return __builtin_bit_cast(float, ((unsigned int)b) << 16);
}
__device__ __forceinline__ float bfhi(unsigned int u) {
  return __builtin_bit_cast(float, u & 0xffff0000u);
}

struct NTab { int n[6]; };
struct PrepTab { const float* wsrc[9]; const int* dst[6]; int shift[6]; };
struct PTab { const int* src[6]; const int* dst[6]; const float* w[6]; int shift[6]; };
struct TTy { const float* h[3]; unsigned char* hpA[3]; unsigned char* hpB[3];
             const unsigned short* wA[3]; const unsigned short* wB[3]; int cum[4]; };
struct GATab { const unsigned char* hpA[3]; const unsigned char* hpB[3];
               const unsigned* swA[3]; const unsigned* swB[3];
               const int* ofA[3]; const int* ofB[3];
               const float* A1[3]; const float* A2[3];
               unsigned short* agg[3]; int cum[4]; };
struct FTab { const float* h[3]; const unsigned short* agg[3];
              const unsigned short* wbf[3]; const float* gm[3]; const float* bt[3];
              float* out[3]; int cum[4]; };

// ---- merged prep: blocks [0,2304) convert 9 weight mats; [2304,3840) coarse hist ----
__global__ __launch_bounds__(256) void prep_kernel(PrepTab Q, unsigned short* __restrict__ wbf,
                                                   int* __restrict__ chist) {
  const int bid = blockIdx.x, tid = threadIdx.x;
  __shared__ int h[64];
  if (bid < 2304) {
    int m = bid >> 8;
    int i = (bid & 255) * 256 + tid;
    wbf[m * 65536 + i] = f2bf(Q.wsrc[m][i]);
  } else {
    int b2 = bid - 2304;
    int r = b2 >> 8;          // 256 blocks per relation, 1024 edges each
    int blk = b2 & 255;
    if (tid < 64) h[tid] = 0;
    __syncthreads();
    const int* dp = Q.dst[r] + blk * 1024;
    const int sh = Q.shift[r];
#pragma unroll
    for (int k = 0; k < 4; ++k) atomicAdd(&h[dp[k * 256 + tid] >> sh], 1);
    __syncthreads();
    if (tid < 64) { int c = h[tid]; if (c) atomicAdd(&chist[r * 64 + tid], c); }
  }
}

// ---- tiny coarse scan: ccur (working cursor) + cbase (read-only windows) ----
__global__ void scan384_kernel(const int* __restrict__ chist, int* __restrict__ ccur,
                               int* __restrict__ cbase) {
  int r = threadIdx.x;
  if (r < 6) {
    int off = 0;
    for (int b = 0; b < 64; ++b) {
      ccur[r * 64 + b] = off;
      cbase[r * 65 + b] = off;
      off += chist[r * 64 + b];
    }
    cbase[r * 65 + 64] = off;  // == NE
  }
}

// ---- partition pass A: coarse 64-bucket partition into tmp (dst, packed) ----
__global__ __launch_bounds__(256) void partA6_kernel(PTab P, int* __restrict__ ccur,
                                                     int2* __restrict__ tmp) {
  int r = blockIdx.y;
  const int tid = threadIdx.x;
  __shared__ int hist[64], lbase[64], lcur[64];
  if (tid < 64) { hist[tid] = 0; lcur[tid] = 0; }
  __syncthreads();
  const int ebase = blockIdx.x * 1024;
  const int sh = P.shift[r];
  int dsts[4]; unsigned pk[4]; int bks[4];
#pragma unroll
  for (int k = 0; k < 4; ++k) {
    int e = ebase + k * 256 + tid;
    int d = P.dst[r][e];
    dsts[k] = d;
    pk[k] = (unsigned)P.src[r][e] | ((unsigned)f2bf(P.w[r][e]) << 16);
    bks[k] = d >> sh;
    atomicAdd(&hist[bks[k]], 1);
  }
  __syncthreads();
  if (tid < 64) {
    int c = hist[tid];
    if (c) lbase[tid] = atomicAdd(&ccur[r * 64 + tid], c);
  }
  __syncthreads();
#pragma unroll
  for (int k = 0; k < 4; ++k) {
    int pos = lbase[bks[k]] + atomicAdd(&lcur[bks[k]], 1);
    tmp[(size_t)r * NE + pos] = make_int2(dsts[k], (int)pk[k]);
  }
}

// ---- shared GEMM pieces: 64 rows x (256x256) bf16 MFMA (rounds 6-15 proven) ----
__device__ __forceinline__ void stage_x_f32(const float* __restrict__ g, int r0,
                                            unsigned short* xs, int tid) {
#pragma unroll
  for (int it = 0; it < 16; ++it) {
    int i = it * 256 + tid;
    int row = i >> 6, q = i & 63;
    float4 v = reinterpret_cast<const float4*>(g)[(size_t)(r0 + row) * 64 + q];
    ushort4 b;
    b.x = f2bf(v.x); b.y = f2bf(v.y); b.z = f2bf(v.z); b.w = f2bf(v.w);
    *reinterpret_cast<ushort4*>(&xs[row * 264 + q * 4]) = b;
  }
}

__device__ __forceinline__ void gemm_frag(const unsigned short* xs,
                                          const unsigned short* __restrict__ Wg,
                                          unsigned short* wl, int tid,
                                          f32x4 accv[4][4]) {
  const int wid = tid >> 6, lhi = (tid & 63) >> 4, llo = tid & 15;
  for (int ks = 0; ks < 8; ++ks) {
    const int k0 = ks * 32;
    __syncthreads();  // protects xs (first iter) and wl reads from prev iter
    {
      const uint4* gp = reinterpret_cast<const uint4*>(Wg + (size_t)tid * 256 + k0);
      uint4 a0 = gp[0], a1 = gp[1], a2 = gp[2], a3 = gp[3];
      uint4* lp = reinterpret_cast<uint4*>(wl + tid * 56);
      lp[0] = a0; lp[1] = a1; lp[2] = a2; lp[3] = a3;
    }
    __syncthreads();
    bf16x8 afr[4], bfr[4];
#pragma unroll
    for (int rt = 0; rt < 4; ++rt)
      afr[rt] = *reinterpret_cast<const bf16x8*>(&xs[(rt * 16 + llo) * 264 + k0 + lhi * 8]);
#pragma unroll
    for (int nt = 0; nt < 4; ++nt)
      bfr[nt] = *reinterpret_cast<const bf16x8*>(&wl[(wid * 64 + nt * 16 + llo) * 56 + lhi * 8]);
#pragma unroll
    for (int rt = 0; rt < 4; ++rt)
#pragma unroll
      for (int nt = 0; nt < 4; ++nt)
        accv[rt][nt] = __builtin_amdgcn_mfma_f32_16x16x32_bf16(afr[rt], bfr[nt], accv[rt][nt], 0, 0, 0);
  }
}

// ---- writeout: accv -> fp8 e4m3 bytes (hp row = 256 B) ----
__device__ __forceinline__ void writeout_hp(unsigned char* __restrict__ hp, int r0, int tid,
                                            f32x4 accv[4][4]) {
  const int wid = tid >> 6, lane = tid & 63, lhi = lane >> 4, llo = lane & 15;
#pragma unroll
  for (int rt = 0; rt < 4; ++rt)
#pragma unroll
    for (int nt = 0; nt < 4; ++nt) {
      int col = wid * 64 + nt * 16 + llo;
#pragma unroll
      for (int rg = 0; rg < 4; ++rg) {
        int row = rt * 16 + lhi * 4 + rg;
        int pk = __builtin_amdgcn_cvt_pk_fp8_f32(accv[rt][nt][rg], accv[rt][nt][rg], 0, false);
        hp[(size_t)(r0 + row) * DIM + col] = (unsigned char)(pk & 0xff);
      }
    }
}

// ---- mid kernel: partB (blocks [0,384)) ∥ transformT (blocks [384,1280)) ----
__global__ __launch_bounds__(256) void mid_kernel(const int2* __restrict__ tmp,
                                                  const int* __restrict__ cbase,
                                                  int* __restrict__ offs,
                                                  unsigned* __restrict__ srcw,
                                                  NTab N, TTy T) {
  __shared__ union alignas(16) SM {
    struct { unsigned short xs[64 * 264]; unsigned short wl[256 * 56]; } t;
    struct { int hist[512]; int part[256]; } p;
  } sm;
  const int bid = blockIdx.x, tid = threadIdx.x;

  if (bid < 384) {
    // ---------------- partB path (round-11 proven) ----------------
    int r = bid >> 6, b = bid & 63;
    const int n = N.n[r], s = n >> 6;
    const int dbase = b * s;
    int* hist = sm.p.hist;
    int* part = sm.p.part;
    for (int i = tid; i < s; i += 256) hist[i] = 0;
    __syncthreads();
    const int wbeg = cbase[r * 65 + b], wend = cbase[r * 65 + b + 1];
    const int2* __restrict__ tr = tmp + (size_t)r * NE;
    for (int i = wbeg + tid; i < wend; i += 256)
      atomicAdd(&hist[tr[i].x - dbase], 1);
    __syncthreads();
    const int per = (s > 256) ? 2 : 1;
    const int base = tid * per;
    int vals[2];
    int mysum = 0;
#pragma unroll
    for (int j = 0; j < 2; ++j) {
      int idx = base + j;
      vals[j] = (j < per && idx < s) ? hist[idx] : 0;
      mysum += vals[j];
    }
    part[tid] = mysum;
    __syncthreads();
    for (int off = 1; off < 256; off <<= 1) {
      int v = (tid >= off) ? part[tid - off] : 0;
      __syncthreads();
      part[tid] += v;
      __syncthreads();
    }
    int run = part[tid] - mysum + wbeg;
#pragma unroll
    for (int j = 0; j < 2; ++j) {
      int idx = base + j;
      if (j < per && idx < s) {
        hist[idx] = run;                         // becomes the live cursor
        offs[r * HSTRIDE + dbase + idx] = run;   // fine CSR offsets
        run += vals[j];
      }
    }
    if (b == 0 && tid == 0) offs[r * HSTRIDE + n] = NE;
    __syncthreads();
    for (int i = wbeg + tid; i < wend; i += 256) {
      int2 e = tr[i];
      int pos = atomicAdd(&hist[e.x - dbase], 1);
      srcw[(size_t)r * NE + pos] = (unsigned)e.y;
    }
  } else {
    // ---------------- transformT path (fp8 writeout) ----------------
    const int bx = bid - 384;
    int t = 0;
#pragma unroll
    for (int k = 1; k < 3; ++k) t += (bx >= T.cum[k]);
    const int r0 = (bx - T.cum[t]) * 64;

    stage_x_f32(T.h[t], r0, sm.t.xs, tid);

    f32x4 accv[4][4];
#pragma unroll
    for (int a = 0; a < 4; ++a)
#pragma unroll
      for (int b2 = 0; b2 < 4; ++b2) accv[a][b2] = {0.f, 0.f, 0.f, 0.f};
    gemm_frag(sm.t.xs, T.wA[t], sm.t.wl, tid, accv);
    writeout_hp(T.hpA[t], r0, tid, accv);

#pragma unroll
    for (int a = 0; a < 4; ++a)
#pragma unroll
      for (int b2 = 0; b2 < 4; ++b2) accv[a][b2] = {0.f, 0.f, 0.f, 0.f};
    gemm_frag(sm.t.xs, T.wB[t], sm.t.wl, tid, accv);  // first barrier inside protects wl reuse
    writeout_hp(T.hpB[t], r0, tid, accv);
  }
}

// ---- bucket walk (fp8 rows, round-14 single guarded body, packed f32 math) ----
// m = (Σ w·hp[src]) / Σw ; accumulators are f32x2 -> v_pk_fma_f32
__device__ __forceinline__ void bucket_msg(const unsigned* __restrict__ sw,
                                           const unsigned char* __restrict__ hp,
                                           int beg, int end, int half, int c8,
                                           float& m0, float& m1, float& m2, float& m3,
                                           float& m4, float& m5, float& m6, float& m7) {
  f32x2 a01 = {0.f, 0.f}, a23 = {0.f, 0.f}, a45 = {0.f, 0.f}, a67 = {0.f, 0.f};
  float degw = 0.f;
  const int boff = c8 * 8;
  for (int j = beg; j < end; j += 8) {
    int ib = j + half * 4;
    unsigned e0 = (ib + 0 < end) ? sw[ib + 0] : 0u;
    unsigned e1 = (ib + 1 < end) ? sw[ib + 1] : 0u;
    unsigned e2 = (ib + 2 < end) ? sw[ib + 2] : 0u;
    unsigned e3 = (ib + 3 < end) ? sw[ib + 3] : 0u;
    float w0 = bfhi(e0), w1 = bfhi(e1), w2 = bfhi(e2), w3 = bfhi(e3);
    uint2 x0 = *reinterpret_cast<const uint2*>(hp + (size_t)(e0 & 0xffff) * DIM + boff);
    uint2 x1 = *reinterpret_cast<const uint2*>(hp + (size_t)(e1 & 0xffff) * DIM + boff);
    uint2 x2 = *reinterpret_cast<const uint2*>(hp + (size_t)(e2 & 0xffff) * DIM + boff);
    uint2 x3 = *reinterpret_cast<const uint2*>(hp + (size_t)(e3 & 0xffff) * DIM + boff);
    degw += (w0 + w1) + (w2 + w3);
    f32x2 wv0 = {w0, w0}, wv1 = {w1, w1}, wv2 = {w2, w2}, wv3 = {w3, w3};
    a01 += wv0 * __builtin_amdgcn_cvt_pk_f32_fp8(x0.x, false);
    a23 += wv0 * __builtin_amdgcn_cvt_pk_f32_fp8(x0.x, true);
    a45 += wv0 * __builtin_amdgcn_cvt_pk_f32_fp8(x0.y, false);
    a67 += wv0 * __builtin_amdgcn_cvt_pk_f32_fp8(x0.y, true);
    a01 += wv1 * __builtin_amdgcn_cvt_pk_f32_fp8(x1.x, false);
    a23 += wv1 * __builtin_amdgcn_cvt_pk_f32_fp8(x1.x, true);
    a45 += wv1 * __builtin_amdgcn_cvt_pk_f32_fp8(x1.y, false);
    a67 += wv1 * __builtin_amdgcn_cvt_pk_f32_fp8(x1.y, true);
    a01 += wv2 * __builtin_amdgcn_cvt_pk_f32_fp8(x2.x, false);
    a23 += wv2 * __builtin_amdgcn_cvt_pk_f32_fp8(x2.x, true);
    a45 += wv2 * __builtin_amdgcn_cvt_pk_f32_fp8(x2.y, false);
    a67 += wv2 * __builtin_amdgcn_cvt_pk_f32_fp8(x2.y, true);
    a01 += wv3 * __builtin_amdgcn_cvt_pk_f32_fp8(x3.x, false);
    a23 += wv3 * __builtin_amdgcn_cvt_pk_f32_fp8(x3.x, true);
    a45 += wv3 * __builtin_amdgcn_cvt_pk_f32_fp8(x3.y, false);
    a67 += wv3 * __builtin_amdgcn_cvt_pk_f32_fp8(x3.y, true);
  }
  float a0 = a01.x, a1 = a01.y, a2 = a23.x, a3 = a23.y;
  float a4 = a45.x, a5 = a45.y, a6 = a67.x, a7 = a67.y;
  a0 += __shfl_xor(a0, 32); a1 += __shfl_xor(a1, 32);
  a2 += __shfl_xor(a2, 32); a3 += __shfl_xor(a3, 32);
  a4 += __shfl_xor(a4, 32); a5 += __shfl_xor(a5, 32);
  a6 += __shfl_xor(a6, 32); a7 += __shfl_xor(a7, 32);
  degw += __shfl_xor(degw, 32);
  float inv = (degw == 0.f) ? 1.f : 1.f / degw;
  m0 = a0 * inv; m1 = a1 * inv; m2 = a2 * inv; m3 = a3 * inv;
  m4 = a4 * inv; m5 = a5 * inv; m6 = a6 * inv; m7 = a7 * inv;
}

// ---- gather + relation attention: agg[node] = c1*mA + c2*mB (bf16) ----
__global__ __launch_bounds__(256) void gatherAtt_kernel(GATab T) {
  const int bx = blockIdx.x;
  int t = 0;
#pragma unroll
  for (int k = 1; k < 3; ++k) t += (bx >= T.cum[k]);
  const int node = (bx - T.cum[t]) * 4 + (threadIdx.x >> 6);
  const int lane = threadIdx.x & 63;
  const int half = lane >> 5;
  const int c8 = lane & 31;

  const int* ofA = T.ofA[t];
  const int* ofB = T.ofB[t];
  float mA0, mA1, mA2, mA3, mA4, mA5, mA6, mA7;
  float mB0, mB1, mB2, mB3, mB4, mB5, mB6, mB7;
  bucket_msg(T.swA[t], T.hpA[t], ofA[node], ofA[node + 1], half, c8,
             mA0, mA1, mA2, mA3, mA4, mA5, mA6, mA7);
  bucket_msg(T.swB[t], T.hpB[t], ofB[node], ofB[node + 1], half, c8,
             mB0, mB1, mB2, mB3, mB4, mB5, mB6, mB7);

  // attention: scores via in-register dots + intra-half shfl reduce, then softmax
  const float4* A1v = reinterpret_cast<const float4*>(T.A1[t]);  // [4][64] float4
  const float4* A2v = reinterpret_cast<const float4*>(T.A2[t]);
  float c1 = 0.f, c2 = 0.f;
#pragma unroll
  for (int hh = 0; hh < 4; ++hh) {
    float4 qa = A1v[hh * 64 + c8 * 2], qb = A1v[hh * 64 + c8 * 2 + 1];
    float4 ra = A2v[hh * 64 + c8 * 2], rb = A2v[hh * 64 + c8 * 2 + 1];
    float sA = mA0 * qa.x + mA1 * qa.y + mA2 * qa.z + mA3 * qa.w
             + mA4 * qb.x + mA5 * qb.y + mA6 * qb.z + mA7 * qb.w;
    float sB = mB0 * ra.x + mB1 * ra.y + mB2 * ra.z + mB3 * ra.w
             + mB4 * rb.x + mB5 * rb.y + mB6 * rb.z + mB7 * rb.w;
#pragma unroll
    for (int o = 1; o <= 16; o <<= 1) { sA += __shfl_xor(sA, o); sB += __shfl_xor(sB, o); }
    // softmax over the 2 relations; scale = 1/(sqrt(256)*0.5) = 0.125
    float s1 = sA * 0.125f, s2 = sB * 0.125f;
    float mx = fmaxf(s1, s2);
    float e1 = __expf(s1 - mx), e2 = __expf(s2 - mx);
    float inv = 1.f / (e1 + e2);
    c1 += e1 * inv; c2 += e2 * inv;
  }
  c1 *= 0.25f; c2 *= 0.25f;  // mean over H=4 heads

  if (half == 0) {
    u32x4 o;
    o.x = (unsigned)f2bf(c1 * mA0 + c2 * mB0) | ((unsigned)f2bf(c1 * mA1 + c2 * mB1) << 16);
    o.y = (unsigned)f2bf(c1 * mA2 + c2 * mB2) | ((unsigned)f2bf(c1 * mA3 + c2 * mB3) << 16);
    o.z = (unsigned)f2bf(c1 * mA4 + c2 * mB4) | ((unsigned)f2bf(c1 * mA5 + c2 * mB5) << 16);
    o.w = (unsigned)f2bf(c1 * mA6 + c2 * mB6) | ((unsigned)f2bf(c1 * mA7 + c2 * mB7) << 16);
    __builtin_nontemporal_store(o, reinterpret_cast<u32x4*>(T.agg[t]) + (size_t)node * 32 + c8);
  }
}

// ---- all 3 types merged: self-GEMM + agg + residual + LN + leaky (round-15 proven) ----
__global__ __launch_bounds__(256) void fuse3_kernel(FTab F) {
  __shared__ alignas(16) union SM {
    struct { unsigned short x[64 * 264]; unsigned short w[256 * 56]; } g;
    unsigned short s[64 * 260];  // self result, bf16
  } ov;
  __shared__ float sgb[512];
  const int tid = threadIdx.x;
  const int bx = blockIdx.x;
  int t = 0;
#pragma unroll
  for (int k = 1; k < 3; ++k) t += (bx >= F.cum[k]);
  const int r0 = (bx - F.cum[t]) * 64;
  const float* __restrict__ h = F.h[t];
  const unsigned short* __restrict__ agg = F.agg[t];

  stage_x_f32(h, r0, ov.g.x, tid);
  for (int i = tid; i < 512; i += 256) sgb[i] = (i < 256) ? F.gm[t][i] : F.bt[t][i - 256];

  f32x4 accv[4][4];
#pragma unroll
  for (int a = 0; a < 4; ++a)
#pragma unroll
    for (int b = 0; b < 4; ++b) accv[a][b] = {0.f, 0.f, 0.f, 0.f};

  gemm_frag(ov.g.x, F.wbf[t], ov.g.w, tid, accv);

  const int wid = tid >> 6, lane = tid & 63, lhi = lane >> 4, llo = lane & 15;
  __syncthreads();  // all MFMA LDS reads done before overlaying ov.s
#pragma unroll
  for (int rt = 0; rt < 4; ++rt)
#pragma unroll
    for (int nt = 0; nt < 4; ++nt) {
      int col = wid * 64 + nt * 16 + llo;
#pragma unroll
      for (int rg = 0; rg < 4; ++rg)
        ov.s[(rt * 16 + lhi * 4 + rg) * 260 + col] = f2bf(accv[rt][nt][rg]);
    }
  __syncthreads();

  // epilogue: wave handles 16 rows; lane owns 4 dims
  const int d0 = lane * 4;
  const float4 g4 = *reinterpret_cast<const float4*>(&sgb[d0]);
  const float4 b4 = *reinterpret_cast<const float4*>(&sgb[256 + d0]);
  float* __restrict__ outp = F.out[t];

  for (int rl = 0; rl < 16; ++rl) {
    int row = wid * 16 + rl;
    size_t gb = (size_t)(r0 + row) * DIM + d0;
    ushort4 ab = *reinterpret_cast<const ushort4*>(agg + gb);
    float4 av = {bf2f(ab.x), bf2f(ab.y), bf2f(ab.z), bf2f(ab.w)};
    float4 hvv = *reinterpret_cast<const float4*>(h + gb);
    ushort4 sb = *reinterpret_cast<const ushort4*>(&ov.s[row * 260 + d0]);
    float4 sv = {bf2f(sb.x), bf2f(sb.y), bf2f(sb.z), bf2f(sb.w)};

    float4 u;
    u.x = sv.x + av.x + hvv.x;
    u.y = sv.y + av.y + hvv.y;
    u.z = sv.z + av.z + hvv.z;
    u.w = sv.w + av.w + hvv.w;

    float s1v = u.x + u.y + u.z + u.w;
    float s2v = u.x * u.x + u.y * u.y + u.z * u.z + u.w * u.w;
#pragma unroll
    for (int o = 1; o < 64; o <<= 1) { s1v += __shfl_xor(s1v, o); s2v += __shfl_xor(s2v, o); }
    float mu = s1v * (1.f / 256.f);
    float var = s2v * (1.f / 256.f) - mu * mu;
    float rstd = rsqrtf(var + 1e-5f);

    float4 y;
    y.x = (u.x - mu) * rstd * g4.x + b4.x;
    y.y = (u.y - mu) * rstd * g4.y + b4.y;
    y.z = (u.z - mu) * rstd * g4.z + b4.z;
    y.w = (u.w - mu) * rstd * g4.w + b4.w;
    y.x = fmaxf(y.x, 0.01f * y.x);
    y.y = fmaxf(y.y, 0.01f * y.y);
    y.z = fmaxf(y.z, 0.01f * y.z);
    y.w = fmaxf(y.w, 0.01f * y.w);
    *reinterpret_cast<float4*>(outp + gb) = y;
  }
}

// ---- workspace layout (bytes); ~80 MB (< proven ~139 MB) ----
static constexpr size_t AL(size_t x) { return (x + 255) & ~size_t(255); }
// aggregated messages (bf16), one row per node, type-major l|g|d
static constexpr size_t AGG_TOT = (size_t)(NLr + NGr + NDr) * DIM;      // ushorts
// transformed embeddings (fp8, 1 byte/elem), all 6 relations, sized by SRC rows
static constexpr size_t HPe_L2G = 0;                                    // NLr rows
static constexpr size_t HPe_G2L = HPe_L2G + (size_t)NLr * DIM;          // NGr
static constexpr size_t HPe_G2D = HPe_G2L + (size_t)NGr * DIM;          // NGr
static constexpr size_t HPe_D2G = HPe_G2D + (size_t)NGr * DIM;          // NDr
static constexpr size_t HPe_L2D = HPe_D2G + (size_t)NDr * DIM;          // NLr
static constexpr size_t HPe_D2L = HPe_L2D + (size_t)NLr * DIM;          // NDr
static constexpr size_t HP_TOT  = HPe_D2L + (size_t)NDr * DIM;          // bytes
static constexpr size_t OFF_AGG   = 0;
static constexpr size_t OFF_HP    = AL(OFF_AGG + AGG_TOT * 2);
static constexpr size_t OFF_WBF   = AL(OFF_HP + HP_TOT);
static constexpr size_t OFF_OFFS  = AL(OFF_WBF + 9 * 65536 * 2);
static constexpr size_t OFF_CHIST = AL(OFF_OFFS + 6 * HSTRIDE * 4);     // 384 ints
static constexpr size_t OFF_CBASE = AL(OFF_CHIST + 384 * 4);            // 6*65 ints
static constexpr size_t OFF_CCUR  = AL(OFF_CBASE + 390 * 4);            // 384 ints
static constexpr size_t OFF_TMP   = AL(OFF_CCUR + 384 * 4);             // 6*NE int2
static constexpr size_t OFF_SRCW  = AL(OFF_TMP + (size_t)6 * NE * 8);   // 6*NE u32

extern "C" void kernel_launch(void* const* d_in, const int* in_sizes, int n_in,
                              void* d_out, int out_size, void* d_ws, size_t ws_size,
                              hipStream_t stream) {
  char* wsb = (char*)d_ws;
  unsigned short* agg = (unsigned short*)(wsb + OFF_AGG);
  unsigned char* hp   = (unsigned char*)(wsb + OFF_HP);
  unsigned short* wbf = (unsigned short*)(wsb + OFF_WBF);
  int* offs  = (int*)(wsb + OFF_OFFS);
  int* chist = (int*)(wsb + OFF_CHIST);
  int* cbase = (int*)(wsb + OFF_CBASE);
  int* ccur  = (int*)(wsb + OFF_CCUR);
  int2* tmp  = (int2*)(wsb + OFF_TMP);
  unsigned* srcw = (unsigned*)(wsb + OFF_SRCW);
  float* out = (float*)d_out;

  // relation order: l2g, g2l, g2d, d2g, l2d, d2l
  const int base[6] = {3, 8, 13, 18, 23, 28};
  const int ndst[6] = {NGr, NLr, NDr, NGr, NDr, NLr};
  const size_t hpOff[6]  = {HPe_L2G, HPe_G2L, HPe_G2D, HPe_D2G, HPe_L2D, HPe_D2L};

  // merged prep: weight f32->bf16 + coarse dst histogram
  (void)hipMemsetAsync(chist, 0, 384 * 4, stream);
  PrepTab Q; PTab P; NTab N;
  Q.wsrc[0] = (const float*)d_in[6];  Q.wsrc[1] = (const float*)d_in[11];
  Q.wsrc[2] = (const float*)d_in[16]; Q.wsrc[3] = (const float*)d_in[21];
  Q.wsrc[4] = (const float*)d_in[26]; Q.wsrc[5] = (const float*)d_in[31];
  Q.wsrc[6] = (const float*)d_in[33]; Q.wsrc[7] = (const float*)d_in[36];
  Q.wsrc[8] = (const float*)d_in[39];
  for (int r = 0; r < 6; ++r) {
    int sh = (ndst[r] == NGr) ? 9 : (ndst[r] == NLr ? 8 : 7);  // coarse = n>>6
    Q.dst[r] = (const int*)d_in[base[r] + 1];
    Q.shift[r] = sh;
    P.src[r] = (const int*)d_in[base[r]];
    P.dst[r] = (const int*)d_in[base[r] + 1];
    P.w[r]  = (const float*)d_in[base[r] + 2];
    P.shift[r] = sh;
    N.n[r] = ndst[r];
  }
  prep_kernel<<<2304 + 1536, 256, 0, stream>>>(Q, wbf, chist);
  scan384_kernel<<<1, 64, 0, stream>>>(chist, ccur, cbase);

  // partition pass A (coarse)
  partA6_kernel<<<dim3(NE / 1024, 6), 256, 0, stream>>>(P, ccur, tmp);

  // mid: partB (fine placement + offs) OVERLAPPED with transformT (independent)
  // type l -> {l2g(0), l2d(4)}, type g -> {g2l(1), g2d(2)}, type d -> {d2g(3), d2l(5)}
  TTy T;
  T.h[0] = (const float*)d_in[0]; T.h[1] = (const float*)d_in[1]; T.h[2] = (const float*)d_in[2];
  T.hpA[0] = hp + hpOff[0]; T.hpB[0] = hp + hpOff[4];
  T.hpA[1] = hp + hpOff[1]; T.hpB[1] = hp + hpOff[2];
  T.hpA[2] = hp + hpOff[3]; T.hpB[2] = hp + hpOff[5];
  T.wA[0] = wbf + 0 * 65536; T.wB[0] = wbf + 4 * 65536;
  T.wA[1] = wbf + 1 * 65536; T.wB[1] = wbf + 2 * 65536;
  T.wA[2] = wbf + 3 * 65536; T.wB[2] = wbf + 5 * 65536;
  T.cum[0] = 0; T.cum[1] = NLr / 64; T.cum[2] = (NLr + NGr) / 64; T.cum[3] = (NLr + NGr + NDr) / 64;
  mid_kernel<<<384 + 896, 256, 0, stream>>>(tmp, cbase, offs, srcw, N, T);

  // gather + attention per dest type: l <- {g2l(1), d2l(5)}, g <- {l2g(0), d2g(3)},
  // d <- {g2d(2), l2d(4)}; one wave per node, serial two-bucket walk (fp8 rows)
  GATab G;
  const int relA[3] = {1, 0, 2}, relB[3] = {5, 3, 4};
  const int aA[3] = {12, 7, 17}, aB[3] = {32, 22, 27};
  const size_t aggBase[3] = {0, (size_t)NLr * DIM, (size_t)(NLr + NGr) * DIM};
  for (int t = 0; t < 3; ++t) {
    G.hpA[t] = hp + hpOff[relA[t]];
    G.hpB[t] = hp + hpOff[relB[t]];
    G.swA[t] = srcw + (size_t)relA[t] * NE;
    G.swB[t] = srcw + (size_t)relB[t] * NE;
    G.ofA[t] = offs + relA[t] * HSTRIDE;
    G.ofB[t] = offs + relB[t] * HSTRIDE;
    G.A1[t] = (const float*)d_in[aA[t]];
    G.A2[t] = (const float*)d_in[aB[t]];
    G.agg[t] = agg + aggBase[t];
  }
  G.cum[0] = 0; G.cum[1] = NLr / 4; G.cum[2] = (NLr + NGr) / 4; G.cum[3] = (NLr + NGr + NDr) / 4;
  gatherAtt_kernel<<<G.cum[3], 256, 0, stream>>>(G);

  // fused update, all 3 types in one launch
  FTab F;
  F.h[0] = (const float*)d_in[0]; F.h[1] = (const float*)d_in[1]; F.h[2] = (const float*)d_in[2];
  F.agg[0] = agg + aggBase[0]; F.agg[1] = agg + aggBase[1]; F.agg[2] = agg + aggBase[2];
  F.wbf[0] = wbf + 6 * 65536; F.wbf[1] = wbf + 7 * 65536; F.wbf[2] = wbf + 8 * 65536;
  F.gm[0] = (const float*)d_in[34]; F.bt[0] = (const float*)d_in[35];
  F.gm[1] = (const float*)d_in[37]; F.bt[1] = (const float*)d_in[38];
  F.gm[2] = (const float*)d_in[40]; F.bt[2] = (const float*)d_in[41];
  F.out[0] = out;
  F.out[1] = out + (size_t)NLr * DIM;
  F.out[2] = out + (size_t)(NLr + NGr) * DIM;
  F.cum[0] = 0; F.cum[1] = NLr / 64; F.cum[2] = (NLr + NGr) / 64; F.cum[3] = (NLr + NGr + NDr) / 64;
  fuse3_kernel<<<F.cum[3], 256, 0, stream>>>(F);
}